// Round 13
// baseline (1149.463 us; speedup 1.0000x reference)
//
#include <hip/hip_runtime.h>
#include <cstdint>
#include <cstddef>

// HGT forward (2 layers) on MI355X.
// R12 -> R13: R12's persistent double-buffer pipeline REVERTED (LDS 33KB +
// 84 VGPR -> occupancy 65->23%, dur 187->269us; ILP lost to TLP). Back to the
// R11 structure (single 16KB albuf, 1 tile/block, 8 waves, 65% occ), plus an
// OCCUPANCY-NEUTRAL prefetch: the score phase's q_h[dst]/ntype[dst] gathers
// issue right after the first barrier (dst known from s_dst), hiding their
// latency under staging+MFMA+k'/v' writes. ~+12 VGPR, pinned to the 64-reg
// bucket via __launch_bounds__(512,8). Math bit-identical: absmax must stay
// 2.441406e-4.

namespace {

constexpr int T_N  = 3;
constexpr int R_N  = 4;
constexpr int HD   = 128;
constexpr int IND  = 256;
constexpr int NH   = 8;
constexpr int MAXT = 240;

typedef unsigned short u16;
typedef unsigned int   u32;
typedef _Float16 f16;
typedef __attribute__((ext_vector_type(8))) _Float16 f16x8;
typedef __attribute__((ext_vector_type(4))) float    f32x4;

// ----------------------------- utility kernels -----------------------------
__global__ void k_fill_i32(int* __restrict__ p, int v, int n) {
  int i = blockIdx.x * 256 + threadIdx.x;
  if (i < n) p[i] = v;
}
__global__ void k_copy_i32(int* __restrict__ d, const int* __restrict__ s, int n) {
  int i = blockIdx.x * 256 + threadIdx.x;
  if (i < n) d[i] = s[i];
}
__global__ void k_hist_dst(const int* __restrict__ dst, int* __restrict__ cnt, int E) {
  int i = blockIdx.x * 256 + threadIdx.x;
  if (i < E) atomicAdd(&cnt[dst[i]], 1);
}
__global__ void k_scan_a(const int* __restrict__ in, int* __restrict__ out,
                         int* __restrict__ bsums, int n) {
  __shared__ int s[256];
  int gid = blockIdx.x * 256 + threadIdx.x;
  int v = (gid < n) ? in[gid] : 0;
  s[threadIdx.x] = v;
  __syncthreads();
  for (int off = 1; off < 256; off <<= 1) {
    int t = (threadIdx.x >= off) ? s[threadIdx.x - off] : 0;
    __syncthreads();
    s[threadIdx.x] += t;
    __syncthreads();
  }
  if (gid < n) out[gid] = s[threadIdx.x] - v;
  if (threadIdx.x == 255) bsums[blockIdx.x] = s[255];
}
__global__ void k_scan_b(int* __restrict__ bsums, int nb) {
  __shared__ int s[256];
  int v = (threadIdx.x < nb) ? bsums[threadIdx.x] : 0;
  s[threadIdx.x] = v;
  __syncthreads();
  for (int off = 1; off < 256; off <<= 1) {
    int t = (threadIdx.x >= off) ? s[threadIdx.x - off] : 0;
    __syncthreads();
    s[threadIdx.x] += t;
    __syncthreads();
  }
  if (threadIdx.x < nb) bsums[threadIdx.x] = s[threadIdx.x] - v;
}
__global__ void k_scan_c(int* __restrict__ out, const int* __restrict__ bsums, int n) {
  int gid = blockIdx.x * 256 + threadIdx.x;
  if (gid < n) out[gid] += bsums[blockIdx.x];
}
// rank[e] = position of edge e in the dst-CSR ordering
__global__ void k_rank_dst(const int* __restrict__ dst, int* __restrict__ cur,
                           int* __restrict__ rank, int E) {
  int i = blockIdx.x * 256 + threadIdx.x;
  if (i < E) rank[i] = atomicAdd(&cur[dst[i]], 1);
}
__global__ void k_bhist(const int* __restrict__ src, const int* __restrict__ etype,
                        const int* __restrict__ ntype, int* __restrict__ bcnt, int E) {
  __shared__ int loc[12];
  if (threadIdx.x < 12) loc[threadIdx.x] = 0;
  __syncthreads();
  int i = blockIdx.x * 256 + threadIdx.x;
  if (i < E) {
    int b = ntype[src[i]] * R_N + etype[i];
    atomicAdd(&loc[b], 1);
  }
  __syncthreads();
  if (threadIdx.x < 12) atomicAdd(&bcnt[threadIdx.x], loc[threadIdx.x]);
}
__global__ void k_bscan(const int* __restrict__ bcnt, int* __restrict__ bal,
                        int* __restrict__ bcur) {
  if (threadIdx.x == 0 && blockIdx.x == 0) {
    int run = 0;
    for (int b = 0; b < 12; b++) {
      bal[b] = run;
      bcur[b] = run;
      run += (bcnt[b] + 63) & ~63;
    }
    bal[12] = run;
  }
}
__global__ void k_bscatter(const int* __restrict__ src, const int* __restrict__ etype,
                           const int* __restrict__ ntype, int* __restrict__ bcur,
                           int* __restrict__ esorted, int E) {
  __shared__ int loc[12];
  __shared__ int base[12];
  if (threadIdx.x < 12) loc[threadIdx.x] = 0;
  __syncthreads();
  int i = blockIdx.x * 256 + threadIdx.x;
  int b = 0, lpos = 0;
  if (i < E) {
    b = ntype[src[i]] * R_N + etype[i];
    lpos = atomicAdd(&loc[b], 1);
  }
  __syncthreads();
  if (threadIdx.x < 12) {
    int c = loc[threadIdx.x];
    base[threadIdx.x] = (c > 0) ? atomicAdd(&bcur[threadIdx.x], c) : 0;
  }
  __syncthreads();
  if (i < E) esorted[base[b] + lpos] = i;
}
// node-type buckets (3), 64-aligned
__global__ void k_nhist(const int* __restrict__ ntype, int* __restrict__ ncnt, int N) {
  __shared__ int loc[3];
  if (threadIdx.x < 3) loc[threadIdx.x] = 0;
  __syncthreads();
  int i = blockIdx.x * 256 + threadIdx.x;
  if (i < N) atomicAdd(&loc[ntype[i]], 1);
  __syncthreads();
  if (threadIdx.x < 3) atomicAdd(&ncnt[threadIdx.x], loc[threadIdx.x]);
}
__global__ void k_nscan(const int* __restrict__ ncnt, int* __restrict__ nal,
                        int* __restrict__ ncur) {
  if (threadIdx.x == 0 && blockIdx.x == 0) {
    int run = 0;
    for (int t = 0; t < 3; t++) {
      nal[t] = run;
      ncur[t] = run;
      run += (ncnt[t] + 63) & ~63;
    }
    nal[3] = run;
  }
}
__global__ void k_nscatter(const int* __restrict__ ntype, int* __restrict__ ncur,
                           int* __restrict__ nsorted, int N) {
  __shared__ int loc[3];
  __shared__ int base[3];
  if (threadIdx.x < 3) loc[threadIdx.x] = 0;
  __syncthreads();
  int i = blockIdx.x * 256 + threadIdx.x;
  int t = 0, lpos = 0;
  if (i < N) {
    t = ntype[i];
    lpos = atomicAdd(&loc[t], 1);
  }
  __syncthreads();
  if (threadIdx.x < 3) {
    int c = loc[threadIdx.x];
    base[threadIdx.x] = (c > 0) ? atomicAdd(&ncur[threadIdx.x], c) : 0;
  }
  __syncthreads();
  if (i < N) nsorted[base[t] + lpos] = i;
}

// transpose+f16: src [T][Kd][Cd] fp32 -> dst [T][Cd][Kd] f16 (k contiguous)
__global__ void k_transp(const float* __restrict__ src, u16* __restrict__ dst,
                         int Kd, int Cd) {
  int c = blockIdx.x;
  int t = blockIdx.y;
  for (int k = threadIdx.x; k < Kd; k += blockDim.x)
    dst[((size_t)t * Cd + c) * Kd + k] =
        __builtin_bit_cast(u16, (f16)src[((size_t)t * Kd + k) * Cd + c]);
}

// ------------------------------ math kernels -------------------------------
// rte table -> f16 [240][128]
__global__ void k_rte(const float* __restrict__ emb, const float* __restrict__ W,
                      const float* __restrict__ bias, u16* __restrict__ out, int l) {
  int t = blockIdx.x;
  int lane = threadIdx.x;
  __shared__ __align__(16) float s[2 * HD];
  ((float4*)s)[lane] = ((const float4*)(emb + (size_t)t * 2 * HD))[lane];
  __syncthreads();
  const float* Wl = W + (size_t)l * 2 * HD * HD;
  float o0 = bias[l * HD + 2 * lane];
  float o1 = bias[l * HD + 2 * lane + 1];
  #pragma unroll 4
  for (int k = 0; k < 2 * HD; k++) {
    float xv = s[k];
    float2 w = ((const float2*)(Wl + (size_t)k * HD))[lane];
    o0 = fmaf(xv, w.x, o0);
    o1 = fmaf(xv, w.y, o1);
  }
  u32 pk = (u32)__builtin_bit_cast(u16, (f16)o0)
         | ((u32)__builtin_bit_cast(u16, (f16)o1) << 16);
  ((u32*)out)[t * 64 + lane] = pk;
}

// Combined per-(type,rel) matrices, f16, stored [b][c][k] (k contiguous)
__global__ void k_wcomb(const float* __restrict__ Wk, const float* __restrict__ Wv,
                        const float* __restrict__ bk, const float* __restrict__ bv,
                        const float* __restrict__ Ratt, const float* __restrict__ Rmsg,
                        u16* __restrict__ Wcomb, float* __restrict__ bcomb, int l) {
  int bc = blockIdx.x;
  int b  = bc >> 8;
  int c  = bc & 255;
  int st = b >> 2, rt = b & 3;
  int k  = threadIdx.x;
  bool isv = (c >= HD);
  int c0 = isv ? c - HD : c;
  int h  = c0 >> 4, cc = c0 & 15;
  const float* W = (isv ? Wv : Wk) + (((size_t)(l * T_N + st) * HD) + k) * HD + h * 16;
  const float* A = (isv ? Rmsg : Ratt) + (((size_t)(l * R_N + rt) * NH + h) * 16) * 16 + cc;
  float s = 0.f;
  #pragma unroll
  for (int d = 0; d < 16; d++) s = fmaf(W[d], A[d * 16], s);
  Wcomb[((size_t)b * 256 + c) * HD + k] = __builtin_bit_cast(u16, (f16)s);
  if (k == 0) {
    const float* bb = (isv ? bv : bk) + (size_t)(l * T_N + st) * HD + h * 16;
    float sb = 0.f;
    #pragma unroll
    for (int d = 0; d < 16; d++) sb = fmaf(bb[d], A[d * 16], sb);
    bcomb[b * 256 + c] = sb;
  }
}

// Generic MFMA node linear over type-sorted buckets.
// out = act( A[n][0..K) @ WT[t]^T + bias[t] ); ACT: 0 tanh, 1 none, 2 blend.
template<int K, int ACT, bool AHALF>
__global__ __launch_bounds__(256) void k_ngemm(
    const float* __restrict__ Af, const u16* __restrict__ Ah,
    const u16* __restrict__ WT, const float* __restrict__ bias,
    const int* __restrict__ nsorted, const int* __restrict__ nal,
    const float* __restrict__ skip_l,
    float* __restrict__ out_f, u16* __restrict__ out_h,
    const float* __restrict__ xin) {
  int tile0 = blockIdx.x * 64;
  if (tile0 >= nal[3]) return;
  int t = 0;
  #pragma unroll
  for (int i = 1; i < 3; i++) t += (tile0 >= nal[i]);

  __shared__ __align__(16) u16 ab[64 * K];   // f16, XOR-swizzled rows (G4)
  __shared__ int s_nid[64];
  int tid = threadIdx.x;
  int lane = tid & 63, w = tid >> 6;
  int l15 = lane & 15, l4 = lane >> 4;

  if (tid < 64) s_nid[tid] = nsorted[tile0 + tid];
  __syncthreads();

  { // stage: thread (row=tid>>2, quarter=tid&3) -> K/4 elements -> f16 LDS
    int r = tid >> 2, q4 = tid & 3;
    int nid = s_nid[r];
    char* rowp = (char*)ab + r * (2 * K);
    int sw = (r & 7) << 4;
    int base = q4 * (K / 2);               // byte base within row
    if (nid >= 0) {
      if (AHALF) {
        const f16x8* ap = (const f16x8*)(Ah + (size_t)nid * K + q4 * (K / 4));
        #pragma unroll
        for (int i = 0; i < K / 32; i++)
          *(f16x8*)(rowp + ((base + 16 * i) ^ sw)) = ap[i];
      } else {
        const float4* ap = (const float4*)(Af + (size_t)nid * K + q4 * (K / 4));
        #pragma unroll
        for (int i = 0; i < K / 32; i++) {
          float4 a = ap[2 * i], a2 = ap[2 * i + 1];
          f16x8 hv;
          hv[0] = (f16)a.x;  hv[1] = (f16)a.y;  hv[2] = (f16)a.z;  hv[3] = (f16)a.w;
          hv[4] = (f16)a2.x; hv[5] = (f16)a2.y; hv[6] = (f16)a2.z; hv[7] = (f16)a2.w;
          *(f16x8*)(rowp + ((base + 16 * i) ^ sw)) = hv;
        }
      }
    } else {
      f16x8 z;
      #pragma unroll
      for (int j = 0; j < 8; j++) z[j] = (f16)0.f;
      #pragma unroll
      for (int i = 0; i < K / 32; i++)
        *(f16x8*)(rowp + ((base + 16 * i) ^ sw)) = z;
    }
  }
  __syncthreads();

  f32x4 acc[4][2];
  #pragma unroll
  for (int ni = 0; ni < 2; ni++) {
    float bc = bias[t * HD + w * 32 + ni * 16 + l15];
    #pragma unroll
    for (int mi = 0; mi < 4; mi++) {
      acc[mi][ni][0] = bc; acc[mi][ni][1] = bc;
      acc[mi][ni][2] = bc; acc[mi][ni][3] = bc;
    }
  }
  const u16* Wt = WT + (size_t)t * HD * K;
  #pragma unroll
  for (int ks = 0; ks < K / 32; ks++) {
    int k0 = ks * 32 + 8 * l4;
    f16x8 bf[2], af[4];
    #pragma unroll
    for (int ni = 0; ni < 2; ni++)
      bf[ni] = *(const f16x8*)(Wt + (size_t)(w * 32 + ni * 16 + l15) * K + k0);
    #pragma unroll
    for (int mi = 0; mi < 4; mi++) {
      int row = mi * 16 + l15;
      af[mi] = *(const f16x8*)((const char*)ab + row * (2 * K) +
                               ((2 * k0) ^ ((row & 7) << 4)));
    }
    #pragma unroll
    for (int mi = 0; mi < 4; mi++)
      #pragma unroll
      for (int ni = 0; ni < 2; ni++)
        acc[mi][ni] = __builtin_amdgcn_mfma_f32_16x16x32_f16(af[mi], bf[ni],
                                                             acc[mi][ni], 0, 0, 0);
  }

  float alpha = 0.f;
  if (ACT == 2) alpha = 1.f / (1.f + expf(-skip_l[t]));
  #pragma unroll
  for (int mi = 0; mi < 4; mi++)
    #pragma unroll
    for (int r = 0; r < 4; r++) {
      int rowl = mi * 16 + l4 * 4 + r;
      int nid = s_nid[rowl];
      if (nid >= 0) {
        #pragma unroll
        for (int ni = 0; ni < 2; ni++) {
          int c = w * 32 + ni * 16 + l15;
          float val = acc[mi][ni][r];
          if (ACT == 0) val = tanhf(val);
          if (ACT == 2) {
            float xo = xin[(size_t)nid * HD + c];
            val = val * alpha + xo * (1.f - alpha);
          }
          if (out_f) out_f[(size_t)nid * HD + c] = val;
          if (out_h) out_h[(size_t)nid * HD + c] =
              __builtin_bit_cast(u16, (f16)val);
        }
      }
    }
}

// MFMA edge kernel, f16 gathers. 512 threads / 8 waves; wave w owns combined
// cols [w*32, w*32+32): w<4 -> k' (to LDS for scores), w>=4 -> v' (to global).
// R13: score-phase q_h[dst]/ntype[dst] gathers issue right after barrier 1 ->
// latency hides under staging adds + MFMA + k'/v' writes. launch_bounds(512,8)
// pins the 64-VGPR occupancy bucket (8 waves/SIMD).
__global__ __launch_bounds__(512, 8) void k_edge_gemm(
    const u16* __restrict__ x_h, const u16* __restrict__ rte_h,
    const u16* __restrict__ Wcomb, const float* __restrict__ bcomb,
    const u16* __restrict__ q_h, const int* __restrict__ esorted,
    const int* __restrict__ bal, const int* __restrict__ src,
    const int* __restrict__ dst, const int* __restrict__ etime,
    const int* __restrict__ ntype, const int* __restrict__ rank,
    const float* __restrict__ pri_l,
    u16* __restrict__ score_h, u16* __restrict__ v_csr) {
  int tile0 = blockIdx.x * 64;
  if (tile0 >= bal[12]) return;
  int b = 0;
  #pragma unroll
  for (int i = 1; i < 12; i++) b += (tile0 >= bal[i]);
  int st = b >> 2, rt = b & 3;

  __shared__ __align__(16) u16 albuf[64 * HD];   // 16 KB
  __shared__ int s_eid[64];
  __shared__ int s_dst[64];
  __shared__ int s_rank[64];
  int tid = threadIdx.x;
  int lane = tid & 63, w = tid >> 6;
  int l15 = lane & 15, l4 = lane >> 4;
  int r8 = tid >> 3, h8 = tid & 7;

  if (tid < 64) {
    int e = esorted[tile0 + tid];
    s_eid[tid] = e;
    s_dst[tid] = (e >= 0) ? dst[e] : 0;
    s_rank[tid] = (e >= 0) ? rank[e] : 0;
  }
  __syncthreads();

  // R13 prefetch: this thread's score task is (edge r8, head h8). Issue the
  // q/ntype gathers NOW; they drain during staging + MFMA + writes.
  int c_en = s_eid[r8];
  int c_rk = s_rank[r8];
  int c_d  = s_dst[r8];
  int c_tt = ntype[c_d];
  const f16x8* qp = (const f16x8*)(q_h + (size_t)c_d * HD + h8 * 16);
  f16x8 cqa = qp[0], cqb = qp[1];

  { // stage: row = tid>>3, part = tid&7 -> 16 f16 each (2x 16B gathers)
    int e = c_en;
    char* rowp = (char*)albuf + r8 * 256;
    int sw = (r8 & 7) << 4;
    if (e >= 0) {
      const f16x8* xs = (const f16x8*)(x_h + (size_t)src[e] * HD + h8 * 16);
      const f16x8* rp = (const f16x8*)(rte_h + (size_t)etime[e] * HD + h8 * 16);
      f16x8 h0 = xs[0] + rp[0];
      f16x8 h1 = xs[1] + rp[1];
      *(f16x8*)(rowp + ((h8 * 32) ^ sw))      = h0;
      *(f16x8*)(rowp + ((h8 * 32 + 16) ^ sw)) = h1;
    } else {
      f16x8 z;
      #pragma unroll
      for (int j = 0; j < 8; j++) z[j] = (f16)0.f;
      *(f16x8*)(rowp + ((h8 * 32) ^ sw))      = z;
      *(f16x8*)(rowp + ((h8 * 32 + 16) ^ sw)) = z;
    }
  }
  __syncthreads();

  f32x4 acc[4][2];
  #pragma unroll
  for (int ni = 0; ni < 2; ni++) {
    float bc = bcomb[b * 256 + w * 32 + ni * 16 + l15];
    #pragma unroll
    for (int mi = 0; mi < 4; mi++) {
      acc[mi][ni][0] = bc; acc[mi][ni][1] = bc;
      acc[mi][ni][2] = bc; acc[mi][ni][3] = bc;
    }
  }
  const u16* Wb = Wcomb + (size_t)b * 256 * HD;
  #pragma unroll
  for (int ks = 0; ks < 4; ks++) {
    int k0 = ks * 32 + 8 * l4;
    f16x8 bf[2], af[4];
    #pragma unroll
    for (int ni = 0; ni < 2; ni++)
      bf[ni] = *(const f16x8*)(Wb + (size_t)(w * 32 + ni * 16 + l15) * HD + k0);
    #pragma unroll
    for (int mi = 0; mi < 4; mi++) {
      int row = mi * 16 + l15;
      af[mi] = *(const f16x8*)((const char*)albuf + row * 256 +
                               ((2 * k0) ^ ((row & 7) << 4)));
    }
    #pragma unroll
    for (int mi = 0; mi < 4; mi++)
      #pragma unroll
      for (int ni = 0; ni < 2; ni++)
        acc[mi][ni] = __builtin_amdgcn_mfma_f32_16x16x32_f16(af[mi], bf[ni],
                                                             acc[mi][ni], 0, 0, 0);
  }
  __syncthreads();

  if (w < 4) {       // k' cols [w*32, w*32+32) -> albuf f16 (swizzled)
    #pragma unroll
    for (int mi = 0; mi < 4; mi++)
      #pragma unroll
      for (int r = 0; r < 4; r++) {
        int row = mi * 16 + l4 * 4 + r;
        char* rowp = (char*)albuf + row * 256;
        int sw = (row & 7) << 4;
        #pragma unroll
        for (int ni = 0; ni < 2; ni++) {
          int c = w * 32 + ni * 16 + l15;
          *(u16*)(rowp + ((2 * c) ^ sw)) =
              __builtin_bit_cast(u16, (f16)acc[mi][ni][r]);
        }
      }
  } else {           // v' cols [(w-4)*32, ..) -> v_csr[rank] f16
    int wv = w - 4;
    #pragma unroll
    for (int mi = 0; mi < 4; mi++)
      #pragma unroll
      for (int r = 0; r < 4; r++) {
        int rowl = mi * 16 + l4 * 4 + r;
        if (s_eid[rowl] >= 0) {
          u16* vp = v_csr + (size_t)s_rank[rowl] * HD + wv * 32 + l15;
          #pragma unroll
          for (int ni = 0; ni < 2; ni++)
            vp[ni * 16] = __builtin_bit_cast(u16, (f16)acc[mi][ni][r]);
        }
      }
  }
  __syncthreads();

  // scores: thread's task = (edge r8, head h8); q/tt/rk were prefetched
  if (c_en >= 0) {
    const char* rowp = (const char*)albuf + r8 * 256;
    int sw = (r8 & 7) << 4;
    f16x8 kh0 = *(const f16x8*)(rowp + ((h8 * 32) ^ sw));
    f16x8 kh1 = *(const f16x8*)(rowp + ((h8 * 32 + 16) ^ sw));
    float sc = 0.f;
    #pragma unroll
    for (int j = 0; j < 8; j++) sc += (float)cqa[j] * (float)kh0[j];
    #pragma unroll
    for (int j = 0; j < 8; j++) sc += (float)cqb[j] * (float)kh1[j];
    float pri = pri_l[((c_tt * R_N + rt) * T_N + st) * NH + h8];
    score_h[(size_t)c_rk * NH + h8] =
        __builtin_bit_cast(u16, (f16)(sc * pri * 0.25f));
  }
}

// Per-node (1 wave): segment softmax + weighted v-sum + exact GELU -> g (f16).
__global__ void k_aggr(const int* __restrict__ row_ptr,
                       const u16* __restrict__ score_h,
                       const u16* __restrict__ v_csr,
                       u16* __restrict__ g_h, int N) {
  int n = blockIdx.x;
  int lane = threadIdx.x;
  int start = row_ptr[n], end = row_ptr[n + 1];

  int h = lane & 7, jj = lane >> 3;
  float m = -3.0e38f;
  for (int idx = start + jj; idx < end; idx += 8)
    m = fmaxf(m, (float)__builtin_bit_cast(f16, score_h[(size_t)idx * NH + h]));
  #pragma unroll
  for (int off = 8; off < 64; off <<= 1) m = fmaxf(m, __shfl_xor(m, off));
  float z = 0.f;
  for (int idx = start + jj; idx < end; idx += 8)
    z += expf((float)__builtin_bit_cast(f16, score_h[(size_t)idx * NH + h]) - m);
  #pragma unroll
  for (int off = 8; off < 64; off <<= 1) z += __shfl_xor(z, off);

  int myh = lane >> 3;
  float md = __shfl(m, myh);
  float zd = __shfl(z, myh);
  float rz = (zd > 0.f) ? 1.f / zd : 0.f;

  float a0 = 0.f, a1 = 0.f;
  for (int idx = start; idx < end; idx++) {
    float sc = (float)__builtin_bit_cast(f16, score_h[(size_t)idx * NH + myh]);
    float wgt = expf(sc - md) * rz;
    u32 v2 = ((const u32*)(v_csr + (size_t)idx * HD))[lane];
    float v0 = (float)__builtin_bit_cast(f16, (u16)(v2 & 0xffffu));
    float v1 = (float)__builtin_bit_cast(f16, (u16)(v2 >> 16));
    a0 = fmaf(wgt, v0, a0);
    a1 = fmaf(wgt, v1, a1);
  }

  a0 = 0.5f * a0 * (1.f + erff(a0 * 0.7071067811865475f));
  a1 = 0.5f * a1 * (1.f + erff(a1 * 0.7071067811865475f));
  u32 pk = (u32)__builtin_bit_cast(u16, (f16)a0)
         | ((u32)__builtin_bit_cast(u16, (f16)a1) << 16);
  ((u32*)(g_h + (size_t)n * HD))[lane] = pk;
}

}  // namespace

extern "C" void kernel_launch(void* const* d_in, const int* in_sizes, int n_in,
                              void* d_out, int out_size, void* d_ws, size_t ws_size,
                              hipStream_t stream) {
  const float* node_feature = (const float*)d_in[0];
  const int*   node_type    = (const int*)d_in[1];
  const int*   edge_time    = (const int*)d_in[2];
  const int*   edge_type    = (const int*)d_in[3];
  const int*   edge_index   = (const int*)d_in[4];
  const float* adapt_W      = (const float*)d_in[5];
  const float* adapt_b      = (const float*)d_in[6];
  const float* Wk           = (const float*)d_in[7];
  const float* bk           = (const float*)d_in[8];
  const float* Wq           = (const float*)d_in[9];
  const float* bq           = (const float*)d_in[10];
  const float* Wv           = (const float*)d_in[11];
  const float* bv           = (const float*)d_in[12];
  const float* Wa           = (const float*)d_in[13];
  const float* ba           = (const float*)d_in[14];
  const float* rel_pri      = (const float*)d_in[15];
  const float* rel_att      = (const float*)d_in[16];
  const float* rel_msg      = (const float*)d_in[17];
  const float* skip         = (const float*)d_in[18];
  const float* rte_emb      = (const float*)d_in[19];
  const float* rte_W        = (const float*)d_in[20];
  const float* rte_b        = (const float*)d_in[21];

  const int N = in_sizes[1];
  const int E = in_sizes[2];
  const int* src  = edge_index;
  const int* dstp = edge_index + E;

  float* x = (float*)d_out;

  size_t off = 0;
  auto carve = [&](size_t bytes) -> void* {
    void* p = (char*)d_ws + off;
    off += (bytes + 255) & ~(size_t)255;
    return p;
  };
  // ~252 MB total (R8's 290MB crashed; stay under 256MiB).
  u16*   v_csr   = (u16*)  carve((size_t)E * HD * 2);   // 204.8 MB, CSR-perm
  u16*   score_h = (u16*)  carve((size_t)E * NH * 2);   // 12.8 MB, CSR-perm
  u16*   x_h     = (u16*)  carve((size_t)N * HD * 2);   // 12.8 MB
  u16*   qg      = (u16*)  carve((size_t)N * HD * 2);   // 12.8 MB: q_h then g_h
  u16*   rte_h   = (u16*)  carve((size_t)MAXT * HD * 2);
  u16*   Wcomb   = (u16*)  carve((size_t)12 * 256 * HD * 2);
  float* bcomb   = (float*)carve((size_t)12 * 256 * 4);
  u16*   adaptWT = (u16*)  carve((size_t)T_N * HD * IND * 2);
  u16*   WqT     = (u16*)  carve((size_t)2 * T_N * HD * HD * 2);
  u16*   WaT     = (u16*)  carve((size_t)2 * T_N * HD * HD * 2);
  int*   row_ptr = (int*)  carve((size_t)(N + 1) * 4);
  int*   cnt     = (int*)  carve((size_t)(N + 1) * 4);
  int*   rank    = (int*)  carve((size_t)E * 4);
  int*   bsums   = (int*)  carve(1024 * 4);
  int*   bcnt    = (int*)  carve(16 * 4);
  int*   bal     = (int*)  carve(16 * 4);
  int*   bcur    = (int*)  carve(16 * 4);
  int*   ncnt    = (int*)  carve(16 * 4);
  int*   nal     = (int*)  carve(16 * 4);
  int*   ncur    = (int*)  carve(16 * 4);
  const int EP = E + 12 * 64;
  const int NP = N + 3 * 64;
  int*   esorted = (int*)  carve((size_t)EP * 4);
  int*   nsorted = (int*)  carve((size_t)NP * 4);
  (void)ws_size; (void)n_in; (void)out_size;

  const int gE  = (E + 255) / 256;
  const int gN1 = (N + 1 + 255) / 256;
  const int gN  = (N + 255) / 256;
  const int gEP = (EP + 255) / 256;
  const int gNP = (NP + 255) / 256;
  const int etiles = (EP + 63) / 64;
  const int ntiles = (NP + 63) / 64;

  // CSR row_ptr + rank permutation (dst order)
  k_fill_i32<<<gN1, 256, 0, stream>>>(cnt, 0, N + 1);
  k_hist_dst<<<gE, 256, 0, stream>>>(dstp, cnt, E);
  k_scan_a<<<gN1, 256, 0, stream>>>(cnt, row_ptr, bsums, N + 1);
  k_scan_b<<<1, 256, 0, stream>>>(bsums, gN1);
  k_scan_c<<<gN1, 256, 0, stream>>>(row_ptr, bsums, N + 1);
  k_copy_i32<<<gN, 256, 0, stream>>>(cnt, row_ptr, N);
  k_rank_dst<<<gE, 256, 0, stream>>>(dstp, cnt, rank, E);

  // edge (src_type, rel_type) buckets (original order within bucket)
  k_fill_i32<<<1, 256, 0, stream>>>(bcnt, 0, 16);
  k_bhist<<<gE, 256, 0, stream>>>(src, edge_type, node_type, bcnt, E);
  k_bscan<<<1, 64, 0, stream>>>(bcnt, bal, bcur);
  k_fill_i32<<<gEP, 256, 0, stream>>>(esorted, -1, EP);
  k_bscatter<<<gE, 256, 0, stream>>>(src, edge_type, node_type, bcur, esorted, E);

  // node type buckets
  k_fill_i32<<<1, 256, 0, stream>>>(ncnt, 0, 16);
  k_nhist<<<gN, 256, 0, stream>>>(node_type, ncnt, N);
  k_nscan<<<1, 64, 0, stream>>>(ncnt, nal, ncur);
  k_fill_i32<<<gNP, 256, 0, stream>>>(nsorted, -1, NP);
  k_nscatter<<<gN, 256, 0, stream>>>(node_type, ncur, nsorted, N);

  // f16 transposed weights
  k_transp<<<dim3(HD, T_N), 128, 0, stream>>>(adapt_W, adaptWT, IND, HD);
  for (int l = 0; l < 2; l++) {
    k_transp<<<dim3(HD, T_N), 128, 0, stream>>>(
        Wq + (size_t)l * T_N * HD * HD, WqT + (size_t)l * T_N * HD * HD, HD, HD);
    k_transp<<<dim3(HD, T_N), 128, 0, stream>>>(
        Wa + (size_t)l * T_N * HD * HD, WaT + (size_t)l * T_N * HD * HD, HD, HD);
  }

  // adapt: x = tanh(node_feature @ adapt_W[t] + adapt_b[t]); also x_h mirror
  k_ngemm<IND, 0, false><<<ntiles, 256, 0, stream>>>(
      node_feature, nullptr, adaptWT, adapt_b, nsorted, nal, nullptr,
      x, x_h, nullptr);

  for (int l = 0; l < 2; l++) {
    k_rte<<<MAXT, 64, 0, stream>>>(rte_emb, rte_W, rte_b, rte_h, l);
    k_wcomb<<<12 * 256, 128, 0, stream>>>(Wk, Wv, bk, bv, rel_att, rel_msg,
                                          Wcomb, bcomb, l);
    // q (f16 -> qg), input from x_h
    k_ngemm<HD, 1, true><<<ntiles, 256, 0, stream>>>(
        nullptr, x_h, WqT + (size_t)l * T_N * HD * HD, bq + (size_t)l * T_N * HD,
        nsorted, nal, nullptr, nullptr, qg, nullptr);
    k_edge_gemm<<<etiles, 512, 0, stream>>>(x_h, rte_h, Wcomb, bcomb, qg,
                                            esorted, bal, src, dstp, edge_time,
                                            node_type, rank,
                                            rel_pri + (size_t)l * T_N * R_N * T_N * NH,
                                            score_h, v_csr);
    // g (f16) overwrites qg -- q_h dead after edge_gemm (stream-ordered)
    k_aggr<<<N, 64, 0, stream>>>(row_ptr, score_h, v_csr, qg, N);
    // out-linear + skip blend; reads g (f16), writes x fp32 + x_h mirror
    k_ngemm<HD, 2, true><<<ntiles, 256, 0, stream>>>(
        nullptr, qg, WaT + (size_t)l * T_N * HD * HD, ba + (size_t)l * T_N * HD,
        nsorted, nal, skip + (size_t)l * T_N, x, x_h, x);
  }
}

// Round 14
// 946.719 us; speedup vs baseline: 1.2142x; 1.2142x over previous
//
#include <hip/hip_runtime.h>
#include <cstdint>
#include <cstddef>

// HGT forward (2 layers) on MI355X.
// R13 -> R14: R13's launch_bounds(512,8) pin forced 32 VGPR -> prefetch state
// spilled to scratch (WRITE 225->725MB, FETCH 258->526MB, dur 187->297us).
// R14 = same occupancy-neutral q-prefetch, but launch_bounds(512) only: the
// compiler allocates ~52-64 VGPR, no spill, occupancy ~R11. Clean A/B of the
// prefetch vs R11. Math bit-identical: absmax must stay 2.441406e-4.

namespace {

constexpr int T_N  = 3;
constexpr int R_N  = 4;
constexpr int HD   = 128;
constexpr int IND  = 256;
constexpr int NH   = 8;
constexpr int MAXT = 240;

typedef unsigned short u16;
typedef unsigned int   u32;
typedef _Float16 f16;
typedef __attribute__((ext_vector_type(8))) _Float16 f16x8;
typedef __attribute__((ext_vector_type(4))) float    f32x4;

// ----------------------------- utility kernels -----------------------------
__global__ void k_fill_i32(int* __restrict__ p, int v, int n) {
  int i = blockIdx.x * 256 + threadIdx.x;
  if (i < n) p[i] = v;
}
__global__ void k_copy_i32(int* __restrict__ d, const int* __restrict__ s, int n) {
  int i = blockIdx.x * 256 + threadIdx.x;
  if (i < n) d[i] = s[i];
}
__global__ void k_hist_dst(const int* __restrict__ dst, int* __restrict__ cnt, int E) {
  int i = blockIdx.x * 256 + threadIdx.x;
  if (i < E) atomicAdd(&cnt[dst[i]], 1);
}
__global__ void k_scan_a(const int* __restrict__ in, int* __restrict__ out,
                         int* __restrict__ bsums, int n) {
  __shared__ int s[256];
  int gid = blockIdx.x * 256 + threadIdx.x;
  int v = (gid < n) ? in[gid] : 0;
  s[threadIdx.x] = v;
  __syncthreads();
  for (int off = 1; off < 256; off <<= 1) {
    int t = (threadIdx.x >= off) ? s[threadIdx.x - off] : 0;
    __syncthreads();
    s[threadIdx.x] += t;
    __syncthreads();
  }
  if (gid < n) out[gid] = s[threadIdx.x] - v;
  if (threadIdx.x == 255) bsums[blockIdx.x] = s[255];
}
__global__ void k_scan_b(int* __restrict__ bsums, int nb) {
  __shared__ int s[256];
  int v = (threadIdx.x < nb) ? bsums[threadIdx.x] : 0;
  s[threadIdx.x] = v;
  __syncthreads();
  for (int off = 1; off < 256; off <<= 1) {
    int t = (threadIdx.x >= off) ? s[threadIdx.x - off] : 0;
    __syncthreads();
    s[threadIdx.x] += t;
    __syncthreads();
  }
  if (threadIdx.x < nb) bsums[threadIdx.x] = s[threadIdx.x] - v;
}
__global__ void k_scan_c(int* __restrict__ out, const int* __restrict__ bsums, int n) {
  int gid = blockIdx.x * 256 + threadIdx.x;
  if (gid < n) out[gid] += bsums[blockIdx.x];
}
// rank[e] = position of edge e in the dst-CSR ordering
__global__ void k_rank_dst(const int* __restrict__ dst, int* __restrict__ cur,
                           int* __restrict__ rank, int E) {
  int i = blockIdx.x * 256 + threadIdx.x;
  if (i < E) rank[i] = atomicAdd(&cur[dst[i]], 1);
}
__global__ void k_bhist(const int* __restrict__ src, const int* __restrict__ etype,
                        const int* __restrict__ ntype, int* __restrict__ bcnt, int E) {
  __shared__ int loc[12];
  if (threadIdx.x < 12) loc[threadIdx.x] = 0;
  __syncthreads();
  int i = blockIdx.x * 256 + threadIdx.x;
  if (i < E) {
    int b = ntype[src[i]] * R_N + etype[i];
    atomicAdd(&loc[b], 1);
  }
  __syncthreads();
  if (threadIdx.x < 12) atomicAdd(&bcnt[threadIdx.x], loc[threadIdx.x]);
}
__global__ void k_bscan(const int* __restrict__ bcnt, int* __restrict__ bal,
                        int* __restrict__ bcur) {
  if (threadIdx.x == 0 && blockIdx.x == 0) {
    int run = 0;
    for (int b = 0; b < 12; b++) {
      bal[b] = run;
      bcur[b] = run;
      run += (bcnt[b] + 63) & ~63;
    }
    bal[12] = run;
  }
}
__global__ void k_bscatter(const int* __restrict__ src, const int* __restrict__ etype,
                           const int* __restrict__ ntype, int* __restrict__ bcur,
                           int* __restrict__ esorted, int E) {
  __shared__ int loc[12];
  __shared__ int base[12];
  if (threadIdx.x < 12) loc[threadIdx.x] = 0;
  __syncthreads();
  int i = blockIdx.x * 256 + threadIdx.x;
  int b = 0, lpos = 0;
  if (i < E) {
    b = ntype[src[i]] * R_N + etype[i];
    lpos = atomicAdd(&loc[b], 1);
  }
  __syncthreads();
  if (threadIdx.x < 12) {
    int c = loc[threadIdx.x];
    base[threadIdx.x] = (c > 0) ? atomicAdd(&bcur[threadIdx.x], c) : 0;
  }
  __syncthreads();
  if (i < E) esorted[base[b] + lpos] = i;
}
// node-type buckets (3), 64-aligned
__global__ void k_nhist(const int* __restrict__ ntype, int* __restrict__ ncnt, int N) {
  __shared__ int loc[3];
  if (threadIdx.x < 3) loc[threadIdx.x] = 0;
  __syncthreads();
  int i = blockIdx.x * 256 + threadIdx.x;
  if (i < N) atomicAdd(&loc[ntype[i]], 1);
  __syncthreads();
  if (threadIdx.x < 3) atomicAdd(&ncnt[threadIdx.x], loc[threadIdx.x]);
}
__global__ void k_nscan(const int* __restrict__ ncnt, int* __restrict__ nal,
                        int* __restrict__ ncur) {
  if (threadIdx.x == 0 && blockIdx.x == 0) {
    int run = 0;
    for (int t = 0; t < 3; t++) {
      nal[t] = run;
      ncur[t] = run;
      run += (ncnt[t] + 63) & ~63;
    }
    nal[3] = run;
  }
}
__global__ void k_nscatter(const int* __restrict__ ntype, int* __restrict__ ncur,
                           int* __restrict__ nsorted, int N) {
  __shared__ int loc[3];
  __shared__ int base[3];
  if (threadIdx.x < 3) loc[threadIdx.x] = 0;
  __syncthreads();
  int i = blockIdx.x * 256 + threadIdx.x;
  int t = 0, lpos = 0;
  if (i < N) {
    t = ntype[i];
    lpos = atomicAdd(&loc[t], 1);
  }
  __syncthreads();
  if (threadIdx.x < 3) {
    int c = loc[threadIdx.x];
    base[threadIdx.x] = (c > 0) ? atomicAdd(&ncur[threadIdx.x], c) : 0;
  }
  __syncthreads();
  if (i < N) nsorted[base[t] + lpos] = i;
}

// transpose+f16: src [T][Kd][Cd] fp32 -> dst [T][Cd][Kd] f16 (k contiguous)
__global__ void k_transp(const float* __restrict__ src, u16* __restrict__ dst,
                         int Kd, int Cd) {
  int c = blockIdx.x;
  int t = blockIdx.y;
  for (int k = threadIdx.x; k < Kd; k += blockDim.x)
    dst[((size_t)t * Cd + c) * Kd + k] =
        __builtin_bit_cast(u16, (f16)src[((size_t)t * Kd + k) * Cd + c]);
}

// ------------------------------ math kernels -------------------------------
// rte table -> f16 [240][128]
__global__ void k_rte(const float* __restrict__ emb, const float* __restrict__ W,
                      const float* __restrict__ bias, u16* __restrict__ out, int l) {
  int t = blockIdx.x;
  int lane = threadIdx.x;
  __shared__ __align__(16) float s[2 * HD];
  ((float4*)s)[lane] = ((const float4*)(emb + (size_t)t * 2 * HD))[lane];
  __syncthreads();
  const float* Wl = W + (size_t)l * 2 * HD * HD;
  float o0 = bias[l * HD + 2 * lane];
  float o1 = bias[l * HD + 2 * lane + 1];
  #pragma unroll 4
  for (int k = 0; k < 2 * HD; k++) {
    float xv = s[k];
    float2 w = ((const float2*)(Wl + (size_t)k * HD))[lane];
    o0 = fmaf(xv, w.x, o0);
    o1 = fmaf(xv, w.y, o1);
  }
  u32 pk = (u32)__builtin_bit_cast(u16, (f16)o0)
         | ((u32)__builtin_bit_cast(u16, (f16)o1) << 16);
  ((u32*)out)[t * 64 + lane] = pk;
}

// Combined per-(type,rel) matrices, f16, stored [b][c][k] (k contiguous)
__global__ void k_wcomb(const float* __restrict__ Wk, const float* __restrict__ Wv,
                        const float* __restrict__ bk, const float* __restrict__ bv,
                        const float* __restrict__ Ratt, const float* __restrict__ Rmsg,
                        u16* __restrict__ Wcomb, float* __restrict__ bcomb, int l) {
  int bc = blockIdx.x;
  int b  = bc >> 8;
  int c  = bc & 255;
  int st = b >> 2, rt = b & 3;
  int k  = threadIdx.x;
  bool isv = (c >= HD);
  int c0 = isv ? c - HD : c;
  int h  = c0 >> 4, cc = c0 & 15;
  const float* W = (isv ? Wv : Wk) + (((size_t)(l * T_N + st) * HD) + k) * HD + h * 16;
  const float* A = (isv ? Rmsg : Ratt) + (((size_t)(l * R_N + rt) * NH + h) * 16) * 16 + cc;
  float s = 0.f;
  #pragma unroll
  for (int d = 0; d < 16; d++) s = fmaf(W[d], A[d * 16], s);
  Wcomb[((size_t)b * 256 + c) * HD + k] = __builtin_bit_cast(u16, (f16)s);
  if (k == 0) {
    const float* bb = (isv ? bv : bk) + (size_t)(l * T_N + st) * HD + h * 16;
    float sb = 0.f;
    #pragma unroll
    for (int d = 0; d < 16; d++) sb = fmaf(bb[d], A[d * 16], sb);
    bcomb[b * 256 + c] = sb;
  }
}

// Generic MFMA node linear over type-sorted buckets.
// out = act( A[n][0..K) @ WT[t]^T + bias[t] ); ACT: 0 tanh, 1 none, 2 blend.
template<int K, int ACT, bool AHALF>
__global__ __launch_bounds__(256) void k_ngemm(
    const float* __restrict__ Af, const u16* __restrict__ Ah,
    const u16* __restrict__ WT, const float* __restrict__ bias,
    const int* __restrict__ nsorted, const int* __restrict__ nal,
    const float* __restrict__ skip_l,
    float* __restrict__ out_f, u16* __restrict__ out_h,
    const float* __restrict__ xin) {
  int tile0 = blockIdx.x * 64;
  if (tile0 >= nal[3]) return;
  int t = 0;
  #pragma unroll
  for (int i = 1; i < 3; i++) t += (tile0 >= nal[i]);

  __shared__ __align__(16) u16 ab[64 * K];   // f16, XOR-swizzled rows (G4)
  __shared__ int s_nid[64];
  int tid = threadIdx.x;
  int lane = tid & 63, w = tid >> 6;
  int l15 = lane & 15, l4 = lane >> 4;

  if (tid < 64) s_nid[tid] = nsorted[tile0 + tid];
  __syncthreads();

  { // stage: thread (row=tid>>2, quarter=tid&3) -> K/4 elements -> f16 LDS
    int r = tid >> 2, q4 = tid & 3;
    int nid = s_nid[r];
    char* rowp = (char*)ab + r * (2 * K);
    int sw = (r & 7) << 4;
    int base = q4 * (K / 2);               // byte base within row
    if (nid >= 0) {
      if (AHALF) {
        const f16x8* ap = (const f16x8*)(Ah + (size_t)nid * K + q4 * (K / 4));
        #pragma unroll
        for (int i = 0; i < K / 32; i++)
          *(f16x8*)(rowp + ((base + 16 * i) ^ sw)) = ap[i];
      } else {
        const float4* ap = (const float4*)(Af + (size_t)nid * K + q4 * (K / 4));
        #pragma unroll
        for (int i = 0; i < K / 32; i++) {
          float4 a = ap[2 * i], a2 = ap[2 * i + 1];
          f16x8 hv;
          hv[0] = (f16)a.x;  hv[1] = (f16)a.y;  hv[2] = (f16)a.z;  hv[3] = (f16)a.w;
          hv[4] = (f16)a2.x; hv[5] = (f16)a2.y; hv[6] = (f16)a2.z; hv[7] = (f16)a2.w;
          *(f16x8*)(rowp + ((base + 16 * i) ^ sw)) = hv;
        }
      }
    } else {
      f16x8 z;
      #pragma unroll
      for (int j = 0; j < 8; j++) z[j] = (f16)0.f;
      #pragma unroll
      for (int i = 0; i < K / 32; i++)
        *(f16x8*)(rowp + ((base + 16 * i) ^ sw)) = z;
    }
  }
  __syncthreads();

  f32x4 acc[4][2];
  #pragma unroll
  for (int ni = 0; ni < 2; ni++) {
    float bc = bias[t * HD + w * 32 + ni * 16 + l15];
    #pragma unroll
    for (int mi = 0; mi < 4; mi++) {
      acc[mi][ni][0] = bc; acc[mi][ni][1] = bc;
      acc[mi][ni][2] = bc; acc[mi][ni][3] = bc;
    }
  }
  const u16* Wt = WT + (size_t)t * HD * K;
  #pragma unroll
  for (int ks = 0; ks < K / 32; ks++) {
    int k0 = ks * 32 + 8 * l4;
    f16x8 bf[2], af[4];
    #pragma unroll
    for (int ni = 0; ni < 2; ni++)
      bf[ni] = *(const f16x8*)(Wt + (size_t)(w * 32 + ni * 16 + l15) * K + k0);
    #pragma unroll
    for (int mi = 0; mi < 4; mi++) {
      int row = mi * 16 + l15;
      af[mi] = *(const f16x8*)((const char*)ab + row * (2 * K) +
                               ((2 * k0) ^ ((row & 7) << 4)));
    }
    #pragma unroll
    for (int mi = 0; mi < 4; mi++)
      #pragma unroll
      for (int ni = 0; ni < 2; ni++)
        acc[mi][ni] = __builtin_amdgcn_mfma_f32_16x16x32_f16(af[mi], bf[ni],
                                                             acc[mi][ni], 0, 0, 0);
  }

  float alpha = 0.f;
  if (ACT == 2) alpha = 1.f / (1.f + expf(-skip_l[t]));
  #pragma unroll
  for (int mi = 0; mi < 4; mi++)
    #pragma unroll
    for (int r = 0; r < 4; r++) {
      int rowl = mi * 16 + l4 * 4 + r;
      int nid = s_nid[rowl];
      if (nid >= 0) {
        #pragma unroll
        for (int ni = 0; ni < 2; ni++) {
          int c = w * 32 + ni * 16 + l15;
          float val = acc[mi][ni][r];
          if (ACT == 0) val = tanhf(val);
          if (ACT == 2) {
            float xo = xin[(size_t)nid * HD + c];
            val = val * alpha + xo * (1.f - alpha);
          }
          if (out_f) out_f[(size_t)nid * HD + c] = val;
          if (out_h) out_h[(size_t)nid * HD + c] =
              __builtin_bit_cast(u16, (f16)val);
        }
      }
    }
}

// MFMA edge kernel, f16 gathers. 512 threads / 8 waves; wave w owns combined
// cols [w*32, w*32+32): w<4 -> k' (to LDS for scores), w>=4 -> v' (to global).
// R14: score-phase q_h[dst]/ntype[dst] prefetch right after barrier 1 (as
// R13), but NO min-waves pin -> compiler picks ~52-64 VGPR, no spill.
__global__ __launch_bounds__(512) void k_edge_gemm(
    const u16* __restrict__ x_h, const u16* __restrict__ rte_h,
    const u16* __restrict__ Wcomb, const float* __restrict__ bcomb,
    const u16* __restrict__ q_h, const int* __restrict__ esorted,
    const int* __restrict__ bal, const int* __restrict__ src,
    const int* __restrict__ dst, const int* __restrict__ etime,
    const int* __restrict__ ntype, const int* __restrict__ rank,
    const float* __restrict__ pri_l,
    u16* __restrict__ score_h, u16* __restrict__ v_csr) {
  int tile0 = blockIdx.x * 64;
  if (tile0 >= bal[12]) return;
  int b = 0;
  #pragma unroll
  for (int i = 1; i < 12; i++) b += (tile0 >= bal[i]);
  int st = b >> 2, rt = b & 3;

  __shared__ __align__(16) u16 albuf[64 * HD];   // 16 KB
  __shared__ int s_eid[64];
  __shared__ int s_dst[64];
  __shared__ int s_rank[64];
  int tid = threadIdx.x;
  int lane = tid & 63, w = tid >> 6;
  int l15 = lane & 15, l4 = lane >> 4;
  int r8 = tid >> 3, h8 = tid & 7;

  if (tid < 64) {
    int e = esorted[tile0 + tid];
    s_eid[tid] = e;
    s_dst[tid] = (e >= 0) ? dst[e] : 0;
    s_rank[tid] = (e >= 0) ? rank[e] : 0;
  }
  __syncthreads();

  // prefetch for the score phase: this thread's task = (edge r8, head h8)
  int c_en = s_eid[r8];
  int c_rk = s_rank[r8];
  int c_d  = s_dst[r8];
  int c_tt = ntype[c_d];
  const f16x8* qp = (const f16x8*)(q_h + (size_t)c_d * HD + h8 * 16);
  f16x8 cqa = qp[0], cqb = qp[1];

  { // stage: row = tid>>3, part = tid&7 -> 16 f16 each (2x 16B gathers)
    char* rowp = (char*)albuf + r8 * 256;
    int sw = (r8 & 7) << 4;
    if (c_en >= 0) {
      const f16x8* xs = (const f16x8*)(x_h + (size_t)src[c_en] * HD + h8 * 16);
      const f16x8* rp = (const f16x8*)(rte_h + (size_t)etime[c_en] * HD + h8 * 16);
      f16x8 h0 = xs[0] + rp[0];
      f16x8 h1 = xs[1] + rp[1];
      *(f16x8*)(rowp + ((h8 * 32) ^ sw))      = h0;
      *(f16x8*)(rowp + ((h8 * 32 + 16) ^ sw)) = h1;
    } else {
      f16x8 z;
      #pragma unroll
      for (int j = 0; j < 8; j++) z[j] = (f16)0.f;
      *(f16x8*)(rowp + ((h8 * 32) ^ sw))      = z;
      *(f16x8*)(rowp + ((h8 * 32 + 16) ^ sw)) = z;
    }
  }
  __syncthreads();

  f32x4 acc[4][2];
  #pragma unroll
  for (int ni = 0; ni < 2; ni++) {
    float bc = bcomb[b * 256 + w * 32 + ni * 16 + l15];
    #pragma unroll
    for (int mi = 0; mi < 4; mi++) {
      acc[mi][ni][0] = bc; acc[mi][ni][1] = bc;
      acc[mi][ni][2] = bc; acc[mi][ni][3] = bc;
    }
  }
  const u16* Wb = Wcomb + (size_t)b * 256 * HD;
  #pragma unroll
  for (int ks = 0; ks < 4; ks++) {
    int k0 = ks * 32 + 8 * l4;
    f16x8 bf[2], af[4];
    #pragma unroll
    for (int ni = 0; ni < 2; ni++)
      bf[ni] = *(const f16x8*)(Wb + (size_t)(w * 32 + ni * 16 + l15) * HD + k0);
    #pragma unroll
    for (int mi = 0; mi < 4; mi++) {
      int row = mi * 16 + l15;
      af[mi] = *(const f16x8*)((const char*)albuf + row * 256 +
                               ((2 * k0) ^ ((row & 7) << 4)));
    }
    #pragma unroll
    for (int mi = 0; mi < 4; mi++)
      #pragma unroll
      for (int ni = 0; ni < 2; ni++)
        acc[mi][ni] = __builtin_amdgcn_mfma_f32_16x16x32_f16(af[mi], bf[ni],
                                                             acc[mi][ni], 0, 0, 0);
  }
  __syncthreads();

  if (w < 4) {       // k' cols [w*32, w*32+32) -> albuf f16 (swizzled)
    #pragma unroll
    for (int mi = 0; mi < 4; mi++)
      #pragma unroll
      for (int r = 0; r < 4; r++) {
        int row = mi * 16 + l4 * 4 + r;
        char* rowp = (char*)albuf + row * 256;
        int sw = (row & 7) << 4;
        #pragma unroll
        for (int ni = 0; ni < 2; ni++) {
          int c = w * 32 + ni * 16 + l15;
          *(u16*)(rowp + ((2 * c) ^ sw)) =
              __builtin_bit_cast(u16, (f16)acc[mi][ni][r]);
        }
      }
  } else {           // v' cols [(w-4)*32, ..) -> v_csr[rank] f16
    int wv = w - 4;
    #pragma unroll
    for (int mi = 0; mi < 4; mi++)
      #pragma unroll
      for (int r = 0; r < 4; r++) {
        int rowl = mi * 16 + l4 * 4 + r;
        if (s_eid[rowl] >= 0) {
          u16* vp = v_csr + (size_t)s_rank[rowl] * HD + wv * 32 + l15;
          #pragma unroll
          for (int ni = 0; ni < 2; ni++)
            vp[ni * 16] = __builtin_bit_cast(u16, (f16)acc[mi][ni][r]);
        }
      }
  }
  __syncthreads();

  // scores: thread's task = (edge r8, head h8); q/tt/rk were prefetched
  if (c_en >= 0) {
    const char* rowp = (const char*)albuf + r8 * 256;
    int sw = (r8 & 7) << 4;
    f16x8 kh0 = *(const f16x8*)(rowp + ((h8 * 32) ^ sw));
    f16x8 kh1 = *(const f16x8*)(rowp + ((h8 * 32 + 16) ^ sw));
    float sc = 0.f;
    #pragma unroll
    for (int j = 0; j < 8; j++) sc += (float)cqa[j] * (float)kh0[j];
    #pragma unroll
    for (int j = 0; j < 8; j++) sc += (float)cqb[j] * (float)kh1[j];
    float pri = pri_l[((c_tt * R_N + rt) * T_N + st) * NH + h8];
    score_h[(size_t)c_rk * NH + h8] =
        __builtin_bit_cast(u16, (f16)(sc * pri * 0.25f));
  }
}

// Per-node (1 wave): segment softmax + weighted v-sum + exact GELU -> g (f16).
__global__ void k_aggr(const int* __restrict__ row_ptr,
                       const u16* __restrict__ score_h,
                       const u16* __restrict__ v_csr,
                       u16* __restrict__ g_h, int N) {
  int n = blockIdx.x;
  int lane = threadIdx.x;
  int start = row_ptr[n], end = row_ptr[n + 1];

  int h = lane & 7, jj = lane >> 3;
  float m = -3.0e38f;
  for (int idx = start + jj; idx < end; idx += 8)
    m = fmaxf(m, (float)__builtin_bit_cast(f16, score_h[(size_t)idx * NH + h]));
  #pragma unroll
  for (int off = 8; off < 64; off <<= 1) m = fmaxf(m, __shfl_xor(m, off));
  float z = 0.f;
  for (int idx = start + jj; idx < end; idx += 8)
    z += expf((float)__builtin_bit_cast(f16, score_h[(size_t)idx * NH + h]) - m);
  #pragma unroll
  for (int off = 8; off < 64; off <<= 1) z += __shfl_xor(z, off);

  int myh = lane >> 3;
  float md = __shfl(m, myh);
  float zd = __shfl(z, myh);
  float rz = (zd > 0.f) ? 1.f / zd : 0.f;

  float a0 = 0.f, a1 = 0.f;
  for (int idx = start; idx < end; idx++) {
    float sc = (float)__builtin_bit_cast(f16, score_h[(size_t)idx * NH + myh]);
    float wgt = expf(sc - md) * rz;
    u32 v2 = ((const u32*)(v_csr + (size_t)idx * HD))[lane];
    float v0 = (float)__builtin_bit_cast(f16, (u16)(v2 & 0xffffu));
    float v1 = (float)__builtin_bit_cast(f16, (u16)(v2 >> 16));
    a0 = fmaf(wgt, v0, a0);
    a1 = fmaf(wgt, v1, a1);
  }

  a0 = 0.5f * a0 * (1.f + erff(a0 * 0.7071067811865475f));
  a1 = 0.5f * a1 * (1.f + erff(a1 * 0.7071067811865475f));
  u32 pk = (u32)__builtin_bit_cast(u16, (f16)a0)
         | ((u32)__builtin_bit_cast(u16, (f16)a1) << 16);
  ((u32*)(g_h + (size_t)n * HD))[lane] = pk;
}

}  // namespace

extern "C" void kernel_launch(void* const* d_in, const int* in_sizes, int n_in,
                              void* d_out, int out_size, void* d_ws, size_t ws_size,
                              hipStream_t stream) {
  const float* node_feature = (const float*)d_in[0];
  const int*   node_type    = (const int*)d_in[1];
  const int*   edge_time    = (const int*)d_in[2];
  const int*   edge_type    = (const int*)d_in[3];
  const int*   edge_index   = (const int*)d_in[4];
  const float* adapt_W      = (const float*)d_in[5];
  const float* adapt_b      = (const float*)d_in[6];
  const float* Wk           = (const float*)d_in[7];
  const float* bk           = (const float*)d_in[8];
  const float* Wq           = (const float*)d_in[9];
  const float* bq           = (const float*)d_in[10];
  const float* Wv           = (const float*)d_in[11];
  const float* bv           = (const float*)d_in[12];
  const float* Wa           = (const float*)d_in[13];
  const float* ba           = (const float*)d_in[14];
  const float* rel_pri      = (const float*)d_in[15];
  const float* rel_att      = (const float*)d_in[16];
  const float* rel_msg      = (const float*)d_in[17];
  const float* skip         = (const float*)d_in[18];
  const float* rte_emb      = (const float*)d_in[19];
  const float* rte_W        = (const float*)d_in[20];
  const float* rte_b        = (const float*)d_in[21];

  const int N = in_sizes[1];
  const int E = in_sizes[2];
  const int* src  = edge_index;
  const int* dstp = edge_index + E;

  float* x = (float*)d_out;

  size_t off = 0;
  auto carve = [&](size_t bytes) -> void* {
    void* p = (char*)d_ws + off;
    off += (bytes + 255) & ~(size_t)255;
    return p;
  };
  // ~252 MB total (R8's 290MB crashed; stay under 256MiB).
  u16*   v_csr   = (u16*)  carve((size_t)E * HD * 2);   // 204.8 MB, CSR-perm
  u16*   score_h = (u16*)  carve((size_t)E * NH * 2);   // 12.8 MB, CSR-perm
  u16*   x_h     = (u16*)  carve((size_t)N * HD * 2);   // 12.8 MB
  u16*   qg      = (u16*)  carve((size_t)N * HD * 2);   // 12.8 MB: q_h then g_h
  u16*   rte_h   = (u16*)  carve((size_t)MAXT * HD * 2);
  u16*   Wcomb   = (u16*)  carve((size_t)12 * 256 * HD * 2);
  float* bcomb   = (float*)carve((size_t)12 * 256 * 4);
  u16*   adaptWT = (u16*)  carve((size_t)T_N * HD * IND * 2);
  u16*   WqT     = (u16*)  carve((size_t)2 * T_N * HD * HD * 2);
  u16*   WaT     = (u16*)  carve((size_t)2 * T_N * HD * HD * 2);
  int*   row_ptr = (int*)  carve((size_t)(N + 1) * 4);
  int*   cnt     = (int*)  carve((size_t)(N + 1) * 4);
  int*   rank    = (int*)  carve((size_t)E * 4);
  int*   bsums   = (int*)  carve(1024 * 4);
  int*   bcnt    = (int*)  carve(16 * 4);
  int*   bal     = (int*)  carve(16 * 4);
  int*   bcur    = (int*)  carve(16 * 4);
  int*   ncnt    = (int*)  carve(16 * 4);
  int*   nal     = (int*)  carve(16 * 4);
  int*   ncur    = (int*)  carve(16 * 4);
  const int EP = E + 12 * 64;
  const int NP = N + 3 * 64;
  int*   esorted = (int*)  carve((size_t)EP * 4);
  int*   nsorted = (int*)  carve((size_t)NP * 4);
  (void)ws_size; (void)n_in; (void)out_size;

  const int gE  = (E + 255) / 256;
  const int gN1 = (N + 1 + 255) / 256;
  const int gN  = (N + 255) / 256;
  const int gEP = (EP + 255) / 256;
  const int gNP = (NP + 255) / 256;
  const int etiles = (EP + 63) / 64;
  const int ntiles = (NP + 63) / 64;

  // CSR row_ptr + rank permutation (dst order)
  k_fill_i32<<<gN1, 256, 0, stream>>>(cnt, 0, N + 1);
  k_hist_dst<<<gE, 256, 0, stream>>>(dstp, cnt, E);
  k_scan_a<<<gN1, 256, 0, stream>>>(cnt, row_ptr, bsums, N + 1);
  k_scan_b<<<1, 256, 0, stream>>>(bsums, gN1);
  k_scan_c<<<gN1, 256, 0, stream>>>(row_ptr, bsums, N + 1);
  k_copy_i32<<<gN, 256, 0, stream>>>(cnt, row_ptr, N);
  k_rank_dst<<<gE, 256, 0, stream>>>(dstp, cnt, rank, E);

  // edge (src_type, rel_type) buckets (original order within bucket)
  k_fill_i32<<<1, 256, 0, stream>>>(bcnt, 0, 16);
  k_bhist<<<gE, 256, 0, stream>>>(src, edge_type, node_type, bcnt, E);
  k_bscan<<<1, 64, 0, stream>>>(bcnt, bal, bcur);
  k_fill_i32<<<gEP, 256, 0, stream>>>(esorted, -1, EP);
  k_bscatter<<<gE, 256, 0, stream>>>(src, edge_type, node_type, bcur, esorted, E);

  // node type buckets
  k_fill_i32<<<1, 256, 0, stream>>>(ncnt, 0, 16);
  k_nhist<<<gN, 256, 0, stream>>>(node_type, ncnt, N);
  k_nscan<<<1, 64, 0, stream>>>(ncnt, nal, ncur);
  k_fill_i32<<<gNP, 256, 0, stream>>>(nsorted, -1, NP);
  k_nscatter<<<gN, 256, 0, stream>>>(node_type, ncur, nsorted, N);

  // f16 transposed weights
  k_transp<<<dim3(HD, T_N), 128, 0, stream>>>(adapt_W, adaptWT, IND, HD);
  for (int l = 0; l < 2; l++) {
    k_transp<<<dim3(HD, T_N), 128, 0, stream>>>(
        Wq + (size_t)l * T_N * HD * HD, WqT + (size_t)l * T_N * HD * HD, HD, HD);
    k_transp<<<dim3(HD, T_N), 128, 0, stream>>>(
        Wa + (size_t)l * T_N * HD * HD, WaT + (size_t)l * T_N * HD * HD, HD, HD);
  }

  // adapt: x = tanh(node_feature @ adapt_W[t] + adapt_b[t]); also x_h mirror
  k_ngemm<IND, 0, false><<<ntiles, 256, 0, stream>>>(
      node_feature, nullptr, adaptWT, adapt_b, nsorted, nal, nullptr,
      x, x_h, nullptr);

  for (int l = 0; l < 2; l++) {
    k_rte<<<MAXT, 64, 0, stream>>>(rte_emb, rte_W, rte_b, rte_h, l);
    k_wcomb<<<12 * 256, 128, 0, stream>>>(Wk, Wv, bk, bv, rel_att, rel_msg,
                                          Wcomb, bcomb, l);
    // q (f16 -> qg), input from x_h
    k_ngemm<HD, 1, true><<<ntiles, 256, 0, stream>>>(
        nullptr, x_h, WqT + (size_t)l * T_N * HD * HD, bq + (size_t)l * T_N * HD,
        nsorted, nal, nullptr, nullptr, qg, nullptr);
    k_edge_gemm<<<etiles, 512, 0, stream>>>(x_h, rte_h, Wcomb, bcomb, qg,
                                            esorted, bal, src, dstp, edge_time,
                                            node_type, rank,
                                            rel_pri + (size_t)l * T_N * R_N * T_N * NH,
                                            score_h, v_csr);
    // g (f16) overwrites qg -- q_h dead after edge_gemm (stream-ordered)
    k_aggr<<<N, 64, 0, stream>>>(row_ptr, score_h, v_csr, qg, N);
    // out-linear + skip blend; reads g (f16), writes x fp32 + x_h mirror
    k_ngemm<HD, 2, true><<<ntiles, 256, 0, stream>>>(
        nullptr, qg, WaT + (size_t)l * T_N * HD * HD, ba + (size_t)l * T_N * HD,
        nsorted, nal, skip + (size_t)l * T_N, x, x_h, x);
  }
}

// Round 15
// 891.938 us; speedup vs baseline: 1.2887x; 1.0614x over previous
//
#include <hip/hip_runtime.h>
#include <cstdint>
#include <cstddef>

// HGT forward (2 layers) on MI355X.
// R15 = exact revert to R11 (best measured: 885us total, edge 187us).
// History: R10 dst-sort (-), R12 persistent pipeline (--, occupancy), R13
// prefetch+pin (--, spill), R14 prefetch-only (-, live-range cost 65->44%
// occ). Conclusion: in this gather-latency regime, added per-wave state or
// LDS always costs more TLP than it hides; R11's 40-VGPR/16KB/8-wave shape
// is the empirical optimum. absmax must stay 2.441406e-4.

namespace {

constexpr int T_N  = 3;
constexpr int R_N  = 4;
constexpr int HD   = 128;
constexpr int IND  = 256;
constexpr int NH   = 8;
constexpr int MAXT = 240;

typedef unsigned short u16;
typedef unsigned int   u32;
typedef _Float16 f16;
typedef __attribute__((ext_vector_type(8))) _Float16 f16x8;
typedef __attribute__((ext_vector_type(4))) float    f32x4;

// ----------------------------- utility kernels -----------------------------
__global__ void k_fill_i32(int* __restrict__ p, int v, int n) {
  int i = blockIdx.x * 256 + threadIdx.x;
  if (i < n) p[i] = v;
}
__global__ void k_copy_i32(int* __restrict__ d, const int* __restrict__ s, int n) {
  int i = blockIdx.x * 256 + threadIdx.x;
  if (i < n) d[i] = s[i];
}
__global__ void k_hist_dst(const int* __restrict__ dst, int* __restrict__ cnt, int E) {
  int i = blockIdx.x * 256 + threadIdx.x;
  if (i < E) atomicAdd(&cnt[dst[i]], 1);
}
__global__ void k_scan_a(const int* __restrict__ in, int* __restrict__ out,
                         int* __restrict__ bsums, int n) {
  __shared__ int s[256];
  int gid = blockIdx.x * 256 + threadIdx.x;
  int v = (gid < n) ? in[gid] : 0;
  s[threadIdx.x] = v;
  __syncthreads();
  for (int off = 1; off < 256; off <<= 1) {
    int t = (threadIdx.x >= off) ? s[threadIdx.x - off] : 0;
    __syncthreads();
    s[threadIdx.x] += t;
    __syncthreads();
  }
  if (gid < n) out[gid] = s[threadIdx.x] - v;
  if (threadIdx.x == 255) bsums[blockIdx.x] = s[255];
}
__global__ void k_scan_b(int* __restrict__ bsums, int nb) {
  __shared__ int s[256];
  int v = (threadIdx.x < nb) ? bsums[threadIdx.x] : 0;
  s[threadIdx.x] = v;
  __syncthreads();
  for (int off = 1; off < 256; off <<= 1) {
    int t = (threadIdx.x >= off) ? s[threadIdx.x - off] : 0;
    __syncthreads();
    s[threadIdx.x] += t;
    __syncthreads();
  }
  if (threadIdx.x < nb) bsums[threadIdx.x] = s[threadIdx.x] - v;
}
__global__ void k_scan_c(int* __restrict__ out, const int* __restrict__ bsums, int n) {
  int gid = blockIdx.x * 256 + threadIdx.x;
  if (gid < n) out[gid] += bsums[blockIdx.x];
}
// rank[e] = position of edge e in the dst-CSR ordering
__global__ void k_rank_dst(const int* __restrict__ dst, int* __restrict__ cur,
                           int* __restrict__ rank, int E) {
  int i = blockIdx.x * 256 + threadIdx.x;
  if (i < E) rank[i] = atomicAdd(&cur[dst[i]], 1);
}
__global__ void k_bhist(const int* __restrict__ src, const int* __restrict__ etype,
                        const int* __restrict__ ntype, int* __restrict__ bcnt, int E) {
  __shared__ int loc[12];
  if (threadIdx.x < 12) loc[threadIdx.x] = 0;
  __syncthreads();
  int i = blockIdx.x * 256 + threadIdx.x;
  if (i < E) {
    int b = ntype[src[i]] * R_N + etype[i];
    atomicAdd(&loc[b], 1);
  }
  __syncthreads();
  if (threadIdx.x < 12) atomicAdd(&bcnt[threadIdx.x], loc[threadIdx.x]);
}
__global__ void k_bscan(const int* __restrict__ bcnt, int* __restrict__ bal,
                        int* __restrict__ bcur) {
  if (threadIdx.x == 0 && blockIdx.x == 0) {
    int run = 0;
    for (int b = 0; b < 12; b++) {
      bal[b] = run;
      bcur[b] = run;
      run += (bcnt[b] + 63) & ~63;
    }
    bal[12] = run;
  }
}
__global__ void k_bscatter(const int* __restrict__ src, const int* __restrict__ etype,
                           const int* __restrict__ ntype, int* __restrict__ bcur,
                           int* __restrict__ esorted, int E) {
  __shared__ int loc[12];
  __shared__ int base[12];
  if (threadIdx.x < 12) loc[threadIdx.x] = 0;
  __syncthreads();
  int i = blockIdx.x * 256 + threadIdx.x;
  int b = 0, lpos = 0;
  if (i < E) {
    b = ntype[src[i]] * R_N + etype[i];
    lpos = atomicAdd(&loc[b], 1);
  }
  __syncthreads();
  if (threadIdx.x < 12) {
    int c = loc[threadIdx.x];
    base[threadIdx.x] = (c > 0) ? atomicAdd(&bcur[threadIdx.x], c) : 0;
  }
  __syncthreads();
  if (i < E) esorted[base[b] + lpos] = i;
}
// node-type buckets (3), 64-aligned
__global__ void k_nhist(const int* __restrict__ ntype, int* __restrict__ ncnt, int N) {
  __shared__ int loc[3];
  if (threadIdx.x < 3) loc[threadIdx.x] = 0;
  __syncthreads();
  int i = blockIdx.x * 256 + threadIdx.x;
  if (i < N) atomicAdd(&loc[ntype[i]], 1);
  __syncthreads();
  if (threadIdx.x < 3) atomicAdd(&ncnt[threadIdx.x], loc[threadIdx.x]);
}
__global__ void k_nscan(const int* __restrict__ ncnt, int* __restrict__ nal,
                        int* __restrict__ ncur) {
  if (threadIdx.x == 0 && blockIdx.x == 0) {
    int run = 0;
    for (int t = 0; t < 3; t++) {
      nal[t] = run;
      ncur[t] = run;
      run += (ncnt[t] + 63) & ~63;
    }
    nal[3] = run;
  }
}
__global__ void k_nscatter(const int* __restrict__ ntype, int* __restrict__ ncur,
                           int* __restrict__ nsorted, int N) {
  __shared__ int loc[3];
  __shared__ int base[3];
  if (threadIdx.x < 3) loc[threadIdx.x] = 0;
  __syncthreads();
  int i = blockIdx.x * 256 + threadIdx.x;
  int t = 0, lpos = 0;
  if (i < N) {
    t = ntype[i];
    lpos = atomicAdd(&loc[t], 1);
  }
  __syncthreads();
  if (threadIdx.x < 3) {
    int c = loc[threadIdx.x];
    base[threadIdx.x] = (c > 0) ? atomicAdd(&ncur[threadIdx.x], c) : 0;
  }
  __syncthreads();
  if (i < N) nsorted[base[t] + lpos] = i;
}

// transpose+f16: src [T][Kd][Cd] fp32 -> dst [T][Cd][Kd] f16 (k contiguous)
__global__ void k_transp(const float* __restrict__ src, u16* __restrict__ dst,
                         int Kd, int Cd) {
  int c = blockIdx.x;
  int t = blockIdx.y;
  for (int k = threadIdx.x; k < Kd; k += blockDim.x)
    dst[((size_t)t * Cd + c) * Kd + k] =
        __builtin_bit_cast(u16, (f16)src[((size_t)t * Kd + k) * Cd + c]);
}

// ------------------------------ math kernels -------------------------------
// rte table -> f16 [240][128]
__global__ void k_rte(const float* __restrict__ emb, const float* __restrict__ W,
                      const float* __restrict__ bias, u16* __restrict__ out, int l) {
  int t = blockIdx.x;
  int lane = threadIdx.x;
  __shared__ __align__(16) float s[2 * HD];
  ((float4*)s)[lane] = ((const float4*)(emb + (size_t)t * 2 * HD))[lane];
  __syncthreads();
  const float* Wl = W + (size_t)l * 2 * HD * HD;
  float o0 = bias[l * HD + 2 * lane];
  float o1 = bias[l * HD + 2 * lane + 1];
  #pragma unroll 4
  for (int k = 0; k < 2 * HD; k++) {
    float xv = s[k];
    float2 w = ((const float2*)(Wl + (size_t)k * HD))[lane];
    o0 = fmaf(xv, w.x, o0);
    o1 = fmaf(xv, w.y, o1);
  }
  u32 pk = (u32)__builtin_bit_cast(u16, (f16)o0)
         | ((u32)__builtin_bit_cast(u16, (f16)o1) << 16);
  ((u32*)out)[t * 64 + lane] = pk;
}

// Combined per-(type,rel) matrices, f16, stored [b][c][k] (k contiguous)
__global__ void k_wcomb(const float* __restrict__ Wk, const float* __restrict__ Wv,
                        const float* __restrict__ bk, const float* __restrict__ bv,
                        const float* __restrict__ Ratt, const float* __restrict__ Rmsg,
                        u16* __restrict__ Wcomb, float* __restrict__ bcomb, int l) {
  int bc = blockIdx.x;
  int b  = bc >> 8;
  int c  = bc & 255;
  int st = b >> 2, rt = b & 3;
  int k  = threadIdx.x;
  bool isv = (c >= HD);
  int c0 = isv ? c - HD : c;
  int h  = c0 >> 4, cc = c0 & 15;
  const float* W = (isv ? Wv : Wk) + (((size_t)(l * T_N + st) * HD) + k) * HD + h * 16;
  const float* A = (isv ? Rmsg : Ratt) + (((size_t)(l * R_N + rt) * NH + h) * 16) * 16 + cc;
  float s = 0.f;
  #pragma unroll
  for (int d = 0; d < 16; d++) s = fmaf(W[d], A[d * 16], s);
  Wcomb[((size_t)b * 256 + c) * HD + k] = __builtin_bit_cast(u16, (f16)s);
  if (k == 0) {
    const float* bb = (isv ? bv : bk) + (size_t)(l * T_N + st) * HD + h * 16;
    float sb = 0.f;
    #pragma unroll
    for (int d = 0; d < 16; d++) sb = fmaf(bb[d], A[d * 16], sb);
    bcomb[b * 256 + c] = sb;
  }
}

// Generic MFMA node linear over type-sorted buckets.
// out = act( A[n][0..K) @ WT[t]^T + bias[t] ); ACT: 0 tanh, 1 none, 2 blend.
template<int K, int ACT, bool AHALF>
__global__ __launch_bounds__(256) void k_ngemm(
    const float* __restrict__ Af, const u16* __restrict__ Ah,
    const u16* __restrict__ WT, const float* __restrict__ bias,
    const int* __restrict__ nsorted, const int* __restrict__ nal,
    const float* __restrict__ skip_l,
    float* __restrict__ out_f, u16* __restrict__ out_h,
    const float* __restrict__ xin) {
  int tile0 = blockIdx.x * 64;
  if (tile0 >= nal[3]) return;
  int t = 0;
  #pragma unroll
  for (int i = 1; i < 3; i++) t += (tile0 >= nal[i]);

  __shared__ __align__(16) u16 ab[64 * K];   // f16, XOR-swizzled rows (G4)
  __shared__ int s_nid[64];
  int tid = threadIdx.x;
  int lane = tid & 63, w = tid >> 6;
  int l15 = lane & 15, l4 = lane >> 4;

  if (tid < 64) s_nid[tid] = nsorted[tile0 + tid];
  __syncthreads();

  { // stage: thread (row=tid>>2, quarter=tid&3) -> K/4 elements -> f16 LDS
    int r = tid >> 2, q4 = tid & 3;
    int nid = s_nid[r];
    char* rowp = (char*)ab + r * (2 * K);
    int sw = (r & 7) << 4;
    int base = q4 * (K / 2);               // byte base within row
    if (nid >= 0) {
      if (AHALF) {
        const f16x8* ap = (const f16x8*)(Ah + (size_t)nid * K + q4 * (K / 4));
        #pragma unroll
        for (int i = 0; i < K / 32; i++)
          *(f16x8*)(rowp + ((base + 16 * i) ^ sw)) = ap[i];
      } else {
        const float4* ap = (const float4*)(Af + (size_t)nid * K + q4 * (K / 4));
        #pragma unroll
        for (int i = 0; i < K / 32; i++) {
          float4 a = ap[2 * i], a2 = ap[2 * i + 1];
          f16x8 hv;
          hv[0] = (f16)a.x;  hv[1] = (f16)a.y;  hv[2] = (f16)a.z;  hv[3] = (f16)a.w;
          hv[4] = (f16)a2.x; hv[5] = (f16)a2.y; hv[6] = (f16)a2.z; hv[7] = (f16)a2.w;
          *(f16x8*)(rowp + ((base + 16 * i) ^ sw)) = hv;
        }
      }
    } else {
      f16x8 z;
      #pragma unroll
      for (int j = 0; j < 8; j++) z[j] = (f16)0.f;
      #pragma unroll
      for (int i = 0; i < K / 32; i++)
        *(f16x8*)(rowp + ((base + 16 * i) ^ sw)) = z;
    }
  }
  __syncthreads();

  f32x4 acc[4][2];
  #pragma unroll
  for (int ni = 0; ni < 2; ni++) {
    float bc = bias[t * HD + w * 32 + ni * 16 + l15];
    #pragma unroll
    for (int mi = 0; mi < 4; mi++) {
      acc[mi][ni][0] = bc; acc[mi][ni][1] = bc;
      acc[mi][ni][2] = bc; acc[mi][ni][3] = bc;
    }
  }
  const u16* Wt = WT + (size_t)t * HD * K;
  #pragma unroll
  for (int ks = 0; ks < K / 32; ks++) {
    int k0 = ks * 32 + 8 * l4;
    f16x8 bf[2], af[4];
    #pragma unroll
    for (int ni = 0; ni < 2; ni++)
      bf[ni] = *(const f16x8*)(Wt + (size_t)(w * 32 + ni * 16 + l15) * K + k0);
    #pragma unroll
    for (int mi = 0; mi < 4; mi++) {
      int row = mi * 16 + l15;
      af[mi] = *(const f16x8*)((const char*)ab + row * (2 * K) +
                               ((2 * k0) ^ ((row & 7) << 4)));
    }
    #pragma unroll
    for (int mi = 0; mi < 4; mi++)
      #pragma unroll
      for (int ni = 0; ni < 2; ni++)
        acc[mi][ni] = __builtin_amdgcn_mfma_f32_16x16x32_f16(af[mi], bf[ni],
                                                             acc[mi][ni], 0, 0, 0);
  }

  float alpha = 0.f;
  if (ACT == 2) alpha = 1.f / (1.f + expf(-skip_l[t]));
  #pragma unroll
  for (int mi = 0; mi < 4; mi++)
    #pragma unroll
    for (int r = 0; r < 4; r++) {
      int rowl = mi * 16 + l4 * 4 + r;
      int nid = s_nid[rowl];
      if (nid >= 0) {
        #pragma unroll
        for (int ni = 0; ni < 2; ni++) {
          int c = w * 32 + ni * 16 + l15;
          float val = acc[mi][ni][r];
          if (ACT == 0) val = tanhf(val);
          if (ACT == 2) {
            float xo = xin[(size_t)nid * HD + c];
            val = val * alpha + xo * (1.f - alpha);
          }
          if (out_f) out_f[(size_t)nid * HD + c] = val;
          if (out_h) out_h[(size_t)nid * HD + c] =
              __builtin_bit_cast(u16, (f16)val);
        }
      }
    }
}

// MFMA edge kernel, f16 gathers. 512 threads / 8 waves; wave w owns combined
// cols [w*32, w*32+32): w<4 -> k' (to LDS for scores), w>=4 -> v' (to global).
// acc[4][2] = 32 AGPR/wave (~40 regs total) -> high occupancy; no prefetch
// (R13/R14 A/B showed any long-lived register state costs more than it hides).
__global__ __launch_bounds__(512) void k_edge_gemm(
    const u16* __restrict__ x_h, const u16* __restrict__ rte_h,
    const u16* __restrict__ Wcomb, const float* __restrict__ bcomb,
    const u16* __restrict__ q_h, const int* __restrict__ esorted,
    const int* __restrict__ bal, const int* __restrict__ src,
    const int* __restrict__ dst, const int* __restrict__ etime,
    const int* __restrict__ ntype, const int* __restrict__ rank,
    const float* __restrict__ pri_l,
    u16* __restrict__ score_h, u16* __restrict__ v_csr) {
  int tile0 = blockIdx.x * 64;
  if (tile0 >= bal[12]) return;
  int b = 0;
  #pragma unroll
  for (int i = 1; i < 12; i++) b += (tile0 >= bal[i]);
  int st = b >> 2, rt = b & 3;

  __shared__ __align__(16) u16 albuf[64 * HD];   // 16 KB
  __shared__ int s_eid[64];
  __shared__ int s_dst[64];
  __shared__ int s_rank[64];
  int tid = threadIdx.x;
  int lane = tid & 63, w = tid >> 6;
  int l15 = lane & 15, l4 = lane >> 4;

  if (tid < 64) {
    int e = esorted[tile0 + tid];
    s_eid[tid] = e;
    s_dst[tid] = (e >= 0) ? dst[e] : 0;
    s_rank[tid] = (e >= 0) ? rank[e] : 0;
  }
  __syncthreads();

  { // stage: row = tid>>3, part = tid&7 -> 16 f16 each (2x 16B gathers)
    int r = tid >> 3, p = tid & 7;
    int e = s_eid[r];
    char* rowp = (char*)albuf + r * 256;
    int sw = (r & 7) << 4;
    if (e >= 0) {
      const f16x8* xs = (const f16x8*)(x_h + (size_t)src[e] * HD + p * 16);
      const f16x8* rp = (const f16x8*)(rte_h + (size_t)etime[e] * HD + p * 16);
      f16x8 h0 = xs[0] + rp[0];
      f16x8 h1 = xs[1] + rp[1];
      *(f16x8*)(rowp + ((p * 32) ^ sw))      = h0;
      *(f16x8*)(rowp + ((p * 32 + 16) ^ sw)) = h1;
    } else {
      f16x8 z;
      #pragma unroll
      for (int j = 0; j < 8; j++) z[j] = (f16)0.f;
      *(f16x8*)(rowp + ((p * 32) ^ sw))      = z;
      *(f16x8*)(rowp + ((p * 32 + 16) ^ sw)) = z;
    }
  }
  __syncthreads();

  f32x4 acc[4][2];
  #pragma unroll
  for (int ni = 0; ni < 2; ni++) {
    float bc = bcomb[b * 256 + w * 32 + ni * 16 + l15];
    #pragma unroll
    for (int mi = 0; mi < 4; mi++) {
      acc[mi][ni][0] = bc; acc[mi][ni][1] = bc;
      acc[mi][ni][2] = bc; acc[mi][ni][3] = bc;
    }
  }
  const u16* Wb = Wcomb + (size_t)b * 256 * HD;
  #pragma unroll
  for (int ks = 0; ks < 4; ks++) {
    int k0 = ks * 32 + 8 * l4;
    f16x8 bf[2], af[4];
    #pragma unroll
    for (int ni = 0; ni < 2; ni++)
      bf[ni] = *(const f16x8*)(Wb + (size_t)(w * 32 + ni * 16 + l15) * HD + k0);
    #pragma unroll
    for (int mi = 0; mi < 4; mi++) {
      int row = mi * 16 + l15;
      af[mi] = *(const f16x8*)((const char*)albuf + row * 256 +
                               ((2 * k0) ^ ((row & 7) << 4)));
    }
    #pragma unroll
    for (int mi = 0; mi < 4; mi++)
      #pragma unroll
      for (int ni = 0; ni < 2; ni++)
        acc[mi][ni] = __builtin_amdgcn_mfma_f32_16x16x32_f16(af[mi], bf[ni],
                                                             acc[mi][ni], 0, 0, 0);
  }
  __syncthreads();

  if (w < 4) {       // k' cols [w*32, w*32+32) -> albuf f16 (swizzled)
    #pragma unroll
    for (int mi = 0; mi < 4; mi++)
      #pragma unroll
      for (int r = 0; r < 4; r++) {
        int row = mi * 16 + l4 * 4 + r;
        char* rowp = (char*)albuf + row * 256;
        int sw = (row & 7) << 4;
        #pragma unroll
        for (int ni = 0; ni < 2; ni++) {
          int c = w * 32 + ni * 16 + l15;
          *(u16*)(rowp + ((2 * c) ^ sw)) =
              __builtin_bit_cast(u16, (f16)acc[mi][ni][r]);
        }
      }
  } else {           // v' cols [(w-4)*32, ..) -> v_csr[rank] f16
    int wv = w - 4;
    #pragma unroll
    for (int mi = 0; mi < 4; mi++)
      #pragma unroll
      for (int r = 0; r < 4; r++) {
        int rowl = mi * 16 + l4 * 4 + r;
        if (s_eid[rowl] >= 0) {
          u16* vp = v_csr + (size_t)s_rank[rowl] * HD + wv * 32 + l15;
          #pragma unroll
          for (int ni = 0; ni < 2; ni++)
            vp[ni * 16] = __builtin_bit_cast(u16, (f16)acc[mi][ni][r]);
        }
      }
  }
  __syncthreads();

  // scores: 512 (edge, head) tasks, one per thread; write score_h[rank] (f16)
  {
    int e = tid >> 3, h = tid & 7;
    if (s_eid[e] >= 0) {
      int d = s_dst[e];
      int tt = ntype[d];
      const char* rowp = (const char*)albuf + e * 256;
      int sw = (e & 7) << 4;
      f16x8 kh0 = *(const f16x8*)(rowp + ((h * 32) ^ sw));
      f16x8 kh1 = *(const f16x8*)(rowp + ((h * 32 + 16) ^ sw));
      const f16x8* qp = (const f16x8*)(q_h + (size_t)d * HD + h * 16);
      f16x8 qa = qp[0], qb = qp[1];
      float sc = 0.f;
      #pragma unroll
      for (int j = 0; j < 8; j++) sc += (float)qa[j] * (float)kh0[j];
      #pragma unroll
      for (int j = 0; j < 8; j++) sc += (float)qb[j] * (float)kh1[j];
      float pri = pri_l[((tt * R_N + rt) * T_N + st) * NH + h];
      score_h[(size_t)s_rank[e] * NH + h] =
          __builtin_bit_cast(u16, (f16)(sc * pri * 0.25f));
    }
  }
}

// Per-node (1 wave): segment softmax + weighted v-sum + exact GELU -> g (f16).
__global__ void k_aggr(const int* __restrict__ row_ptr,
                       const u16* __restrict__ score_h,
                       const u16* __restrict__ v_csr,
                       u16* __restrict__ g_h, int N) {
  int n = blockIdx.x;
  int lane = threadIdx.x;
  int start = row_ptr[n], end = row_ptr[n + 1];

  int h = lane & 7, jj = lane >> 3;
  float m = -3.0e38f;
  for (int idx = start + jj; idx < end; idx += 8)
    m = fmaxf(m, (float)__builtin_bit_cast(f16, score_h[(size_t)idx * NH + h]));
  #pragma unroll
  for (int off = 8; off < 64; off <<= 1) m = fmaxf(m, __shfl_xor(m, off));
  float z = 0.f;
  for (int idx = start + jj; idx < end; idx += 8)
    z += expf((float)__builtin_bit_cast(f16, score_h[(size_t)idx * NH + h]) - m);
  #pragma unroll
  for (int off = 8; off < 64; off <<= 1) z += __shfl_xor(z, off);

  int myh = lane >> 3;
  float md = __shfl(m, myh);
  float zd = __shfl(z, myh);
  float rz = (zd > 0.f) ? 1.f / zd : 0.f;

  float a0 = 0.f, a1 = 0.f;
  for (int idx = start; idx < end; idx++) {
    float sc = (float)__builtin_bit_cast(f16, score_h[(size_t)idx * NH + myh]);
    float wgt = expf(sc - md) * rz;
    u32 v2 = ((const u32*)(v_csr + (size_t)idx * HD))[lane];
    float v0 = (float)__builtin_bit_cast(f16, (u16)(v2 & 0xffffu));
    float v1 = (float)__builtin_bit_cast(f16, (u16)(v2 >> 16));
    a0 = fmaf(wgt, v0, a0);
    a1 = fmaf(wgt, v1, a1);
  }

  a0 = 0.5f * a0 * (1.f + erff(a0 * 0.7071067811865475f));
  a1 = 0.5f * a1 * (1.f + erff(a1 * 0.7071067811865475f));
  u32 pk = (u32)__builtin_bit_cast(u16, (f16)a0)
         | ((u32)__builtin_bit_cast(u16, (f16)a1) << 16);
  ((u32*)(g_h + (size_t)n * HD))[lane] = pk;
}

}  // namespace

extern "C" void kernel_launch(void* const* d_in, const int* in_sizes, int n_in,
                              void* d_out, int out_size, void* d_ws, size_t ws_size,
                              hipStream_t stream) {
  const float* node_feature = (const float*)d_in[0];
  const int*   node_type    = (const int*)d_in[1];
  const int*   edge_time    = (const int*)d_in[2];
  const int*   edge_type    = (const int*)d_in[3];
  const int*   edge_index   = (const int*)d_in[4];
  const float* adapt_W      = (const float*)d_in[5];
  const float* adapt_b      = (const float*)d_in[6];
  const float* Wk           = (const float*)d_in[7];
  const float* bk           = (const float*)d_in[8];
  const float* Wq           = (const float*)d_in[9];
  const float* bq           = (const float*)d_in[10];
  const float* Wv           = (const float*)d_in[11];
  const float* bv           = (const float*)d_in[12];
  const float* Wa           = (const float*)d_in[13];
  const float* ba           = (const float*)d_in[14];
  const float* rel_pri      = (const float*)d_in[15];
  const float* rel_att      = (const float*)d_in[16];
  const float* rel_msg      = (const float*)d_in[17];
  const float* skip         = (const float*)d_in[18];
  const float* rte_emb      = (const float*)d_in[19];
  const float* rte_W        = (const float*)d_in[20];
  const float* rte_b        = (const float*)d_in[21];

  const int N = in_sizes[1];
  const int E = in_sizes[2];
  const int* src  = edge_index;
  const int* dstp = edge_index + E;

  float* x = (float*)d_out;

  size_t off = 0;
  auto carve = [&](size_t bytes) -> void* {
    void* p = (char*)d_ws + off;
    off += (bytes + 255) & ~(size_t)255;
    return p;
  };
  // ~252 MB total (R8's 290MB crashed; stay under 256MiB).
  u16*   v_csr   = (u16*)  carve((size_t)E * HD * 2);   // 204.8 MB, CSR-perm
  u16*   score_h = (u16*)  carve((size_t)E * NH * 2);   // 12.8 MB, CSR-perm
  u16*   x_h     = (u16*)  carve((size_t)N * HD * 2);   // 12.8 MB
  u16*   qg      = (u16*)  carve((size_t)N * HD * 2);   // 12.8 MB: q_h then g_h
  u16*   rte_h   = (u16*)  carve((size_t)MAXT * HD * 2);
  u16*   Wcomb   = (u16*)  carve((size_t)12 * 256 * HD * 2);
  float* bcomb   = (float*)carve((size_t)12 * 256 * 4);
  u16*   adaptWT = (u16*)  carve((size_t)T_N * HD * IND * 2);
  u16*   WqT     = (u16*)  carve((size_t)2 * T_N * HD * HD * 2);
  u16*   WaT     = (u16*)  carve((size_t)2 * T_N * HD * HD * 2);
  int*   row_ptr = (int*)  carve((size_t)(N + 1) * 4);
  int*   cnt     = (int*)  carve((size_t)(N + 1) * 4);
  int*   rank    = (int*)  carve((size_t)E * 4);
  int*   bsums   = (int*)  carve(1024 * 4);
  int*   bcnt    = (int*)  carve(16 * 4);
  int*   bal     = (int*)  carve(16 * 4);
  int*   bcur    = (int*)  carve(16 * 4);
  int*   ncnt    = (int*)  carve(16 * 4);
  int*   nal     = (int*)  carve(16 * 4);
  int*   ncur    = (int*)  carve(16 * 4);
  const int EP = E + 12 * 64;
  const int NP = N + 3 * 64;
  int*   esorted = (int*)  carve((size_t)EP * 4);
  int*   nsorted = (int*)  carve((size_t)NP * 4);
  (void)ws_size; (void)n_in; (void)out_size;

  const int gE  = (E + 255) / 256;
  const int gN1 = (N + 1 + 255) / 256;
  const int gN  = (N + 255) / 256;
  const int gEP = (EP + 255) / 256;
  const int gNP = (NP + 255) / 256;
  const int etiles = (EP + 63) / 64;
  const int ntiles = (NP + 63) / 64;

  // CSR row_ptr + rank permutation (dst order)
  k_fill_i32<<<gN1, 256, 0, stream>>>(cnt, 0, N + 1);
  k_hist_dst<<<gE, 256, 0, stream>>>(dstp, cnt, E);
  k_scan_a<<<gN1, 256, 0, stream>>>(cnt, row_ptr, bsums, N + 1);
  k_scan_b<<<1, 256, 0, stream>>>(bsums, gN1);
  k_scan_c<<<gN1, 256, 0, stream>>>(row_ptr, bsums, N + 1);
  k_copy_i32<<<gN, 256, 0, stream>>>(cnt, row_ptr, N);
  k_rank_dst<<<gE, 256, 0, stream>>>(dstp, cnt, rank, E);

  // edge (src_type, rel_type) buckets (original order within bucket)
  k_fill_i32<<<1, 256, 0, stream>>>(bcnt, 0, 16);
  k_bhist<<<gE, 256, 0, stream>>>(src, edge_type, node_type, bcnt, E);
  k_bscan<<<1, 64, 0, stream>>>(bcnt, bal, bcur);
  k_fill_i32<<<gEP, 256, 0, stream>>>(esorted, -1, EP);
  k_bscatter<<<gE, 256, 0, stream>>>(src, edge_type, node_type, bcur, esorted, E);

  // node type buckets
  k_fill_i32<<<1, 256, 0, stream>>>(ncnt, 0, 16);
  k_nhist<<<gN, 256, 0, stream>>>(node_type, ncnt, N);
  k_nscan<<<1, 64, 0, stream>>>(ncnt, nal, ncur);
  k_fill_i32<<<gNP, 256, 0, stream>>>(nsorted, -1, NP);
  k_nscatter<<<gN, 256, 0, stream>>>(node_type, ncur, nsorted, N);

  // f16 transposed weights
  k_transp<<<dim3(HD, T_N), 128, 0, stream>>>(adapt_W, adaptWT, IND, HD);
  for (int l = 0; l < 2; l++) {
    k_transp<<<dim3(HD, T_N), 128, 0, stream>>>(
        Wq + (size_t)l * T_N * HD * HD, WqT + (size_t)l * T_N * HD * HD, HD, HD);
    k_transp<<<dim3(HD, T_N), 128, 0, stream>>>(
        Wa + (size_t)l * T_N * HD * HD, WaT + (size_t)l * T_N * HD * HD, HD, HD);
  }

  // adapt: x = tanh(node_feature @ adapt_W[t] + adapt_b[t]); also x_h mirror
  k_ngemm<IND, 0, false><<<ntiles, 256, 0, stream>>>(
      node_feature, nullptr, adaptWT, adapt_b, nsorted, nal, nullptr,
      x, x_h, nullptr);

  for (int l = 0; l < 2; l++) {
    k_rte<<<MAXT, 64, 0, stream>>>(rte_emb, rte_W, rte_b, rte_h, l);
    k_wcomb<<<12 * 256, 128, 0, stream>>>(Wk, Wv, bk, bv, rel_att, rel_msg,
                                          Wcomb, bcomb, l);
    // q (f16 -> qg), input from x_h
    k_ngemm<HD, 1, true><<<ntiles, 256, 0, stream>>>(
        nullptr, x_h, WqT + (size_t)l * T_N * HD * HD, bq + (size_t)l * T_N * HD,
        nsorted, nal, nullptr, nullptr, qg, nullptr);
    k_edge_gemm<<<etiles, 512, 0, stream>>>(x_h, rte_h, Wcomb, bcomb, qg,
                                            esorted, bal, src, dstp, edge_time,
                                            node_type, rank,
                                            rel_pri + (size_t)l * T_N * R_N * T_N * NH,
                                            score_h, v_csr);
    // g (f16) overwrites qg -- q_h dead after edge_gemm (stream-ordered)
    k_aggr<<<N, 64, 0, stream>>>(row_ptr, score_h, v_csr, qg, N);
    // out-linear + skip blend; reads g (f16), writes x fp32 + x_h mirror
    k_ngemm<HD, 2, true><<<ntiles, 256, 0, stream>>>(
        nullptr, qg, WaT + (size_t)l * T_N * HD * HD, ba + (size_t)l * T_N * HD,
        nsorted, nal, skip + (size_t)l * T_N, x, x_h, x);
  }
}

// Round 16
// 889.258 us; speedup vs baseline: 1.2926x; 1.0030x over previous
//
#include <hip/hip_runtime.h>
#include <cstdint>
#include <cstddef>

// HGT forward (2 layers) on MI355X.
// R15 = exact revert to R11 (best measured: 885us total, edge 187us).
// History: R10 dst-sort (-), R12 persistent pipeline (--, occupancy), R13
// prefetch+pin (--, spill), R14 prefetch-only (-, live-range cost 65->44%
// occ). Conclusion: in this gather-latency regime, added per-wave state or
// LDS always costs more TLP than it hides; R11's 40-VGPR/16KB/8-wave shape
// is the empirical optimum. absmax must stay 2.441406e-4.

namespace {

constexpr int T_N  = 3;
constexpr int R_N  = 4;
constexpr int HD   = 128;
constexpr int IND  = 256;
constexpr int NH   = 8;
constexpr int MAXT = 240;

typedef unsigned short u16;
typedef unsigned int   u32;
typedef _Float16 f16;
typedef __attribute__((ext_vector_type(8))) _Float16 f16x8;
typedef __attribute__((ext_vector_type(4))) float    f32x4;

// ----------------------------- utility kernels -----------------------------
__global__ void k_fill_i32(int* __restrict__ p, int v, int n) {
  int i = blockIdx.x * 256 + threadIdx.x;
  if (i < n) p[i] = v;
}
__global__ void k_copy_i32(int* __restrict__ d, const int* __restrict__ s, int n) {
  int i = blockIdx.x * 256 + threadIdx.x;
  if (i < n) d[i] = s[i];
}
__global__ void k_hist_dst(const int* __restrict__ dst, int* __restrict__ cnt, int E) {
  int i = blockIdx.x * 256 + threadIdx.x;
  if (i < E) atomicAdd(&cnt[dst[i]], 1);
}
__global__ void k_scan_a(const int* __restrict__ in, int* __restrict__ out,
                         int* __restrict__ bsums, int n) {
  __shared__ int s[256];
  int gid = blockIdx.x * 256 + threadIdx.x;
  int v = (gid < n) ? in[gid] : 0;
  s[threadIdx.x] = v;
  __syncthreads();
  for (int off = 1; off < 256; off <<= 1) {
    int t = (threadIdx.x >= off) ? s[threadIdx.x - off] : 0;
    __syncthreads();
    s[threadIdx.x] += t;
    __syncthreads();
  }
  if (gid < n) out[gid] = s[threadIdx.x] - v;
  if (threadIdx.x == 255) bsums[blockIdx.x] = s[255];
}
__global__ void k_scan_b(int* __restrict__ bsums, int nb) {
  __shared__ int s[256];
  int v = (threadIdx.x < nb) ? bsums[threadIdx.x] : 0;
  s[threadIdx.x] = v;
  __syncthreads();
  for (int off = 1; off < 256; off <<= 1) {
    int t = (threadIdx.x >= off) ? s[threadIdx.x - off] : 0;
    __syncthreads();
    s[threadIdx.x] += t;
    __syncthreads();
  }
  if (threadIdx.x < nb) bsums[threadIdx.x] = s[threadIdx.x] - v;
}
__global__ void k_scan_c(int* __restrict__ out, const int* __restrict__ bsums, int n) {
  int gid = blockIdx.x * 256 + threadIdx.x;
  if (gid < n) out[gid] += bsums[blockIdx.x];
}
// rank[e] = position of edge e in the dst-CSR ordering
__global__ void k_rank_dst(const int* __restrict__ dst, int* __restrict__ cur,
                           int* __restrict__ rank, int E) {
  int i = blockIdx.x * 256 + threadIdx.x;
  if (i < E) rank[i] = atomicAdd(&cur[dst[i]], 1);
}
__global__ void k_bhist(const int* __restrict__ src, const int* __restrict__ etype,
                        const int* __restrict__ ntype, int* __restrict__ bcnt, int E) {
  __shared__ int loc[12];
  if (threadIdx.x < 12) loc[threadIdx.x] = 0;
  __syncthreads();
  int i = blockIdx.x * 256 + threadIdx.x;
  if (i < E) {
    int b = ntype[src[i]] * R_N + etype[i];
    atomicAdd(&loc[b], 1);
  }
  __syncthreads();
  if (threadIdx.x < 12) atomicAdd(&bcnt[threadIdx.x], loc[threadIdx.x]);
}
__global__ void k_bscan(const int* __restrict__ bcnt, int* __restrict__ bal,
                        int* __restrict__ bcur) {
  if (threadIdx.x == 0 && blockIdx.x == 0) {
    int run = 0;
    for (int b = 0; b < 12; b++) {
      bal[b] = run;
      bcur[b] = run;
      run += (bcnt[b] + 63) & ~63;
    }
    bal[12] = run;
  }
}
__global__ void k_bscatter(const int* __restrict__ src, const int* __restrict__ etype,
                           const int* __restrict__ ntype, int* __restrict__ bcur,
                           int* __restrict__ esorted, int E) {
  __shared__ int loc[12];
  __shared__ int base[12];
  if (threadIdx.x < 12) loc[threadIdx.x] = 0;
  __syncthreads();
  int i = blockIdx.x * 256 + threadIdx.x;
  int b = 0, lpos = 0;
  if (i < E) {
    b = ntype[src[i]] * R_N + etype[i];
    lpos = atomicAdd(&loc[b], 1);
  }
  __syncthreads();
  if (threadIdx.x < 12) {
    int c = loc[threadIdx.x];
    base[threadIdx.x] = (c > 0) ? atomicAdd(&bcur[threadIdx.x], c) : 0;
  }
  __syncthreads();
  if (i < E) esorted[base[b] + lpos] = i;
}
// node-type buckets (3), 64-aligned
__global__ void k_nhist(const int* __restrict__ ntype, int* __restrict__ ncnt, int N) {
  __shared__ int loc[3];
  if (threadIdx.x < 3) loc[threadIdx.x] = 0;
  __syncthreads();
  int i = blockIdx.x * 256 + threadIdx.x;
  if (i < N) atomicAdd(&loc[ntype[i]], 1);
  __syncthreads();
  if (threadIdx.x < 3) atomicAdd(&ncnt[threadIdx.x], loc[threadIdx.x]);
}
__global__ void k_nscan(const int* __restrict__ ncnt, int* __restrict__ nal,
                        int* __restrict__ ncur) {
  if (threadIdx.x == 0 && blockIdx.x == 0) {
    int run = 0;
    for (int t = 0; t < 3; t++) {
      nal[t] = run;
      ncur[t] = run;
      run += (ncnt[t] + 63) & ~63;
    }
    nal[3] = run;
  }
}
__global__ void k_nscatter(const int* __restrict__ ntype, int* __restrict__ ncur,
                           int* __restrict__ nsorted, int N) {
  __shared__ int loc[3];
  __shared__ int base[3];
  if (threadIdx.x < 3) loc[threadIdx.x] = 0;
  __syncthreads();
  int i = blockIdx.x * 256 + threadIdx.x;
  int t = 0, lpos = 0;
  if (i < N) {
    t = ntype[i];
    lpos = atomicAdd(&loc[t], 1);
  }
  __syncthreads();
  if (threadIdx.x < 3) {
    int c = loc[threadIdx.x];
    base[threadIdx.x] = (c > 0) ? atomicAdd(&ncur[threadIdx.x], c) : 0;
  }
  __syncthreads();
  if (i < N) nsorted[base[t] + lpos] = i;
}

// transpose+f16: src [T][Kd][Cd] fp32 -> dst [T][Cd][Kd] f16 (k contiguous)
__global__ void k_transp(const float* __restrict__ src, u16* __restrict__ dst,
                         int Kd, int Cd) {
  int c = blockIdx.x;
  int t = blockIdx.y;
  for (int k = threadIdx.x; k < Kd; k += blockDim.x)
    dst[((size_t)t * Cd + c) * Kd + k] =
        __builtin_bit_cast(u16, (f16)src[((size_t)t * Kd + k) * Cd + c]);
}

// ------------------------------ math kernels -------------------------------
// rte table -> f16 [240][128]
__global__ void k_rte(const float* __restrict__ emb, const float* __restrict__ W,
                      const float* __restrict__ bias, u16* __restrict__ out, int l) {
  int t = blockIdx.x;
  int lane = threadIdx.x;
  __shared__ __align__(16) float s[2 * HD];
  ((float4*)s)[lane] = ((const float4*)(emb + (size_t)t * 2 * HD))[lane];
  __syncthreads();
  const float* Wl = W + (size_t)l * 2 * HD * HD;
  float o0 = bias[l * HD + 2 * lane];
  float o1 = bias[l * HD + 2 * lane + 1];
  #pragma unroll 4
  for (int k = 0; k < 2 * HD; k++) {
    float xv = s[k];
    float2 w = ((const float2*)(Wl + (size_t)k * HD))[lane];
    o0 = fmaf(xv, w.x, o0);
    o1 = fmaf(xv, w.y, o1);
  }
  u32 pk = (u32)__builtin_bit_cast(u16, (f16)o0)
         | ((u32)__builtin_bit_cast(u16, (f16)o1) << 16);
  ((u32*)out)[t * 64 + lane] = pk;
}

// Combined per-(type,rel) matrices, f16, stored [b][c][k] (k contiguous)
__global__ void k_wcomb(const float* __restrict__ Wk, const float* __restrict__ Wv,
                        const float* __restrict__ bk, const float* __restrict__ bv,
                        const float* __restrict__ Ratt, const float* __restrict__ Rmsg,
                        u16* __restrict__ Wcomb, float* __restrict__ bcomb, int l) {
  int bc = blockIdx.x;
  int b  = bc >> 8;
  int c  = bc & 255;
  int st = b >> 2, rt = b & 3;
  int k  = threadIdx.x;
  bool isv = (c >= HD);
  int c0 = isv ? c - HD : c;
  int h  = c0 >> 4, cc = c0 & 15;
  const float* W = (isv ? Wv : Wk) + (((size_t)(l * T_N + st) * HD) + k) * HD + h * 16;
  const float* A = (isv ? Rmsg : Ratt) + (((size_t)(l * R_N + rt) * NH + h) * 16) * 16 + cc;
  float s = 0.f;
  #pragma unroll
  for (int d = 0; d < 16; d++) s = fmaf(W[d], A[d * 16], s);
  Wcomb[((size_t)b * 256 + c) * HD + k] = __builtin_bit_cast(u16, (f16)s);
  if (k == 0) {
    const float* bb = (isv ? bv : bk) + (size_t)(l * T_N + st) * HD + h * 16;
    float sb = 0.f;
    #pragma unroll
    for (int d = 0; d < 16; d++) sb = fmaf(bb[d], A[d * 16], sb);
    bcomb[b * 256 + c] = sb;
  }
}

// Generic MFMA node linear over type-sorted buckets.
// out = act( A[n][0..K) @ WT[t]^T + bias[t] ); ACT: 0 tanh, 1 none, 2 blend.
template<int K, int ACT, bool AHALF>
__global__ __launch_bounds__(256) void k_ngemm(
    const float* __restrict__ Af, const u16* __restrict__ Ah,
    const u16* __restrict__ WT, const float* __restrict__ bias,
    const int* __restrict__ nsorted, const int* __restrict__ nal,
    const float* __restrict__ skip_l,
    float* __restrict__ out_f, u16* __restrict__ out_h,
    const float* __restrict__ xin) {
  int tile0 = blockIdx.x * 64;
  if (tile0 >= nal[3]) return;
  int t = 0;
  #pragma unroll
  for (int i = 1; i < 3; i++) t += (tile0 >= nal[i]);

  __shared__ __align__(16) u16 ab[64 * K];   // f16, XOR-swizzled rows (G4)
  __shared__ int s_nid[64];
  int tid = threadIdx.x;
  int lane = tid & 63, w = tid >> 6;
  int l15 = lane & 15, l4 = lane >> 4;

  if (tid < 64) s_nid[tid] = nsorted[tile0 + tid];
  __syncthreads();

  { // stage: thread (row=tid>>2, quarter=tid&3) -> K/4 elements -> f16 LDS
    int r = tid >> 2, q4 = tid & 3;
    int nid = s_nid[r];
    char* rowp = (char*)ab + r * (2 * K);
    int sw = (r & 7) << 4;
    int base = q4 * (K / 2);               // byte base within row
    if (nid >= 0) {
      if (AHALF) {
        const f16x8* ap = (const f16x8*)(Ah + (size_t)nid * K + q4 * (K / 4));
        #pragma unroll
        for (int i = 0; i < K / 32; i++)
          *(f16x8*)(rowp + ((base + 16 * i) ^ sw)) = ap[i];
      } else {
        const float4* ap = (const float4*)(Af + (size_t)nid * K + q4 * (K / 4));
        #pragma unroll
        for (int i = 0; i < K / 32; i++) {
          float4 a = ap[2 * i], a2 = ap[2 * i + 1];
          f16x8 hv;
          hv[0] = (f16)a.x;  hv[1] = (f16)a.y;  hv[2] = (f16)a.z;  hv[3] = (f16)a.w;
          hv[4] = (f16)a2.x; hv[5] = (f16)a2.y; hv[6] = (f16)a2.z; hv[7] = (f16)a2.w;
          *(f16x8*)(rowp + ((base + 16 * i) ^ sw)) = hv;
        }
      }
    } else {
      f16x8 z;
      #pragma unroll
      for (int j = 0; j < 8; j++) z[j] = (f16)0.f;
      #pragma unroll
      for (int i = 0; i < K / 32; i++)
        *(f16x8*)(rowp + ((base + 16 * i) ^ sw)) = z;
    }
  }
  __syncthreads();

  f32x4 acc[4][2];
  #pragma unroll
  for (int ni = 0; ni < 2; ni++) {
    float bc = bias[t * HD + w * 32 + ni * 16 + l15];
    #pragma unroll
    for (int mi = 0; mi < 4; mi++) {
      acc[mi][ni][0] = bc; acc[mi][ni][1] = bc;
      acc[mi][ni][2] = bc; acc[mi][ni][3] = bc;
    }
  }
  const u16* Wt = WT + (size_t)t * HD * K;
  #pragma unroll
  for (int ks = 0; ks < K / 32; ks++) {
    int k0 = ks * 32 + 8 * l4;
    f16x8 bf[2], af[4];
    #pragma unroll
    for (int ni = 0; ni < 2; ni++)
      bf[ni] = *(const f16x8*)(Wt + (size_t)(w * 32 + ni * 16 + l15) * K + k0);
    #pragma unroll
    for (int mi = 0; mi < 4; mi++) {
      int row = mi * 16 + l15;
      af[mi] = *(const f16x8*)((const char*)ab + row * (2 * K) +
                               ((2 * k0) ^ ((row & 7) << 4)));
    }
    #pragma unroll
    for (int mi = 0; mi < 4; mi++)
      #pragma unroll
      for (int ni = 0; ni < 2; ni++)
        acc[mi][ni] = __builtin_amdgcn_mfma_f32_16x16x32_f16(af[mi], bf[ni],
                                                             acc[mi][ni], 0, 0, 0);
  }

  float alpha = 0.f;
  if (ACT == 2) alpha = 1.f / (1.f + expf(-skip_l[t]));
  #pragma unroll
  for (int mi = 0; mi < 4; mi++)
    #pragma unroll
    for (int r = 0; r < 4; r++) {
      int rowl = mi * 16 + l4 * 4 + r;
      int nid = s_nid[rowl];
      if (nid >= 0) {
        #pragma unroll
        for (int ni = 0; ni < 2; ni++) {
          int c = w * 32 + ni * 16 + l15;
          float val = acc[mi][ni][r];
          if (ACT == 0) val = tanhf(val);
          if (ACT == 2) {
            float xo = xin[(size_t)nid * HD + c];
            val = val * alpha + xo * (1.f - alpha);
          }
          if (out_f) out_f[(size_t)nid * HD + c] = val;
          if (out_h) out_h[(size_t)nid * HD + c] =
              __builtin_bit_cast(u16, (f16)val);
        }
      }
    }
}

// MFMA edge kernel, f16 gathers. 512 threads / 8 waves; wave w owns combined
// cols [w*32, w*32+32): w<4 -> k' (to LDS for scores), w>=4 -> v' (to global).
// acc[4][2] = 32 AGPR/wave (~40 regs total) -> high occupancy; no prefetch
// (R13/R14 A/B showed any long-lived register state costs more than it hides).
__global__ __launch_bounds__(512) void k_edge_gemm(
    const u16* __restrict__ x_h, const u16* __restrict__ rte_h,
    const u16* __restrict__ Wcomb, const float* __restrict__ bcomb,
    const u16* __restrict__ q_h, const int* __restrict__ esorted,
    const int* __restrict__ bal, const int* __restrict__ src,
    const int* __restrict__ dst, const int* __restrict__ etime,
    const int* __restrict__ ntype, const int* __restrict__ rank,
    const float* __restrict__ pri_l,
    u16* __restrict__ score_h, u16* __restrict__ v_csr) {
  int tile0 = blockIdx.x * 64;
  if (tile0 >= bal[12]) return;
  int b = 0;
  #pragma unroll
  for (int i = 1; i < 12; i++) b += (tile0 >= bal[i]);
  int st = b >> 2, rt = b & 3;

  __shared__ __align__(16) u16 albuf[64 * HD];   // 16 KB
  __shared__ int s_eid[64];
  __shared__ int s_dst[64];
  __shared__ int s_rank[64];
  int tid = threadIdx.x;
  int lane = tid & 63, w = tid >> 6;
  int l15 = lane & 15, l4 = lane >> 4;

  if (tid < 64) {
    int e = esorted[tile0 + tid];
    s_eid[tid] = e;
    s_dst[tid] = (e >= 0) ? dst[e] : 0;
    s_rank[tid] = (e >= 0) ? rank[e] : 0;
  }
  __syncthreads();

  { // stage: row = tid>>3, part = tid&7 -> 16 f16 each (2x 16B gathers)
    int r = tid >> 3, p = tid & 7;
    int e = s_eid[r];
    char* rowp = (char*)albuf + r * 256;
    int sw = (r & 7) << 4;
    if (e >= 0) {
      const f16x8* xs = (const f16x8*)(x_h + (size_t)src[e] * HD + p * 16);
      const f16x8* rp = (const f16x8*)(rte_h + (size_t)etime[e] * HD + p * 16);
      f16x8 h0 = xs[0] + rp[0];
      f16x8 h1 = xs[1] + rp[1];
      *(f16x8*)(rowp + ((p * 32) ^ sw))      = h0;
      *(f16x8*)(rowp + ((p * 32 + 16) ^ sw)) = h1;
    } else {
      f16x8 z;
      #pragma unroll
      for (int j = 0; j < 8; j++) z[j] = (f16)0.f;
      *(f16x8*)(rowp + ((p * 32) ^ sw))      = z;
      *(f16x8*)(rowp + ((p * 32 + 16) ^ sw)) = z;
    }
  }
  __syncthreads();

  f32x4 acc[4][2];
  #pragma unroll
  for (int ni = 0; ni < 2; ni++) {
    float bc = bcomb[b * 256 + w * 32 + ni * 16 + l15];
    #pragma unroll
    for (int mi = 0; mi < 4; mi++) {
      acc[mi][ni][0] = bc; acc[mi][ni][1] = bc;
      acc[mi][ni][2] = bc; acc[mi][ni][3] = bc;
    }
  }
  const u16* Wb = Wcomb + (size_t)b * 256 * HD;
  #pragma unroll
  for (int ks = 0; ks < 4; ks++) {
    int k0 = ks * 32 + 8 * l4;
    f16x8 bf[2], af[4];
    #pragma unroll
    for (int ni = 0; ni < 2; ni++)
      bf[ni] = *(const f16x8*)(Wb + (size_t)(w * 32 + ni * 16 + l15) * HD + k0);
    #pragma unroll
    for (int mi = 0; mi < 4; mi++) {
      int row = mi * 16 + l15;
      af[mi] = *(const f16x8*)((const char*)albuf + row * 256 +
                               ((2 * k0) ^ ((row & 7) << 4)));
    }
    #pragma unroll
    for (int mi = 0; mi < 4; mi++)
      #pragma unroll
      for (int ni = 0; ni < 2; ni++)
        acc[mi][ni] = __builtin_amdgcn_mfma_f32_16x16x32_f16(af[mi], bf[ni],
                                                             acc[mi][ni], 0, 0, 0);
  }
  __syncthreads();

  if (w < 4) {       // k' cols [w*32, w*32+32) -> albuf f16 (swizzled)
    #pragma unroll
    for (int mi = 0; mi < 4; mi++)
      #pragma unroll
      for (int r = 0; r < 4; r++) {
        int row = mi * 16 + l4 * 4 + r;
        char* rowp = (char*)albuf + row * 256;
        int sw = (row & 7) << 4;
        #pragma unroll
        for (int ni = 0; ni < 2; ni++) {
          int c = w * 32 + ni * 16 + l15;
          *(u16*)(rowp + ((2 * c) ^ sw)) =
              __builtin_bit_cast(u16, (f16)acc[mi][ni][r]);
        }
      }
  } else {           // v' cols [(w-4)*32, ..) -> v_csr[rank] f16
    int wv = w - 4;
    #pragma unroll
    for (int mi = 0; mi < 4; mi++)
      #pragma unroll
      for (int r = 0; r < 4; r++) {
        int rowl = mi * 16 + l4 * 4 + r;
        if (s_eid[rowl] >= 0) {
          u16* vp = v_csr + (size_t)s_rank[rowl] * HD + wv * 32 + l15;
          #pragma unroll
          for (int ni = 0; ni < 2; ni++)
            vp[ni * 16] = __builtin_bit_cast(u16, (f16)acc[mi][ni][r]);
        }
      }
  }
  __syncthreads();

  // scores: 512 (edge, head) tasks, one per thread; write score_h[rank] (f16)
  {
    int e = tid >> 3, h = tid & 7;
    if (s_eid[e] >= 0) {
      int d = s_dst[e];
      int tt = ntype[d];
      const char* rowp = (const char*)albuf + e * 256;
      int sw = (e & 7) << 4;
      f16x8 kh0 = *(const f16x8*)(rowp + ((h * 32) ^ sw));
      f16x8 kh1 = *(const f16x8*)(rowp + ((h * 32 + 16) ^ sw));
      const f16x8* qp = (const f16x8*)(q_h + (size_t)d * HD + h * 16);
      f16x8 qa = qp[0], qb = qp[1];
      float sc = 0.f;
      #pragma unroll
      for (int j = 0; j < 8; j++) sc += (float)qa[j] * (float)kh0[j];
      #pragma unroll
      for (int j = 0; j < 8; j++) sc += (float)qb[j] * (float)kh1[j];
      float pri = pri_l[((tt * R_N + rt) * T_N + st) * NH + h];
      score_h[(size_t)s_rank[e] * NH + h] =
          __builtin_bit_cast(u16, (f16)(sc * pri * 0.25f));
    }
  }
}

// Per-node (1 wave): segment softmax + weighted v-sum + exact GELU -> g (f16).
__global__ void k_aggr(const int* __restrict__ row_ptr,
                       const u16* __restrict__ score_h,
                       const u16* __restrict__ v_csr,
                       u16* __restrict__ g_h, int N) {
  int n = blockIdx.x;
  int lane = threadIdx.x;
  int start = row_ptr[n], end = row_ptr[n + 1];

  int h = lane & 7, jj = lane >> 3;
  float m = -3.0e38f;
  for (int idx = start + jj; idx < end; idx += 8)
    m = fmaxf(m, (float)__builtin_bit_cast(f16, score_h[(size_t)idx * NH + h]));
  #pragma unroll
  for (int off = 8; off < 64; off <<= 1) m = fmaxf(m, __shfl_xor(m, off));
  float z = 0.f;
  for (int idx = start + jj; idx < end; idx += 8)
    z += expf((float)__builtin_bit_cast(f16, score_h[(size_t)idx * NH + h]) - m);
  #pragma unroll
  for (int off = 8; off < 64; off <<= 1) z += __shfl_xor(z, off);

  int myh = lane >> 3;
  float md = __shfl(m, myh);
  float zd = __shfl(z, myh);
  float rz = (zd > 0.f) ? 1.f / zd : 0.f;

  float a0 = 0.f, a1 = 0.f;
  for (int idx = start; idx < end; idx++) {
    float sc = (float)__builtin_bit_cast(f16, score_h[(size_t)idx * NH + myh]);
    float wgt = expf(sc - md) * rz;
    u32 v2 = ((const u32*)(v_csr + (size_t)idx * HD))[lane];
    float v0 = (float)__builtin_bit_cast(f16, (u16)(v2 & 0xffffu));
    float v1 = (float)__builtin_bit_cast(f16, (u16)(v2 >> 16));
    a0 = fmaf(wgt, v0, a0);
    a1 = fmaf(wgt, v1, a1);
  }

  a0 = 0.5f * a0 * (1.f + erff(a0 * 0.7071067811865475f));
  a1 = 0.5f * a1 * (1.f + erff(a1 * 0.7071067811865475f));
  u32 pk = (u32)__builtin_bit_cast(u16, (f16)a0)
         | ((u32)__builtin_bit_cast(u16, (f16)a1) << 16);
  ((u32*)(g_h + (size_t)n * HD))[lane] = pk;
}

}  // namespace

extern "C" void kernel_launch(void* const* d_in, const int* in_sizes, int n_in,
                              void* d_out, int out_size, void* d_ws, size_t ws_size,
                              hipStream_t stream) {
  const float* node_feature = (const float*)d_in[0];
  const int*   node_type    = (const int*)d_in[1];
  const int*   edge_time    = (const int*)d_in[2];
  const int*   edge_type    = (const int*)d_in[3];
  const int*   edge_index   = (const int*)d_in[4];
  const float* adapt_W      = (const float*)d_in[5];
  const float* adapt_b      = (const float*)d_in[6];
  const float* Wk           = (const float*)d_in[7];
  const float* bk           = (const float*)d_in[8];
  const float* Wq           = (const float*)d_in[9];
  const float* bq           = (const float*)d_in[10];
  const float* Wv           = (const float*)d_in[11];
  const float* bv           = (const float*)d_in[12];
  const float* Wa           = (const float*)d_in[13];
  const float* ba           = (const float*)d_in[14];
  const float* rel_pri      = (const float*)d_in[15];
  const float* rel_att      = (const float*)d_in[16];
  const float* rel_msg      = (const float*)d_in[17];
  const float* skip         = (const float*)d_in[18];
  const float* rte_emb      = (const float*)d_in[19];
  const float* rte_W        = (const float*)d_in[20];
  const float* rte_b        = (const float*)d_in[21];

  const int N = in_sizes[1];
  const int E = in_sizes[2];
  const int* src  = edge_index;
  const int* dstp = edge_index + E;

  float* x = (float*)d_out;

  size_t off = 0;
  auto carve = [&](size_t bytes) -> void* {
    void* p = (char*)d_ws + off;
    off += (bytes + 255) & ~(size_t)255;
    return p;
  };
  // ~252 MB total (R8's 290MB crashed; stay under 256MiB).
  u16*   v_csr   = (u16*)  carve((size_t)E * HD * 2);   // 204.8 MB, CSR-perm
  u16*   score_h = (u16*)  carve((size_t)E * NH * 2);   // 12.8 MB, CSR-perm
  u16*   x_h     = (u16*)  carve((size_t)N * HD * 2);   // 12.8 MB
  u16*   qg      = (u16*)  carve((size_t)N * HD * 2);   // 12.8 MB: q_h then g_h
  u16*   rte_h   = (u16*)  carve((size_t)MAXT * HD * 2);
  u16*   Wcomb   = (u16*)  carve((size_t)12 * 256 * HD * 2);
  float* bcomb   = (float*)carve((size_t)12 * 256 * 4);
  u16*   adaptWT = (u16*)  carve((size_t)T_N * HD * IND * 2);
  u16*   WqT     = (u16*)  carve((size_t)2 * T_N * HD * HD * 2);
  u16*   WaT     = (u16*)  carve((size_t)2 * T_N * HD * HD * 2);
  int*   row_ptr = (int*)  carve((size_t)(N + 1) * 4);
  int*   cnt     = (int*)  carve((size_t)(N + 1) * 4);
  int*   rank    = (int*)  carve((size_t)E * 4);
  int*   bsums   = (int*)  carve(1024 * 4);
  int*   bcnt    = (int*)  carve(16 * 4);
  int*   bal     = (int*)  carve(16 * 4);
  int*   bcur    = (int*)  carve(16 * 4);
  int*   ncnt    = (int*)  carve(16 * 4);
  int*   nal     = (int*)  carve(16 * 4);
  int*   ncur    = (int*)  carve(16 * 4);
  const int EP = E + 12 * 64;
  const int NP = N + 3 * 64;
  int*   esorted = (int*)  carve((size_t)EP * 4);
  int*   nsorted = (int*)  carve((size_t)NP * 4);
  (void)ws_size; (void)n_in; (void)out_size;

  const int gE  = (E + 255) / 256;
  const int gN1 = (N + 1 + 255) / 256;
  const int gN  = (N + 255) / 256;
  const int gEP = (EP + 255) / 256;
  const int gNP = (NP + 255) / 256;
  const int etiles = (EP + 63) / 64;
  const int ntiles = (NP + 63) / 64;

  // CSR row_ptr + rank permutation (dst order)
  k_fill_i32<<<gN1, 256, 0, stream>>>(cnt, 0, N + 1);
  k_hist_dst<<<gE, 256, 0, stream>>>(dstp, cnt, E);
  k_scan_a<<<gN1, 256, 0, stream>>>(cnt, row_ptr, bsums, N + 1);
  k_scan_b<<<1, 256, 0, stream>>>(bsums, gN1);
  k_scan_c<<<gN1, 256, 0, stream>>>(row_ptr, bsums, N + 1);
  k_copy_i32<<<gN, 256, 0, stream>>>(cnt, row_ptr, N);
  k_rank_dst<<<gE, 256, 0, stream>>>(dstp, cnt, rank, E);

  // edge (src_type, rel_type) buckets (original order within bucket)
  k_fill_i32<<<1, 256, 0, stream>>>(bcnt, 0, 16);
  k_bhist<<<gE, 256, 0, stream>>>(src, edge_type, node_type, bcnt, E);
  k_bscan<<<1, 64, 0, stream>>>(bcnt, bal, bcur);
  k_fill_i32<<<gEP, 256, 0, stream>>>(esorted, -1, EP);
  k_bscatter<<<gE, 256, 0, stream>>>(src, edge_type, node_type, bcur, esorted, E);

  // node type buckets
  k_fill_i32<<<1, 256, 0, stream>>>(ncnt, 0, 16);
  k_nhist<<<gN, 256, 0, stream>>>(node_type, ncnt, N);
  k_nscan<<<1, 64, 0, stream>>>(ncnt, nal, ncur);
  k_fill_i32<<<gNP, 256, 0, stream>>>(nsorted, -1, NP);
  k_nscatter<<<gN, 256, 0, stream>>>(node_type, ncur, nsorted, N);

  // f16 transposed weights
  k_transp<<<dim3(HD, T_N), 128, 0, stream>>>(adapt_W, adaptWT, IND, HD);
  for (int l = 0; l < 2; l++) {
    k_transp<<<dim3(HD, T_N), 128, 0, stream>>>(
        Wq + (size_t)l * T_N * HD * HD, WqT + (size_t)l * T_N * HD * HD, HD, HD);
    k_transp<<<dim3(HD, T_N), 128, 0, stream>>>(
        Wa + (size_t)l * T_N * HD * HD, WaT + (size_t)l * T_N * HD * HD, HD, HD);
  }

  // adapt: x = tanh(node_feature @ adapt_W[t] + adapt_b[t]); also x_h mirror
  k_ngemm<IND, 0, false><<<ntiles, 256, 0, stream>>>(
      node_feature, nullptr, adaptWT, adapt_b, nsorted, nal, nullptr,
      x, x_h, nullptr);

  for (int l = 0; l < 2; l++) {
    k_rte<<<MAXT, 64, 0, stream>>>(rte_emb, rte_W, rte_b, rte_h, l);
    k_wcomb<<<12 * 256, 128, 0, stream>>>(Wk, Wv, bk, bv, rel_att, rel_msg,
                                          Wcomb, bcomb, l);
    // q (f16 -> qg), input from x_h
    k_ngemm<HD, 1, true><<<ntiles, 256, 0, stream>>>(
        nullptr, x_h, WqT + (size_t)l * T_N * HD * HD, bq + (size_t)l * T_N * HD,
        nsorted, nal, nullptr, nullptr, qg, nullptr);
    k_edge_gemm<<<etiles, 512, 0, stream>>>(x_h, rte_h, Wcomb, bcomb, qg,
                                            esorted, bal, src, dstp, edge_time,
                                            node_type, rank,
                                            rel_pri + (size_t)l * T_N * R_N * T_N * NH,
                                            score_h, v_csr);
    // g (f16) overwrites qg -- q_h dead after edge_gemm (stream-ordered)
    k_aggr<<<N, 64, 0, stream>>>(row_ptr, score_h, v_csr, qg, N);
    // out-linear + skip blend; reads g (f16), writes x fp32 + x_h mirror
    k_ngemm<HD, 2, true><<<ntiles, 256, 0, stream>>>(
        nullptr, qg, WaT + (size_t)l * T_N * HD * HD, ba + (size_t)l * T_N * HD,
        nsorted, nal, skip + (size_t)l * T_N, x, x_h, x);
  }
}

// Round 17
// 802.190 us; speedup vs baseline: 1.4329x; 1.1085x over previous
//
#include <hip/hip_runtime.h>
#include <cstdint>
#include <cstddef>

// HGT forward (2 layers) on MI355X.
// R17: dispatch consolidation on top of R16 (= R11, best: 889us, edge 187us).
// Setup chain 17->8 kernels (fused fills / histograms / small scans /
// scatters), 5 transposes -> 1, rte+wcomb batched across both layers
// (doubled buffers, +1.7MB ws). Per-edge/per-node math untouched -> absmax
// must stay 2.441406e-4. Edge kernel frozen (R10/R12/R13/R14 escapes all
// A/B-falsified; R11 shape is the empirical optimum).

namespace {

constexpr int T_N  = 3;
constexpr int R_N  = 4;
constexpr int HD   = 128;
constexpr int IND  = 256;
constexpr int NH   = 8;
constexpr int MAXT = 240;

typedef unsigned short u16;
typedef unsigned int   u32;
typedef _Float16 f16;
typedef __attribute__((ext_vector_type(8))) _Float16 f16x8;
typedef __attribute__((ext_vector_type(4))) float    f32x4;

// ----------------------------- setup kernels -------------------------------
// one fill to rule them all: cnt[0..nCnt)=0, esorted[0..nE)=-1,
// nsorted[0..nN)=-1, bcnt/ncnt[0..15]=0
__global__ void k_fill_all(int* __restrict__ cnt, int* __restrict__ esorted,
                           int* __restrict__ nsorted, int* __restrict__ bcnt,
                           int* __restrict__ ncnt, int nCnt, int nE, int nN) {
  int i = blockIdx.x * 256 + threadIdx.x;
  if (i < nCnt) cnt[i] = 0;
  if (i < nE)  esorted[i] = -1;
  if (i < nN)  nsorted[i] = -1;
  if (i < 16) { bcnt[i] = 0; ncnt[i] = 0; }
}
// fused histograms: per-dst degree (global atomics), 12-bucket edge hist,
// 3-bucket node hist (both LDS-aggregated)
__global__ void k_hist_all(const int* __restrict__ src, const int* __restrict__ etype,
                           const int* __restrict__ ntype, const int* __restrict__ dst,
                           int* __restrict__ cnt, int* __restrict__ bcnt,
                           int* __restrict__ ncnt, int E, int N) {
  __shared__ int loc12[12];
  __shared__ int loc3[3];
  int tid = threadIdx.x;
  if (tid < 12) loc12[tid] = 0;
  if (tid < 3)  loc3[tid] = 0;
  __syncthreads();
  int i = blockIdx.x * 256 + tid;
  if (i < E) {
    atomicAdd(&cnt[dst[i]], 1);
    int b = ntype[src[i]] * R_N + etype[i];
    atomicAdd(&loc12[b], 1);
  }
  if (i < N) atomicAdd(&loc3[ntype[i]], 1);
  __syncthreads();
  if (tid < 12) atomicAdd(&bcnt[tid], loc12[tid]);
  if (tid < 3)  atomicAdd(&ncnt[tid], loc3[tid]);
}
__global__ void k_scan_a(const int* __restrict__ in, int* __restrict__ out,
                         int* __restrict__ bsums, int n) {
  __shared__ int s[256];
  int gid = blockIdx.x * 256 + threadIdx.x;
  int v = (gid < n) ? in[gid] : 0;
  s[threadIdx.x] = v;
  __syncthreads();
  for (int off = 1; off < 256; off <<= 1) {
    int t = (threadIdx.x >= off) ? s[threadIdx.x - off] : 0;
    __syncthreads();
    s[threadIdx.x] += t;
    __syncthreads();
  }
  if (gid < n) out[gid] = s[threadIdx.x] - v;
  if (threadIdx.x == 255) bsums[blockIdx.x] = s[255];
}
__global__ void k_scan_b(int* __restrict__ bsums, int nb) {
  __shared__ int s[256];
  int v = (threadIdx.x < nb) ? bsums[threadIdx.x] : 0;
  s[threadIdx.x] = v;
  __syncthreads();
  for (int off = 1; off < 256; off <<= 1) {
    int t = (threadIdx.x >= off) ? s[threadIdx.x - off] : 0;
    __syncthreads();
    s[threadIdx.x] += t;
    __syncthreads();
  }
  if (threadIdx.x < nb) bsums[threadIdx.x] = s[threadIdx.x] - v;
}
// scan_c fused with the row_ptr->cnt copy (cnt = final row_ptr value)
__global__ void k_scan_c_copy(int* __restrict__ out, const int* __restrict__ bsums,
                              int* __restrict__ cnt, int n, int N) {
  int gid = blockIdx.x * 256 + threadIdx.x;
  if (gid < n) {
    int v = out[gid] + bsums[blockIdx.x];
    out[gid] = v;
    if (gid < N) cnt[gid] = v;
  }
}
// tiny 12-bucket + 3-bucket exclusive scans (64-aligned)
__global__ void k_scan_small(const int* __restrict__ bcnt, int* __restrict__ bal,
                             int* __restrict__ bcur, const int* __restrict__ ncnt,
                             int* __restrict__ nal, int* __restrict__ ncur) {
  if (threadIdx.x == 0 && blockIdx.x == 0) {
    int run = 0;
    for (int b = 0; b < 12; b++) {
      bal[b] = run; bcur[b] = run;
      run += (bcnt[b] + 63) & ~63;
    }
    bal[12] = run;
    run = 0;
    for (int t = 0; t < 3; t++) {
      nal[t] = run; ncur[t] = run;
      run += (ncnt[t] + 63) & ~63;
    }
    nal[3] = run;
  }
}
// fused: rank[e] (CSR position), edge bucket scatter, node type scatter
__global__ void k_scatter_all(const int* __restrict__ src, const int* __restrict__ etype,
                              const int* __restrict__ ntype, const int* __restrict__ dst,
                              int* __restrict__ cnt, int* __restrict__ rank,
                              int* __restrict__ bcur, int* __restrict__ esorted,
                              int* __restrict__ ncur, int* __restrict__ nsorted,
                              int E, int N) {
  __shared__ int loc12[12], base12[12];
  __shared__ int loc3[3],  base3[3];
  int tid = threadIdx.x;
  if (tid < 12) loc12[tid] = 0;
  if (tid < 3)  loc3[tid] = 0;
  __syncthreads();
  int i = blockIdx.x * 256 + tid;
  int b = 0, lpos = 0, t = 0, lpos3 = 0;
  if (i < E) {
    rank[i] = atomicAdd(&cnt[dst[i]], 1);
    b = ntype[src[i]] * R_N + etype[i];
    lpos = atomicAdd(&loc12[b], 1);
  }
  if (i < N) {
    t = ntype[i];
    lpos3 = atomicAdd(&loc3[t], 1);
  }
  __syncthreads();
  if (tid < 12) { int c = loc12[tid]; base12[tid] = (c > 0) ? atomicAdd(&bcur[tid], c) : 0; }
  if (tid < 3)  { int c = loc3[tid];  base3[tid]  = (c > 0) ? atomicAdd(&ncur[tid], c) : 0; }
  __syncthreads();
  if (i < E) esorted[base12[b] + lpos] = i;
  if (i < N) nsorted[base3[t] + lpos3] = i;
}

// fused transpose+f16 for all 5 weight tensors (adapt K=256; Wq/Wa l=0,1
// K=128). dst[(t..)*Cd + c][k] = src[(t..)*Kd + k][c], Cd = 128 for all.
__global__ void k_transp_all(const float* __restrict__ adapt_W,
                             const float* __restrict__ Wq,
                             const float* __restrict__ Wa,
                             u16* __restrict__ adaptWT, u16* __restrict__ WqT,
                             u16* __restrict__ WaT) {
  int c = blockIdx.x;          // 0..127
  int y = blockIdx.y;          // 0..14: group = y/T_N, t = y%T_N
  int g = y / T_N, t = y % T_N;
  const float* srcp;
  u16* dstp;
  int Kd;
  if (g == 0) {
    srcp = adapt_W + (size_t)t * IND * HD;
    dstp = adaptWT + (size_t)t * HD * IND;
    Kd = IND;
  } else if (g <= 2) {
    int l = g - 1;
    srcp = Wq + ((size_t)l * T_N + t) * HD * HD;
    dstp = WqT + ((size_t)l * T_N + t) * HD * HD;
    Kd = HD;
  } else {
    int l = g - 3;
    srcp = Wa + ((size_t)l * T_N + t) * HD * HD;
    dstp = WaT + ((size_t)l * T_N + t) * HD * HD;
    Kd = HD;
  }
  for (int k = threadIdx.x; k < Kd; k += blockDim.x)
    dstp[(size_t)c * Kd + k] =
        __builtin_bit_cast(u16, (f16)srcp[(size_t)k * HD + c]);
}

// ------------------------------ math kernels -------------------------------
// rte table, BOTH layers -> f16 [2][240][128]; grid 480
__global__ void k_rte(const float* __restrict__ emb, const float* __restrict__ W,
                      const float* __restrict__ bias, u16* __restrict__ out) {
  int bx = blockIdx.x;
  int l = bx / MAXT, t = bx % MAXT;
  int lane = threadIdx.x;
  __shared__ __align__(16) float s[2 * HD];
  ((float4*)s)[lane] = ((const float4*)(emb + (size_t)t * 2 * HD))[lane];
  __syncthreads();
  const float* Wl = W + (size_t)l * 2 * HD * HD;
  float o0 = bias[l * HD + 2 * lane];
  float o1 = bias[l * HD + 2 * lane + 1];
  #pragma unroll 4
  for (int k = 0; k < 2 * HD; k++) {
    float xv = s[k];
    float2 w = ((const float2*)(Wl + (size_t)k * HD))[lane];
    o0 = fmaf(xv, w.x, o0);
    o1 = fmaf(xv, w.y, o1);
  }
  u32 pk = (u32)__builtin_bit_cast(u16, (f16)o0)
         | ((u32)__builtin_bit_cast(u16, (f16)o1) << 16);
  ((u32*)out)[((size_t)l * MAXT + t) * 64 + lane] = pk;
}

// Combined per-(type,rel) matrices, BOTH layers; grid 2*12*256
__global__ void k_wcomb(const float* __restrict__ Wk, const float* __restrict__ Wv,
                        const float* __restrict__ bk, const float* __restrict__ bv,
                        const float* __restrict__ Ratt, const float* __restrict__ Rmsg,
                        u16* __restrict__ Wcomb, float* __restrict__ bcomb) {
  int gbc = blockIdx.x;
  int l  = gbc / (12 * 256);
  int bc = gbc % (12 * 256);
  int b  = bc >> 8;
  int c  = bc & 255;
  int st = b >> 2, rt = b & 3;
  int k  = threadIdx.x;
  bool isv = (c >= HD);
  int c0 = isv ? c - HD : c;
  int h  = c0 >> 4, cc = c0 & 15;
  const float* W = (isv ? Wv : Wk) + (((size_t)(l * T_N + st) * HD) + k) * HD + h * 16;
  const float* A = (isv ? Rmsg : Ratt) + (((size_t)(l * R_N + rt) * NH + h) * 16) * 16 + cc;
  float s = 0.f;
  #pragma unroll
  for (int d = 0; d < 16; d++) s = fmaf(W[d], A[d * 16], s);
  Wcomb[(((size_t)l * 12 + b) * 256 + c) * HD + k] = __builtin_bit_cast(u16, (f16)s);
  if (k == 0) {
    const float* bb = (isv ? bv : bk) + (size_t)(l * T_N + st) * HD + h * 16;
    float sb = 0.f;
    #pragma unroll
    for (int d = 0; d < 16; d++) sb = fmaf(bb[d], A[d * 16], sb);
    bcomb[((size_t)l * 12 + b) * 256 + c] = sb;
  }
}

// Generic MFMA node linear over type-sorted buckets (unchanged from R16).
template<int K, int ACT, bool AHALF>
__global__ __launch_bounds__(256) void k_ngemm(
    const float* __restrict__ Af, const u16* __restrict__ Ah,
    const u16* __restrict__ WT, const float* __restrict__ bias,
    const int* __restrict__ nsorted, const int* __restrict__ nal,
    const float* __restrict__ skip_l,
    float* __restrict__ out_f, u16* __restrict__ out_h,
    const float* __restrict__ xin) {
  int tile0 = blockIdx.x * 64;
  if (tile0 >= nal[3]) return;
  int t = 0;
  #pragma unroll
  for (int i = 1; i < 3; i++) t += (tile0 >= nal[i]);

  __shared__ __align__(16) u16 ab[64 * K];   // f16, XOR-swizzled rows (G4)
  __shared__ int s_nid[64];
  int tid = threadIdx.x;
  int lane = tid & 63, w = tid >> 6;
  int l15 = lane & 15, l4 = lane >> 4;

  if (tid < 64) s_nid[tid] = nsorted[tile0 + tid];
  __syncthreads();

  {
    int r = tid >> 2, q4 = tid & 3;
    int nid = s_nid[r];
    char* rowp = (char*)ab + r * (2 * K);
    int sw = (r & 7) << 4;
    int base = q4 * (K / 2);
    if (nid >= 0) {
      if (AHALF) {
        const f16x8* ap = (const f16x8*)(Ah + (size_t)nid * K + q4 * (K / 4));
        #pragma unroll
        for (int i = 0; i < K / 32; i++)
          *(f16x8*)(rowp + ((base + 16 * i) ^ sw)) = ap[i];
      } else {
        const float4* ap = (const float4*)(Af + (size_t)nid * K + q4 * (K / 4));
        #pragma unroll
        for (int i = 0; i < K / 32; i++) {
          float4 a = ap[2 * i], a2 = ap[2 * i + 1];
          f16x8 hv;
          hv[0] = (f16)a.x;  hv[1] = (f16)a.y;  hv[2] = (f16)a.z;  hv[3] = (f16)a.w;
          hv[4] = (f16)a2.x; hv[5] = (f16)a2.y; hv[6] = (f16)a2.z; hv[7] = (f16)a2.w;
          *(f16x8*)(rowp + ((base + 16 * i) ^ sw)) = hv;
        }
      }
    } else {
      f16x8 z;
      #pragma unroll
      for (int j = 0; j < 8; j++) z[j] = (f16)0.f;
      #pragma unroll
      for (int i = 0; i < K / 32; i++)
        *(f16x8*)(rowp + ((base + 16 * i) ^ sw)) = z;
    }
  }
  __syncthreads();

  f32x4 acc[4][2];
  #pragma unroll
  for (int ni = 0; ni < 2; ni++) {
    float bc = bias[t * HD + w * 32 + ni * 16 + l15];
    #pragma unroll
    for (int mi = 0; mi < 4; mi++) {
      acc[mi][ni][0] = bc; acc[mi][ni][1] = bc;
      acc[mi][ni][2] = bc; acc[mi][ni][3] = bc;
    }
  }
  const u16* Wt = WT + (size_t)t * HD * K;
  #pragma unroll
  for (int ks = 0; ks < K / 32; ks++) {
    int k0 = ks * 32 + 8 * l4;
    f16x8 bf[2], af[4];
    #pragma unroll
    for (int ni = 0; ni < 2; ni++)
      bf[ni] = *(const f16x8*)(Wt + (size_t)(w * 32 + ni * 16 + l15) * K + k0);
    #pragma unroll
    for (int mi = 0; mi < 4; mi++) {
      int row = mi * 16 + l15;
      af[mi] = *(const f16x8*)((const char*)ab + row * (2 * K) +
                               ((2 * k0) ^ ((row & 7) << 4)));
    }
    #pragma unroll
    for (int mi = 0; mi < 4; mi++)
      #pragma unroll
      for (int ni = 0; ni < 2; ni++)
        acc[mi][ni] = __builtin_amdgcn_mfma_f32_16x16x32_f16(af[mi], bf[ni],
                                                             acc[mi][ni], 0, 0, 0);
  }

  float alpha = 0.f;
  if (ACT == 2) alpha = 1.f / (1.f + expf(-skip_l[t]));
  #pragma unroll
  for (int mi = 0; mi < 4; mi++)
    #pragma unroll
    for (int r = 0; r < 4; r++) {
      int rowl = mi * 16 + l4 * 4 + r;
      int nid = s_nid[rowl];
      if (nid >= 0) {
        #pragma unroll
        for (int ni = 0; ni < 2; ni++) {
          int c = w * 32 + ni * 16 + l15;
          float val = acc[mi][ni][r];
          if (ACT == 0) val = tanhf(val);
          if (ACT == 2) {
            float xo = xin[(size_t)nid * HD + c];
            val = val * alpha + xo * (1.f - alpha);
          }
          if (out_f) out_f[(size_t)nid * HD + c] = val;
          if (out_h) out_h[(size_t)nid * HD + c] =
              __builtin_bit_cast(u16, (f16)val);
        }
      }
    }
}

// MFMA edge kernel (R11/R16 shape, frozen). 512 thr / 8 waves; wave w owns
// cols [w*32,w*32+32): w<4 -> k' (LDS, scores), w>=4 -> v' (global).
__global__ __launch_bounds__(512) void k_edge_gemm(
    const u16* __restrict__ x_h, const u16* __restrict__ rte_h,
    const u16* __restrict__ Wcomb, const float* __restrict__ bcomb,
    const u16* __restrict__ q_h, const int* __restrict__ esorted,
    const int* __restrict__ bal, const int* __restrict__ src,
    const int* __restrict__ dst, const int* __restrict__ etime,
    const int* __restrict__ ntype, const int* __restrict__ rank,
    const float* __restrict__ pri_l,
    u16* __restrict__ score_h, u16* __restrict__ v_csr) {
  int tile0 = blockIdx.x * 64;
  if (tile0 >= bal[12]) return;
  int b = 0;
  #pragma unroll
  for (int i = 1; i < 12; i++) b += (tile0 >= bal[i]);
  int st = b >> 2, rt = b & 3;

  __shared__ __align__(16) u16 albuf[64 * HD];   // 16 KB
  __shared__ int s_eid[64];
  __shared__ int s_dst[64];
  __shared__ int s_rank[64];
  int tid = threadIdx.x;
  int lane = tid & 63, w = tid >> 6;
  int l15 = lane & 15, l4 = lane >> 4;

  if (tid < 64) {
    int e = esorted[tile0 + tid];
    s_eid[tid] = e;
    s_dst[tid] = (e >= 0) ? dst[e] : 0;
    s_rank[tid] = (e >= 0) ? rank[e] : 0;
  }
  __syncthreads();

  {
    int r = tid >> 3, p = tid & 7;
    int e = s_eid[r];
    char* rowp = (char*)albuf + r * 256;
    int sw = (r & 7) << 4;
    if (e >= 0) {
      const f16x8* xs = (const f16x8*)(x_h + (size_t)src[e] * HD + p * 16);
      const f16x8* rp = (const f16x8*)(rte_h + (size_t)etime[e] * HD + p * 16);
      f16x8 h0 = xs[0] + rp[0];
      f16x8 h1 = xs[1] + rp[1];
      *(f16x8*)(rowp + ((p * 32) ^ sw))      = h0;
      *(f16x8*)(rowp + ((p * 32 + 16) ^ sw)) = h1;
    } else {
      f16x8 z;
      #pragma unroll
      for (int j = 0; j < 8; j++) z[j] = (f16)0.f;
      *(f16x8*)(rowp + ((p * 32) ^ sw))      = z;
      *(f16x8*)(rowp + ((p * 32 + 16) ^ sw)) = z;
    }
  }
  __syncthreads();

  f32x4 acc[4][2];
  #pragma unroll
  for (int ni = 0; ni < 2; ni++) {
    float bc = bcomb[b * 256 + w * 32 + ni * 16 + l15];
    #pragma unroll
    for (int mi = 0; mi < 4; mi++) {
      acc[mi][ni][0] = bc; acc[mi][ni][1] = bc;
      acc[mi][ni][2] = bc; acc[mi][ni][3] = bc;
    }
  }
  const u16* Wb = Wcomb + (size_t)b * 256 * HD;
  #pragma unroll
  for (int ks = 0; ks < 4; ks++) {
    int k0 = ks * 32 + 8 * l4;
    f16x8 bf[2], af[4];
    #pragma unroll
    for (int ni = 0; ni < 2; ni++)
      bf[ni] = *(const f16x8*)(Wb + (size_t)(w * 32 + ni * 16 + l15) * HD + k0);
    #pragma unroll
    for (int mi = 0; mi < 4; mi++) {
      int row = mi * 16 + l15;
      af[mi] = *(const f16x8*)((const char*)albuf + row * 256 +
                               ((2 * k0) ^ ((row & 7) << 4)));
    }
    #pragma unroll
    for (int mi = 0; mi < 4; mi++)
      #pragma unroll
      for (int ni = 0; ni < 2; ni++)
        acc[mi][ni] = __builtin_amdgcn_mfma_f32_16x16x32_f16(af[mi], bf[ni],
                                                             acc[mi][ni], 0, 0, 0);
  }
  __syncthreads();

  if (w < 4) {
    #pragma unroll
    for (int mi = 0; mi < 4; mi++)
      #pragma unroll
      for (int r = 0; r < 4; r++) {
        int row = mi * 16 + l4 * 4 + r;
        char* rowp = (char*)albuf + row * 256;
        int sw = (row & 7) << 4;
        #pragma unroll
        for (int ni = 0; ni < 2; ni++) {
          int c = w * 32 + ni * 16 + l15;
          *(u16*)(rowp + ((2 * c) ^ sw)) =
              __builtin_bit_cast(u16, (f16)acc[mi][ni][r]);
        }
      }
  } else {
    int wv = w - 4;
    #pragma unroll
    for (int mi = 0; mi < 4; mi++)
      #pragma unroll
      for (int r = 0; r < 4; r++) {
        int rowl = mi * 16 + l4 * 4 + r;
        if (s_eid[rowl] >= 0) {
          u16* vp = v_csr + (size_t)s_rank[rowl] * HD + wv * 32 + l15;
          #pragma unroll
          for (int ni = 0; ni < 2; ni++)
            vp[ni * 16] = __builtin_bit_cast(u16, (f16)acc[mi][ni][r]);
        }
      }
  }
  __syncthreads();

  {
    int e = tid >> 3, h = tid & 7;
    if (s_eid[e] >= 0) {
      int d = s_dst[e];
      int tt = ntype[d];
      const char* rowp = (const char*)albuf + e * 256;
      int sw = (e & 7) << 4;
      f16x8 kh0 = *(const f16x8*)(rowp + ((h * 32) ^ sw));
      f16x8 kh1 = *(const f16x8*)(rowp + ((h * 32 + 16) ^ sw));
      const f16x8* qp = (const f16x8*)(q_h + (size_t)d * HD + h * 16);
      f16x8 qa = qp[0], qb = qp[1];
      float sc = 0.f;
      #pragma unroll
      for (int j = 0; j < 8; j++) sc += (float)qa[j] * (float)kh0[j];
      #pragma unroll
      for (int j = 0; j < 8; j++) sc += (float)qb[j] * (float)kh1[j];
      float pri = pri_l[((tt * R_N + rt) * T_N + st) * NH + h];
      score_h[(size_t)s_rank[e] * NH + h] =
          __builtin_bit_cast(u16, (f16)(sc * pri * 0.25f));
    }
  }
}

// Per-node (1 wave): segment softmax + weighted v-sum + exact GELU -> g (f16).
__global__ void k_aggr(const int* __restrict__ row_ptr,
                       const u16* __restrict__ score_h,
                       const u16* __restrict__ v_csr,
                       u16* __restrict__ g_h, int N) {
  int n = blockIdx.x;
  int lane = threadIdx.x;
  int start = row_ptr[n], end = row_ptr[n + 1];

  int h = lane & 7, jj = lane >> 3;
  float m = -3.0e38f;
  for (int idx = start + jj; idx < end; idx += 8)
    m = fmaxf(m, (float)__builtin_bit_cast(f16, score_h[(size_t)idx * NH + h]));
  #pragma unroll
  for (int off = 8; off < 64; off <<= 1) m = fmaxf(m, __shfl_xor(m, off));
  float z = 0.f;
  for (int idx = start + jj; idx < end; idx += 8)
    z += expf((float)__builtin_bit_cast(f16, score_h[(size_t)idx * NH + h]) - m);
  #pragma unroll
  for (int off = 8; off < 64; off <<= 1) z += __shfl_xor(z, off);

  int myh = lane >> 3;
  float md = __shfl(m, myh);
  float zd = __shfl(z, myh);
  float rz = (zd > 0.f) ? 1.f / zd : 0.f;

  float a0 = 0.f, a1 = 0.f;
  for (int idx = start; idx < end; idx++) {
    float sc = (float)__builtin_bit_cast(f16, score_h[(size_t)idx * NH + myh]);
    float wgt = expf(sc - md) * rz;
    u32 v2 = ((const u32*)(v_csr + (size_t)idx * HD))[lane];
    float v0 = (float)__builtin_bit_cast(f16, (u16)(v2 & 0xffffu));
    float v1 = (float)__builtin_bit_cast(f16, (u16)(v2 >> 16));
    a0 = fmaf(wgt, v0, a0);
    a1 = fmaf(wgt, v1, a1);
  }

  a0 = 0.5f * a0 * (1.f + erff(a0 * 0.7071067811865475f));
  a1 = 0.5f * a1 * (1.f + erff(a1 * 0.7071067811865475f));
  u32 pk = (u32)__builtin_bit_cast(u16, (f16)a0)
         | ((u32)__builtin_bit_cast(u16, (f16)a1) << 16);
  ((u32*)(g_h + (size_t)n * HD))[lane] = pk;
}

}  // namespace

extern "C" void kernel_launch(void* const* d_in, const int* in_sizes, int n_in,
                              void* d_out, int out_size, void* d_ws, size_t ws_size,
                              hipStream_t stream) {
  const float* node_feature = (const float*)d_in[0];
  const int*   node_type    = (const int*)d_in[1];
  const int*   edge_time    = (const int*)d_in[2];
  const int*   edge_type    = (const int*)d_in[3];
  const int*   edge_index   = (const int*)d_in[4];
  const float* adapt_W      = (const float*)d_in[5];
  const float* adapt_b      = (const float*)d_in[6];
  const float* Wk           = (const float*)d_in[7];
  const float* bk           = (const float*)d_in[8];
  const float* Wq           = (const float*)d_in[9];
  const float* bq           = (const float*)d_in[10];
  const float* Wv           = (const float*)d_in[11];
  const float* bv           = (const float*)d_in[12];
  const float* Wa           = (const float*)d_in[13];
  const float* ba           = (const float*)d_in[14];
  const float* rel_pri      = (const float*)d_in[15];
  const float* rel_att      = (const float*)d_in[16];
  const float* rel_msg      = (const float*)d_in[17];
  const float* skip         = (const float*)d_in[18];
  const float* rte_emb      = (const float*)d_in[19];
  const float* rte_W        = (const float*)d_in[20];
  const float* rte_b        = (const float*)d_in[21];

  const int N = in_sizes[1];
  const int E = in_sizes[2];
  const int* src  = edge_index;
  const int* dstp = edge_index + E;

  float* x = (float*)d_out;

  size_t off = 0;
  auto carve = [&](size_t bytes) -> void* {
    void* p = (char*)d_ws + off;
    off += (bytes + 255) & ~(size_t)255;
    return p;
  };
  // ~254 MB total (stay under 256MiB; R8's 290MB crashed).
  u16*   v_csr   = (u16*)  carve((size_t)E * HD * 2);   // 204.8 MB, CSR-perm
  u16*   score_h = (u16*)  carve((size_t)E * NH * 2);   // 12.8 MB, CSR-perm
  u16*   x_h     = (u16*)  carve((size_t)N * HD * 2);   // 12.8 MB
  u16*   qg      = (u16*)  carve((size_t)N * HD * 2);   // 12.8 MB: q_h then g_h
  u16*   rte_h   = (u16*)  carve((size_t)2 * MAXT * HD * 2);       // both layers
  u16*   Wcomb   = (u16*)  carve((size_t)2 * 12 * 256 * HD * 2);   // both layers
  float* bcomb   = (float*)carve((size_t)2 * 12 * 256 * 4);
  u16*   adaptWT = (u16*)  carve((size_t)T_N * HD * IND * 2);
  u16*   WqT     = (u16*)  carve((size_t)2 * T_N * HD * HD * 2);
  u16*   WaT     = (u16*)  carve((size_t)2 * T_N * HD * HD * 2);
  int*   row_ptr = (int*)  carve((size_t)(N + 1) * 4);
  int*   cnt     = (int*)  carve((size_t)(N + 1) * 4);
  int*   rank    = (int*)  carve((size_t)E * 4);
  int*   bsums   = (int*)  carve(1024 * 4);
  int*   bcnt    = (int*)  carve(16 * 4);
  int*   bal     = (int*)  carve(16 * 4);
  int*   bcur    = (int*)  carve(16 * 4);
  int*   ncnt    = (int*)  carve(16 * 4);
  int*   nal     = (int*)  carve(16 * 4);
  int*   ncur    = (int*)  carve(16 * 4);
  const int EP = E + 12 * 64;
  const int NP = N + 3 * 64;
  int*   esorted = (int*)  carve((size_t)EP * 4);
  int*   nsorted = (int*)  carve((size_t)NP * 4);
  (void)ws_size; (void)n_in; (void)out_size;

  const int gE  = (E + 255) / 256;
  const int gN1 = (N + 1 + 255) / 256;
  const int gEP = (EP + 255) / 256;
  const int etiles = (EP + 63) / 64;
  const int ntiles = (NP + 63) / 64;

  // ---- setup: 8 dispatches (was 17) ----
  k_fill_all<<<gEP, 256, 0, stream>>>(cnt, esorted, nsorted, bcnt, ncnt,
                                      N + 1, EP, NP);
  k_hist_all<<<gE, 256, 0, stream>>>(src, edge_type, node_type, dstp,
                                     cnt, bcnt, ncnt, E, N);
  k_scan_a<<<gN1, 256, 0, stream>>>(cnt, row_ptr, bsums, N + 1);
  k_scan_b<<<1, 256, 0, stream>>>(bsums, gN1);
  k_scan_c_copy<<<gN1, 256, 0, stream>>>(row_ptr, bsums, cnt, N + 1, N);
  k_scan_small<<<1, 64, 0, stream>>>(bcnt, bal, bcur, ncnt, nal, ncur);
  k_scatter_all<<<gE, 256, 0, stream>>>(src, edge_type, node_type, dstp,
                                        cnt, rank, bcur, esorted,
                                        ncur, nsorted, E, N);

  // ---- weights/tables: 3 dispatches (was 9) ----
  k_transp_all<<<dim3(HD, T_N * 5), 128, 0, stream>>>(adapt_W, Wq, Wa,
                                                      adaptWT, WqT, WaT);
  k_rte<<<2 * MAXT, 64, 0, stream>>>(rte_emb, rte_W, rte_b, rte_h);
  k_wcomb<<<2 * 12 * 256, 128, 0, stream>>>(Wk, Wv, bk, bv, rel_att, rel_msg,
                                            Wcomb, bcomb);

  // adapt: x = tanh(node_feature @ adapt_W[t] + adapt_b[t]); also x_h mirror
  k_ngemm<IND, 0, false><<<ntiles, 256, 0, stream>>>(
      node_feature, nullptr, adaptWT, adapt_b, nsorted, nal, nullptr,
      x, x_h, nullptr);

  for (int l = 0; l < 2; l++) {
    // q (f16 -> qg), input from x_h
    k_ngemm<HD, 1, true><<<ntiles, 256, 0, stream>>>(
        nullptr, x_h, WqT + (size_t)l * T_N * HD * HD, bq + (size_t)l * T_N * HD,
        nsorted, nal, nullptr, nullptr, qg, nullptr);
    k_edge_gemm<<<etiles, 512, 0, stream>>>(
        x_h, rte_h + (size_t)l * MAXT * HD,
        Wcomb + (size_t)l * 12 * 256 * HD, bcomb + (size_t)l * 12 * 256,
        qg, esorted, bal, src, dstp, edge_time, node_type, rank,
        rel_pri + (size_t)l * T_N * R_N * T_N * NH, score_h, v_csr);
    // g (f16) overwrites qg -- q_h dead after edge_gemm (stream-ordered)
    k_aggr<<<N, 64, 0, stream>>>(row_ptr, score_h, v_csr, qg, N);
    // out-linear + skip blend; reads g (f16), writes x fp32 + x_h mirror
    k_ngemm<HD, 2, true><<<ntiles, 256, 0, stream>>>(
        nullptr, qg, WaT + (size_t)l * T_N * HD * HD, ba + (size_t)l * T_N * HD,
        nsorted, nal, skip + (size_t)l * T_N, x, x_h, x);
  }
}

// Round 18
// 800.621 us; speedup vs baseline: 1.4357x; 1.0020x over previous
//
#include <hip/hip_runtime.h>
#include <cstdint>
#include <cstddef>

// HGT forward (2 layers) on MI355X.
// R17: dispatch consolidation on top of R16 (= R11, best: 889us, edge 187us).
// Setup chain 17->8 kernels (fused fills / histograms / small scans /
// scatters), 5 transposes -> 1, rte+wcomb batched across both layers
// (doubled buffers, +1.7MB ws). Per-edge/per-node math untouched -> absmax
// must stay 2.441406e-4. Edge kernel frozen (R10/R12/R13/R14 escapes all
// A/B-falsified; R11 shape is the empirical optimum).

namespace {

constexpr int T_N  = 3;
constexpr int R_N  = 4;
constexpr int HD   = 128;
constexpr int IND  = 256;
constexpr int NH   = 8;
constexpr int MAXT = 240;

typedef unsigned short u16;
typedef unsigned int   u32;
typedef _Float16 f16;
typedef __attribute__((ext_vector_type(8))) _Float16 f16x8;
typedef __attribute__((ext_vector_type(4))) float    f32x4;

// ----------------------------- setup kernels -------------------------------
// one fill to rule them all: cnt[0..nCnt)=0, esorted[0..nE)=-1,
// nsorted[0..nN)=-1, bcnt/ncnt[0..15]=0
__global__ void k_fill_all(int* __restrict__ cnt, int* __restrict__ esorted,
                           int* __restrict__ nsorted, int* __restrict__ bcnt,
                           int* __restrict__ ncnt, int nCnt, int nE, int nN) {
  int i = blockIdx.x * 256 + threadIdx.x;
  if (i < nCnt) cnt[i] = 0;
  if (i < nE)  esorted[i] = -1;
  if (i < nN)  nsorted[i] = -1;
  if (i < 16) { bcnt[i] = 0; ncnt[i] = 0; }
}
// fused histograms: per-dst degree (global atomics), 12-bucket edge hist,
// 3-bucket node hist (both LDS-aggregated)
__global__ void k_hist_all(const int* __restrict__ src, const int* __restrict__ etype,
                           const int* __restrict__ ntype, const int* __restrict__ dst,
                           int* __restrict__ cnt, int* __restrict__ bcnt,
                           int* __restrict__ ncnt, int E, int N) {
  __shared__ int loc12[12];
  __shared__ int loc3[3];
  int tid = threadIdx.x;
  if (tid < 12) loc12[tid] = 0;
  if (tid < 3)  loc3[tid] = 0;
  __syncthreads();
  int i = blockIdx.x * 256 + tid;
  if (i < E) {
    atomicAdd(&cnt[dst[i]], 1);
    int b = ntype[src[i]] * R_N + etype[i];
    atomicAdd(&loc12[b], 1);
  }
  if (i < N) atomicAdd(&loc3[ntype[i]], 1);
  __syncthreads();
  if (tid < 12) atomicAdd(&bcnt[tid], loc12[tid]);
  if (tid < 3)  atomicAdd(&ncnt[tid], loc3[tid]);
}
__global__ void k_scan_a(const int* __restrict__ in, int* __restrict__ out,
                         int* __restrict__ bsums, int n) {
  __shared__ int s[256];
  int gid = blockIdx.x * 256 + threadIdx.x;
  int v = (gid < n) ? in[gid] : 0;
  s[threadIdx.x] = v;
  __syncthreads();
  for (int off = 1; off < 256; off <<= 1) {
    int t = (threadIdx.x >= off) ? s[threadIdx.x - off] : 0;
    __syncthreads();
    s[threadIdx.x] += t;
    __syncthreads();
  }
  if (gid < n) out[gid] = s[threadIdx.x] - v;
  if (threadIdx.x == 255) bsums[blockIdx.x] = s[255];
}
__global__ void k_scan_b(int* __restrict__ bsums, int nb) {
  __shared__ int s[256];
  int v = (threadIdx.x < nb) ? bsums[threadIdx.x] : 0;
  s[threadIdx.x] = v;
  __syncthreads();
  for (int off = 1; off < 256; off <<= 1) {
    int t = (threadIdx.x >= off) ? s[threadIdx.x - off] : 0;
    __syncthreads();
    s[threadIdx.x] += t;
    __syncthreads();
  }
  if (threadIdx.x < nb) bsums[threadIdx.x] = s[threadIdx.x] - v;
}
// scan_c fused with the row_ptr->cnt copy (cnt = final row_ptr value)
__global__ void k_scan_c_copy(int* __restrict__ out, const int* __restrict__ bsums,
                              int* __restrict__ cnt, int n, int N) {
  int gid = blockIdx.x * 256 + threadIdx.x;
  if (gid < n) {
    int v = out[gid] + bsums[blockIdx.x];
    out[gid] = v;
    if (gid < N) cnt[gid] = v;
  }
}
// tiny 12-bucket + 3-bucket exclusive scans (64-aligned)
__global__ void k_scan_small(const int* __restrict__ bcnt, int* __restrict__ bal,
                             int* __restrict__ bcur, const int* __restrict__ ncnt,
                             int* __restrict__ nal, int* __restrict__ ncur) {
  if (threadIdx.x == 0 && blockIdx.x == 0) {
    int run = 0;
    for (int b = 0; b < 12; b++) {
      bal[b] = run; bcur[b] = run;
      run += (bcnt[b] + 63) & ~63;
    }
    bal[12] = run;
    run = 0;
    for (int t = 0; t < 3; t++) {
      nal[t] = run; ncur[t] = run;
      run += (ncnt[t] + 63) & ~63;
    }
    nal[3] = run;
  }
}
// fused: rank[e] (CSR position), edge bucket scatter, node type scatter
__global__ void k_scatter_all(const int* __restrict__ src, const int* __restrict__ etype,
                              const int* __restrict__ ntype, const int* __restrict__ dst,
                              int* __restrict__ cnt, int* __restrict__ rank,
                              int* __restrict__ bcur, int* __restrict__ esorted,
                              int* __restrict__ ncur, int* __restrict__ nsorted,
                              int E, int N) {
  __shared__ int loc12[12], base12[12];
  __shared__ int loc3[3],  base3[3];
  int tid = threadIdx.x;
  if (tid < 12) loc12[tid] = 0;
  if (tid < 3)  loc3[tid] = 0;
  __syncthreads();
  int i = blockIdx.x * 256 + tid;
  int b = 0, lpos = 0, t = 0, lpos3 = 0;
  if (i < E) {
    rank[i] = atomicAdd(&cnt[dst[i]], 1);
    b = ntype[src[i]] * R_N + etype[i];
    lpos = atomicAdd(&loc12[b], 1);
  }
  if (i < N) {
    t = ntype[i];
    lpos3 = atomicAdd(&loc3[t], 1);
  }
  __syncthreads();
  if (tid < 12) { int c = loc12[tid]; base12[tid] = (c > 0) ? atomicAdd(&bcur[tid], c) : 0; }
  if (tid < 3)  { int c = loc3[tid];  base3[tid]  = (c > 0) ? atomicAdd(&ncur[tid], c) : 0; }
  __syncthreads();
  if (i < E) esorted[base12[b] + lpos] = i;
  if (i < N) nsorted[base3[t] + lpos3] = i;
}

// fused transpose+f16 for all 5 weight tensors (adapt K=256; Wq/Wa l=0,1
// K=128). dst[(t..)*Cd + c][k] = src[(t..)*Kd + k][c], Cd = 128 for all.
__global__ void k_transp_all(const float* __restrict__ adapt_W,
                             const float* __restrict__ Wq,
                             const float* __restrict__ Wa,
                             u16* __restrict__ adaptWT, u16* __restrict__ WqT,
                             u16* __restrict__ WaT) {
  int c = blockIdx.x;          // 0..127
  int y = blockIdx.y;          // 0..14: group = y/T_N, t = y%T_N
  int g = y / T_N, t = y % T_N;
  const float* srcp;
  u16* dstp;
  int Kd;
  if (g == 0) {
    srcp = adapt_W + (size_t)t * IND * HD;
    dstp = adaptWT + (size_t)t * HD * IND;
    Kd = IND;
  } else if (g <= 2) {
    int l = g - 1;
    srcp = Wq + ((size_t)l * T_N + t) * HD * HD;
    dstp = WqT + ((size_t)l * T_N + t) * HD * HD;
    Kd = HD;
  } else {
    int l = g - 3;
    srcp = Wa + ((size_t)l * T_N + t) * HD * HD;
    dstp = WaT + ((size_t)l * T_N + t) * HD * HD;
    Kd = HD;
  }
  for (int k = threadIdx.x; k < Kd; k += blockDim.x)
    dstp[(size_t)c * Kd + k] =
        __builtin_bit_cast(u16, (f16)srcp[(size_t)k * HD + c]);
}

// ------------------------------ math kernels -------------------------------
// rte table, BOTH layers -> f16 [2][240][128]; grid 480
__global__ void k_rte(const float* __restrict__ emb, const float* __restrict__ W,
                      const float* __restrict__ bias, u16* __restrict__ out) {
  int bx = blockIdx.x;
  int l = bx / MAXT, t = bx % MAXT;
  int lane = threadIdx.x;
  __shared__ __align__(16) float s[2 * HD];
  ((float4*)s)[lane] = ((const float4*)(emb + (size_t)t * 2 * HD))[lane];
  __syncthreads();
  const float* Wl = W + (size_t)l * 2 * HD * HD;
  float o0 = bias[l * HD + 2 * lane];
  float o1 = bias[l * HD + 2 * lane + 1];
  #pragma unroll 4
  for (int k = 0; k < 2 * HD; k++) {
    float xv = s[k];
    float2 w = ((const float2*)(Wl + (size_t)k * HD))[lane];
    o0 = fmaf(xv, w.x, o0);
    o1 = fmaf(xv, w.y, o1);
  }
  u32 pk = (u32)__builtin_bit_cast(u16, (f16)o0)
         | ((u32)__builtin_bit_cast(u16, (f16)o1) << 16);
  ((u32*)out)[((size_t)l * MAXT + t) * 64 + lane] = pk;
}

// Combined per-(type,rel) matrices, BOTH layers; grid 2*12*256
__global__ void k_wcomb(const float* __restrict__ Wk, const float* __restrict__ Wv,
                        const float* __restrict__ bk, const float* __restrict__ bv,
                        const float* __restrict__ Ratt, const float* __restrict__ Rmsg,
                        u16* __restrict__ Wcomb, float* __restrict__ bcomb) {
  int gbc = blockIdx.x;
  int l  = gbc / (12 * 256);
  int bc = gbc % (12 * 256);
  int b  = bc >> 8;
  int c  = bc & 255;
  int st = b >> 2, rt = b & 3;
  int k  = threadIdx.x;
  bool isv = (c >= HD);
  int c0 = isv ? c - HD : c;
  int h  = c0 >> 4, cc = c0 & 15;
  const float* W = (isv ? Wv : Wk) + (((size_t)(l * T_N + st) * HD) + k) * HD + h * 16;
  const float* A = (isv ? Rmsg : Ratt) + (((size_t)(l * R_N + rt) * NH + h) * 16) * 16 + cc;
  float s = 0.f;
  #pragma unroll
  for (int d = 0; d < 16; d++) s = fmaf(W[d], A[d * 16], s);
  Wcomb[(((size_t)l * 12 + b) * 256 + c) * HD + k] = __builtin_bit_cast(u16, (f16)s);
  if (k == 0) {
    const float* bb = (isv ? bv : bk) + (size_t)(l * T_N + st) * HD + h * 16;
    float sb = 0.f;
    #pragma unroll
    for (int d = 0; d < 16; d++) sb = fmaf(bb[d], A[d * 16], sb);
    bcomb[((size_t)l * 12 + b) * 256 + c] = sb;
  }
}

// Generic MFMA node linear over type-sorted buckets (unchanged from R16).
template<int K, int ACT, bool AHALF>
__global__ __launch_bounds__(256) void k_ngemm(
    const float* __restrict__ Af, const u16* __restrict__ Ah,
    const u16* __restrict__ WT, const float* __restrict__ bias,
    const int* __restrict__ nsorted, const int* __restrict__ nal,
    const float* __restrict__ skip_l,
    float* __restrict__ out_f, u16* __restrict__ out_h,
    const float* __restrict__ xin) {
  int tile0 = blockIdx.x * 64;
  if (tile0 >= nal[3]) return;
  int t = 0;
  #pragma unroll
  for (int i = 1; i < 3; i++) t += (tile0 >= nal[i]);

  __shared__ __align__(16) u16 ab[64 * K];   // f16, XOR-swizzled rows (G4)
  __shared__ int s_nid[64];
  int tid = threadIdx.x;
  int lane = tid & 63, w = tid >> 6;
  int l15 = lane & 15, l4 = lane >> 4;

  if (tid < 64) s_nid[tid] = nsorted[tile0 + tid];
  __syncthreads();

  {
    int r = tid >> 2, q4 = tid & 3;
    int nid = s_nid[r];
    char* rowp = (char*)ab + r * (2 * K);
    int sw = (r & 7) << 4;
    int base = q4 * (K / 2);
    if (nid >= 0) {
      if (AHALF) {
        const f16x8* ap = (const f16x8*)(Ah + (size_t)nid * K + q4 * (K / 4));
        #pragma unroll
        for (int i = 0; i < K / 32; i++)
          *(f16x8*)(rowp + ((base + 16 * i) ^ sw)) = ap[i];
      } else {
        const float4* ap = (const float4*)(Af + (size_t)nid * K + q4 * (K / 4));
        #pragma unroll
        for (int i = 0; i < K / 32; i++) {
          float4 a = ap[2 * i], a2 = ap[2 * i + 1];
          f16x8 hv;
          hv[0] = (f16)a.x;  hv[1] = (f16)a.y;  hv[2] = (f16)a.z;  hv[3] = (f16)a.w;
          hv[4] = (f16)a2.x; hv[5] = (f16)a2.y; hv[6] = (f16)a2.z; hv[7] = (f16)a2.w;
          *(f16x8*)(rowp + ((base + 16 * i) ^ sw)) = hv;
        }
      }
    } else {
      f16x8 z;
      #pragma unroll
      for (int j = 0; j < 8; j++) z[j] = (f16)0.f;
      #pragma unroll
      for (int i = 0; i < K / 32; i++)
        *(f16x8*)(rowp + ((base + 16 * i) ^ sw)) = z;
    }
  }
  __syncthreads();

  f32x4 acc[4][2];
  #pragma unroll
  for (int ni = 0; ni < 2; ni++) {
    float bc = bias[t * HD + w * 32 + ni * 16 + l15];
    #pragma unroll
    for (int mi = 0; mi < 4; mi++) {
      acc[mi][ni][0] = bc; acc[mi][ni][1] = bc;
      acc[mi][ni][2] = bc; acc[mi][ni][3] = bc;
    }
  }
  const u16* Wt = WT + (size_t)t * HD * K;
  #pragma unroll
  for (int ks = 0; ks < K / 32; ks++) {
    int k0 = ks * 32 + 8 * l4;
    f16x8 bf[2], af[4];
    #pragma unroll
    for (int ni = 0; ni < 2; ni++)
      bf[ni] = *(const f16x8*)(Wt + (size_t)(w * 32 + ni * 16 + l15) * K + k0);
    #pragma unroll
    for (int mi = 0; mi < 4; mi++) {
      int row = mi * 16 + l15;
      af[mi] = *(const f16x8*)((const char*)ab + row * (2 * K) +
                               ((2 * k0) ^ ((row & 7) << 4)));
    }
    #pragma unroll
    for (int mi = 0; mi < 4; mi++)
      #pragma unroll
      for (int ni = 0; ni < 2; ni++)
        acc[mi][ni] = __builtin_amdgcn_mfma_f32_16x16x32_f16(af[mi], bf[ni],
                                                             acc[mi][ni], 0, 0, 0);
  }

  float alpha = 0.f;
  if (ACT == 2) alpha = 1.f / (1.f + expf(-skip_l[t]));
  #pragma unroll
  for (int mi = 0; mi < 4; mi++)
    #pragma unroll
    for (int r = 0; r < 4; r++) {
      int rowl = mi * 16 + l4 * 4 + r;
      int nid = s_nid[rowl];
      if (nid >= 0) {
        #pragma unroll
        for (int ni = 0; ni < 2; ni++) {
          int c = w * 32 + ni * 16 + l15;
          float val = acc[mi][ni][r];
          if (ACT == 0) val = tanhf(val);
          if (ACT == 2) {
            float xo = xin[(size_t)nid * HD + c];
            val = val * alpha + xo * (1.f - alpha);
          }
          if (out_f) out_f[(size_t)nid * HD + c] = val;
          if (out_h) out_h[(size_t)nid * HD + c] =
              __builtin_bit_cast(u16, (f16)val);
        }
      }
    }
}

// MFMA edge kernel (R11/R16 shape, frozen). 512 thr / 8 waves; wave w owns
// cols [w*32,w*32+32): w<4 -> k' (LDS, scores), w>=4 -> v' (global).
__global__ __launch_bounds__(512) void k_edge_gemm(
    const u16* __restrict__ x_h, const u16* __restrict__ rte_h,
    const u16* __restrict__ Wcomb, const float* __restrict__ bcomb,
    const u16* __restrict__ q_h, const int* __restrict__ esorted,
    const int* __restrict__ bal, const int* __restrict__ src,
    const int* __restrict__ dst, const int* __restrict__ etime,
    const int* __restrict__ ntype, const int* __restrict__ rank,
    const float* __restrict__ pri_l,
    u16* __restrict__ score_h, u16* __restrict__ v_csr) {
  int tile0 = blockIdx.x * 64;
  if (tile0 >= bal[12]) return;
  int b = 0;
  #pragma unroll
  for (int i = 1; i < 12; i++) b += (tile0 >= bal[i]);
  int st = b >> 2, rt = b & 3;

  __shared__ __align__(16) u16 albuf[64 * HD];   // 16 KB
  __shared__ int s_eid[64];
  __shared__ int s_dst[64];
  __shared__ int s_rank[64];
  int tid = threadIdx.x;
  int lane = tid & 63, w = tid >> 6;
  int l15 = lane & 15, l4 = lane >> 4;

  if (tid < 64) {
    int e = esorted[tile0 + tid];
    s_eid[tid] = e;
    s_dst[tid] = (e >= 0) ? dst[e] : 0;
    s_rank[tid] = (e >= 0) ? rank[e] : 0;
  }
  __syncthreads();

  {
    int r = tid >> 3, p = tid & 7;
    int e = s_eid[r];
    char* rowp = (char*)albuf + r * 256;
    int sw = (r & 7) << 4;
    if (e >= 0) {
      const f16x8* xs = (const f16x8*)(x_h + (size_t)src[e] * HD + p * 16);
      const f16x8* rp = (const f16x8*)(rte_h + (size_t)etime[e] * HD + p * 16);
      f16x8 h0 = xs[0] + rp[0];
      f16x8 h1 = xs[1] + rp[1];
      *(f16x8*)(rowp + ((p * 32) ^ sw))      = h0;
      *(f16x8*)(rowp + ((p * 32 + 16) ^ sw)) = h1;
    } else {
      f16x8 z;
      #pragma unroll
      for (int j = 0; j < 8; j++) z[j] = (f16)0.f;
      *(f16x8*)(rowp + ((p * 32) ^ sw))      = z;
      *(f16x8*)(rowp + ((p * 32 + 16) ^ sw)) = z;
    }
  }
  __syncthreads();

  f32x4 acc[4][2];
  #pragma unroll
  for (int ni = 0; ni < 2; ni++) {
    float bc = bcomb[b * 256 + w * 32 + ni * 16 + l15];
    #pragma unroll
    for (int mi = 0; mi < 4; mi++) {
      acc[mi][ni][0] = bc; acc[mi][ni][1] = bc;
      acc[mi][ni][2] = bc; acc[mi][ni][3] = bc;
    }
  }
  const u16* Wb = Wcomb + (size_t)b * 256 * HD;
  #pragma unroll
  for (int ks = 0; ks < 4; ks++) {
    int k0 = ks * 32 + 8 * l4;
    f16x8 bf[2], af[4];
    #pragma unroll
    for (int ni = 0; ni < 2; ni++)
      bf[ni] = *(const f16x8*)(Wb + (size_t)(w * 32 + ni * 16 + l15) * HD + k0);
    #pragma unroll
    for (int mi = 0; mi < 4; mi++) {
      int row = mi * 16 + l15;
      af[mi] = *(const f16x8*)((const char*)albuf + row * 256 +
                               ((2 * k0) ^ ((row & 7) << 4)));
    }
    #pragma unroll
    for (int mi = 0; mi < 4; mi++)
      #pragma unroll
      for (int ni = 0; ni < 2; ni++)
        acc[mi][ni] = __builtin_amdgcn_mfma_f32_16x16x32_f16(af[mi], bf[ni],
                                                             acc[mi][ni], 0, 0, 0);
  }
  __syncthreads();

  if (w < 4) {
    #pragma unroll
    for (int mi = 0; mi < 4; mi++)
      #pragma unroll
      for (int r = 0; r < 4; r++) {
        int row = mi * 16 + l4 * 4 + r;
        char* rowp = (char*)albuf + row * 256;
        int sw = (row & 7) << 4;
        #pragma unroll
        for (int ni = 0; ni < 2; ni++) {
          int c = w * 32 + ni * 16 + l15;
          *(u16*)(rowp + ((2 * c) ^ sw)) =
              __builtin_bit_cast(u16, (f16)acc[mi][ni][r]);
        }
      }
  } else {
    int wv = w - 4;
    #pragma unroll
    for (int mi = 0; mi < 4; mi++)
      #pragma unroll
      for (int r = 0; r < 4; r++) {
        int rowl = mi * 16 + l4 * 4 + r;
        if (s_eid[rowl] >= 0) {
          u16* vp = v_csr + (size_t)s_rank[rowl] * HD + wv * 32 + l15;
          #pragma unroll
          for (int ni = 0; ni < 2; ni++)
            vp[ni * 16] = __builtin_bit_cast(u16, (f16)acc[mi][ni][r]);
        }
      }
  }
  __syncthreads();

  {
    int e = tid >> 3, h = tid & 7;
    if (s_eid[e] >= 0) {
      int d = s_dst[e];
      int tt = ntype[d];
      const char* rowp = (const char*)albuf + e * 256;
      int sw = (e & 7) << 4;
      f16x8 kh0 = *(const f16x8*)(rowp + ((h * 32) ^ sw));
      f16x8 kh1 = *(const f16x8*)(rowp + ((h * 32 + 16) ^ sw));
      const f16x8* qp = (const f16x8*)(q_h + (size_t)d * HD + h * 16);
      f16x8 qa = qp[0], qb = qp[1];
      float sc = 0.f;
      #pragma unroll
      for (int j = 0; j < 8; j++) sc += (float)qa[j] * (float)kh0[j];
      #pragma unroll
      for (int j = 0; j < 8; j++) sc += (float)qb[j] * (float)kh1[j];
      float pri = pri_l[((tt * R_N + rt) * T_N + st) * NH + h];
      score_h[(size_t)s_rank[e] * NH + h] =
          __builtin_bit_cast(u16, (f16)(sc * pri * 0.25f));
    }
  }
}

// Per-node (1 wave): segment softmax + weighted v-sum + exact GELU -> g (f16).
__global__ void k_aggr(const int* __restrict__ row_ptr,
                       const u16* __restrict__ score_h,
                       const u16* __restrict__ v_csr,
                       u16* __restrict__ g_h, int N) {
  int n = blockIdx.x;
  int lane = threadIdx.x;
  int start = row_ptr[n], end = row_ptr[n + 1];

  int h = lane & 7, jj = lane >> 3;
  float m = -3.0e38f;
  for (int idx = start + jj; idx < end; idx += 8)
    m = fmaxf(m, (float)__builtin_bit_cast(f16, score_h[(size_t)idx * NH + h]));
  #pragma unroll
  for (int off = 8; off < 64; off <<= 1) m = fmaxf(m, __shfl_xor(m, off));
  float z = 0.f;
  for (int idx = start + jj; idx < end; idx += 8)
    z += expf((float)__builtin_bit_cast(f16, score_h[(size_t)idx * NH + h]) - m);
  #pragma unroll
  for (int off = 8; off < 64; off <<= 1) z += __shfl_xor(z, off);

  int myh = lane >> 3;
  float md = __shfl(m, myh);
  float zd = __shfl(z, myh);
  float rz = (zd > 0.f) ? 1.f / zd : 0.f;

  float a0 = 0.f, a1 = 0.f;
  for (int idx = start; idx < end; idx++) {
    float sc = (float)__builtin_bit_cast(f16, score_h[(size_t)idx * NH + myh]);
    float wgt = expf(sc - md) * rz;
    u32 v2 = ((const u32*)(v_csr + (size_t)idx * HD))[lane];
    float v0 = (float)__builtin_bit_cast(f16, (u16)(v2 & 0xffffu));
    float v1 = (float)__builtin_bit_cast(f16, (u16)(v2 >> 16));
    a0 = fmaf(wgt, v0, a0);
    a1 = fmaf(wgt, v1, a1);
  }

  a0 = 0.5f * a0 * (1.f + erff(a0 * 0.7071067811865475f));
  a1 = 0.5f * a1 * (1.f + erff(a1 * 0.7071067811865475f));
  u32 pk = (u32)__builtin_bit_cast(u16, (f16)a0)
         | ((u32)__builtin_bit_cast(u16, (f16)a1) << 16);
  ((u32*)(g_h + (size_t)n * HD))[lane] = pk;
}

}  // namespace

extern "C" void kernel_launch(void* const* d_in, const int* in_sizes, int n_in,
                              void* d_out, int out_size, void* d_ws, size_t ws_size,
                              hipStream_t stream) {
  const float* node_feature = (const float*)d_in[0];
  const int*   node_type    = (const int*)d_in[1];
  const int*   edge_time    = (const int*)d_in[2];
  const int*   edge_type    = (const int*)d_in[3];
  const int*   edge_index   = (const int*)d_in[4];
  const float* adapt_W      = (const float*)d_in[5];
  const float* adapt_b      = (const float*)d_in[6];
  const float* Wk           = (const float*)d_in[7];
  const float* bk           = (const float*)d_in[8];
  const float* Wq           = (const float*)d_in[9];
  const float* bq           = (const float*)d_in[10];
  const float* Wv           = (const float*)d_in[11];
  const float* bv           = (const float*)d_in[12];
  const float* Wa           = (const float*)d_in[13];
  const float* ba           = (const float*)d_in[14];
  const float* rel_pri      = (const float*)d_in[15];
  const float* rel_att      = (const float*)d_in[16];
  const float* rel_msg      = (const float*)d_in[17];
  const float* skip         = (const float*)d_in[18];
  const float* rte_emb      = (const float*)d_in[19];
  const float* rte_W        = (const float*)d_in[20];
  const float* rte_b        = (const float*)d_in[21];

  const int N = in_sizes[1];
  const int E = in_sizes[2];
  const int* src  = edge_index;
  const int* dstp = edge_index + E;

  float* x = (float*)d_out;

  size_t off = 0;
  auto carve = [&](size_t bytes) -> void* {
    void* p = (char*)d_ws + off;
    off += (bytes + 255) & ~(size_t)255;
    return p;
  };
  // ~254 MB total (stay under 256MiB; R8's 290MB crashed).
  u16*   v_csr   = (u16*)  carve((size_t)E * HD * 2);   // 204.8 MB, CSR-perm
  u16*   score_h = (u16*)  carve((size_t)E * NH * 2);   // 12.8 MB, CSR-perm
  u16*   x_h     = (u16*)  carve((size_t)N * HD * 2);   // 12.8 MB
  u16*   qg      = (u16*)  carve((size_t)N * HD * 2);   // 12.8 MB: q_h then g_h
  u16*   rte_h   = (u16*)  carve((size_t)2 * MAXT * HD * 2);       // both layers
  u16*   Wcomb   = (u16*)  carve((size_t)2 * 12 * 256 * HD * 2);   // both layers
  float* bcomb   = (float*)carve((size_t)2 * 12 * 256 * 4);
  u16*   adaptWT = (u16*)  carve((size_t)T_N * HD * IND * 2);
  u16*   WqT     = (u16*)  carve((size_t)2 * T_N * HD * HD * 2);
  u16*   WaT     = (u16*)  carve((size_t)2 * T_N * HD * HD * 2);
  int*   row_ptr = (int*)  carve((size_t)(N + 1) * 4);
  int*   cnt     = (int*)  carve((size_t)(N + 1) * 4);
  int*   rank    = (int*)  carve((size_t)E * 4);
  int*   bsums   = (int*)  carve(1024 * 4);
  int*   bcnt    = (int*)  carve(16 * 4);
  int*   bal     = (int*)  carve(16 * 4);
  int*   bcur    = (int*)  carve(16 * 4);
  int*   ncnt    = (int*)  carve(16 * 4);
  int*   nal     = (int*)  carve(16 * 4);
  int*   ncur    = (int*)  carve(16 * 4);
  const int EP = E + 12 * 64;
  const int NP = N + 3 * 64;
  int*   esorted = (int*)  carve((size_t)EP * 4);
  int*   nsorted = (int*)  carve((size_t)NP * 4);
  (void)ws_size; (void)n_in; (void)out_size;

  const int gE  = (E + 255) / 256;
  const int gN1 = (N + 1 + 255) / 256;
  const int gEP = (EP + 255) / 256;
  const int etiles = (EP + 63) / 64;
  const int ntiles = (NP + 63) / 64;

  // ---- setup: 8 dispatches (was 17) ----
  k_fill_all<<<gEP, 256, 0, stream>>>(cnt, esorted, nsorted, bcnt, ncnt,
                                      N + 1, EP, NP);
  k_hist_all<<<gE, 256, 0, stream>>>(src, edge_type, node_type, dstp,
                                     cnt, bcnt, ncnt, E, N);
  k_scan_a<<<gN1, 256, 0, stream>>>(cnt, row_ptr, bsums, N + 1);
  k_scan_b<<<1, 256, 0, stream>>>(bsums, gN1);
  k_scan_c_copy<<<gN1, 256, 0, stream>>>(row_ptr, bsums, cnt, N + 1, N);
  k_scan_small<<<1, 64, 0, stream>>>(bcnt, bal, bcur, ncnt, nal, ncur);
  k_scatter_all<<<gE, 256, 0, stream>>>(src, edge_type, node_type, dstp,
                                        cnt, rank, bcur, esorted,
                                        ncur, nsorted, E, N);

  // ---- weights/tables: 3 dispatches (was 9) ----
  k_transp_all<<<dim3(HD, T_N * 5), 128, 0, stream>>>(adapt_W, Wq, Wa,
                                                      adaptWT, WqT, WaT);
  k_rte<<<2 * MAXT, 64, 0, stream>>>(rte_emb, rte_W, rte_b, rte_h);
  k_wcomb<<<2 * 12 * 256, 128, 0, stream>>>(Wk, Wv, bk, bv, rel_att, rel_msg,
                                            Wcomb, bcomb);

  // adapt: x = tanh(node_feature @ adapt_W[t] + adapt_b[t]); also x_h mirror
  k_ngemm<IND, 0, false><<<ntiles, 256, 0, stream>>>(
      node_feature, nullptr, adaptWT, adapt_b, nsorted, nal, nullptr,
      x, x_h, nullptr);

  for (int l = 0; l < 2; l++) {
    // q (f16 -> qg), input from x_h
    k_ngemm<HD, 1, true><<<ntiles, 256, 0, stream>>>(
        nullptr, x_h, WqT + (size_t)l * T_N * HD * HD, bq + (size_t)l * T_N * HD,
        nsorted, nal, nullptr, nullptr, qg, nullptr);
    k_edge_gemm<<<etiles, 512, 0, stream>>>(
        x_h, rte_h + (size_t)l * MAXT * HD,
        Wcomb + (size_t)l * 12 * 256 * HD, bcomb + (size_t)l * 12 * 256,
        qg, esorted, bal, src, dstp, edge_time, node_type, rank,
        rel_pri + (size_t)l * T_N * R_N * T_N * NH, score_h, v_csr);
    // g (f16) overwrites qg -- q_h dead after edge_gemm (stream-ordered)
    k_aggr<<<N, 64, 0, stream>>>(row_ptr, score_h, v_csr, qg, N);
    // out-linear + skip blend; reads g (f16), writes x fp32 + x_h mirror
    k_ngemm<HD, 2, true><<<ntiles, 256, 0, stream>>>(
        nullptr, qg, WaT + (size_t)l * T_N * HD * HD, ba + (size_t)l * T_N * HD,
        nsorted, nal, skip + (size_t)l * T_N, x, x_h, x);
  }
}

// Round 19
// 799.601 us; speedup vs baseline: 1.4375x; 1.0013x over previous
//
#include <hip/hip_runtime.h>
#include <cstdint>
#include <cstddef>

// HGT forward (2 layers) on MI355X.
// R19: q-GEMM fusion on top of R18 (801us; edge frozen at R11 shape).
// The 3 standalone q-ngemm dispatches are folded into the preceding node
// linear (adapt -> q0; out-linear l=0 -> q1): after the first MFMA pass the
// f16(out) values are re-staged into the dead LDS buffer (K=128 swizzled
// layout) and a second MFMA pass against WqT produces q in the same block.
// Value-identical math (same f16-rounded inputs/order) -> absmax must stay
// 2.441406e-4. k_aggr widened to 4 nodes/block; final x_h write skipped.

namespace {

constexpr int T_N  = 3;
constexpr int R_N  = 4;
constexpr int HD   = 128;
constexpr int IND  = 256;
constexpr int NH   = 8;
constexpr int MAXT = 240;

typedef unsigned short u16;
typedef unsigned int   u32;
typedef _Float16 f16;
typedef __attribute__((ext_vector_type(8))) _Float16 f16x8;
typedef __attribute__((ext_vector_type(4))) float    f32x4;

// ----------------------------- setup kernels -------------------------------
__global__ void k_fill_all(int* __restrict__ cnt, int* __restrict__ esorted,
                           int* __restrict__ nsorted, int* __restrict__ bcnt,
                           int* __restrict__ ncnt, int nCnt, int nE, int nN) {
  int i = blockIdx.x * 256 + threadIdx.x;
  if (i < nCnt) cnt[i] = 0;
  if (i < nE)  esorted[i] = -1;
  if (i < nN)  nsorted[i] = -1;
  if (i < 16) { bcnt[i] = 0; ncnt[i] = 0; }
}
__global__ void k_hist_all(const int* __restrict__ src, const int* __restrict__ etype,
                           const int* __restrict__ ntype, const int* __restrict__ dst,
                           int* __restrict__ cnt, int* __restrict__ bcnt,
                           int* __restrict__ ncnt, int E, int N) {
  __shared__ int loc12[12];
  __shared__ int loc3[3];
  int tid = threadIdx.x;
  if (tid < 12) loc12[tid] = 0;
  if (tid < 3)  loc3[tid] = 0;
  __syncthreads();
  int i = blockIdx.x * 256 + tid;
  if (i < E) {
    atomicAdd(&cnt[dst[i]], 1);
    int b = ntype[src[i]] * R_N + etype[i];
    atomicAdd(&loc12[b], 1);
  }
  if (i < N) atomicAdd(&loc3[ntype[i]], 1);
  __syncthreads();
  if (tid < 12) atomicAdd(&bcnt[tid], loc12[tid]);
  if (tid < 3)  atomicAdd(&ncnt[tid], loc3[tid]);
}
__global__ void k_scan_a(const int* __restrict__ in, int* __restrict__ out,
                         int* __restrict__ bsums, int n) {
  __shared__ int s[256];
  int gid = blockIdx.x * 256 + threadIdx.x;
  int v = (gid < n) ? in[gid] : 0;
  s[threadIdx.x] = v;
  __syncthreads();
  for (int off = 1; off < 256; off <<= 1) {
    int t = (threadIdx.x >= off) ? s[threadIdx.x - off] : 0;
    __syncthreads();
    s[threadIdx.x] += t;
    __syncthreads();
  }
  if (gid < n) out[gid] = s[threadIdx.x] - v;
  if (threadIdx.x == 255) bsums[blockIdx.x] = s[255];
}
__global__ void k_scan_b(int* __restrict__ bsums, int nb) {
  __shared__ int s[256];
  int v = (threadIdx.x < nb) ? bsums[threadIdx.x] : 0;
  s[threadIdx.x] = v;
  __syncthreads();
  for (int off = 1; off < 256; off <<= 1) {
    int t = (threadIdx.x >= off) ? s[threadIdx.x - off] : 0;
    __syncthreads();
    s[threadIdx.x] += t;
    __syncthreads();
  }
  if (threadIdx.x < nb) bsums[threadIdx.x] = s[threadIdx.x] - v;
}
__global__ void k_scan_c_copy(int* __restrict__ out, const int* __restrict__ bsums,
                              int* __restrict__ cnt, int n, int N) {
  int gid = blockIdx.x * 256 + threadIdx.x;
  if (gid < n) {
    int v = out[gid] + bsums[blockIdx.x];
    out[gid] = v;
    if (gid < N) cnt[gid] = v;
  }
}
__global__ void k_scan_small(const int* __restrict__ bcnt, int* __restrict__ bal,
                             int* __restrict__ bcur, const int* __restrict__ ncnt,
                             int* __restrict__ nal, int* __restrict__ ncur) {
  if (threadIdx.x == 0 && blockIdx.x == 0) {
    int run = 0;
    for (int b = 0; b < 12; b++) {
      bal[b] = run; bcur[b] = run;
      run += (bcnt[b] + 63) & ~63;
    }
    bal[12] = run;
    run = 0;
    for (int t = 0; t < 3; t++) {
      nal[t] = run; ncur[t] = run;
      run += (ncnt[t] + 63) & ~63;
    }
    nal[3] = run;
  }
}
__global__ void k_scatter_all(const int* __restrict__ src, const int* __restrict__ etype,
                              const int* __restrict__ ntype, const int* __restrict__ dst,
                              int* __restrict__ cnt, int* __restrict__ rank,
                              int* __restrict__ bcur, int* __restrict__ esorted,
                              int* __restrict__ ncur, int* __restrict__ nsorted,
                              int E, int N) {
  __shared__ int loc12[12], base12[12];
  __shared__ int loc3[3],  base3[3];
  int tid = threadIdx.x;
  if (tid < 12) loc12[tid] = 0;
  if (tid < 3)  loc3[tid] = 0;
  __syncthreads();
  int i = blockIdx.x * 256 + tid;
  int b = 0, lpos = 0, t = 0, lpos3 = 0;
  if (i < E) {
    rank[i] = atomicAdd(&cnt[dst[i]], 1);
    b = ntype[src[i]] * R_N + etype[i];
    lpos = atomicAdd(&loc12[b], 1);
  }
  if (i < N) {
    t = ntype[i];
    lpos3 = atomicAdd(&loc3[t], 1);
  }
  __syncthreads();
  if (tid < 12) { int c = loc12[tid]; base12[tid] = (c > 0) ? atomicAdd(&bcur[tid], c) : 0; }
  if (tid < 3)  { int c = loc3[tid];  base3[tid]  = (c > 0) ? atomicAdd(&ncur[tid], c) : 0; }
  __syncthreads();
  if (i < E) esorted[base12[b] + lpos] = i;
  if (i < N) nsorted[base3[t] + lpos3] = i;
}

// fused transpose+f16 for all 5 weight tensors
__global__ void k_transp_all(const float* __restrict__ adapt_W,
                             const float* __restrict__ Wq,
                             const float* __restrict__ Wa,
                             u16* __restrict__ adaptWT, u16* __restrict__ WqT,
                             u16* __restrict__ WaT) {
  int c = blockIdx.x;
  int y = blockIdx.y;
  int g = y / T_N, t = y % T_N;
  const float* srcp;
  u16* dstp;
  int Kd;
  if (g == 0) {
    srcp = adapt_W + (size_t)t * IND * HD;
    dstp = adaptWT + (size_t)t * HD * IND;
    Kd = IND;
  } else if (g <= 2) {
    int l = g - 1;
    srcp = Wq + ((size_t)l * T_N + t) * HD * HD;
    dstp = WqT + ((size_t)l * T_N + t) * HD * HD;
    Kd = HD;
  } else {
    int l = g - 3;
    srcp = Wa + ((size_t)l * T_N + t) * HD * HD;
    dstp = WaT + ((size_t)l * T_N + t) * HD * HD;
    Kd = HD;
  }
  for (int k = threadIdx.x; k < Kd; k += blockDim.x)
    dstp[(size_t)c * Kd + k] =
        __builtin_bit_cast(u16, (f16)srcp[(size_t)k * HD + c]);
}

// ------------------------------ math kernels -------------------------------
// rte table, BOTH layers -> f16 [2][240][128]; grid 480
__global__ void k_rte(const float* __restrict__ emb, const float* __restrict__ W,
                      const float* __restrict__ bias, u16* __restrict__ out) {
  int bx = blockIdx.x;
  int l = bx / MAXT, t = bx % MAXT;
  int lane = threadIdx.x;
  __shared__ __align__(16) float s[2 * HD];
  ((float4*)s)[lane] = ((const float4*)(emb + (size_t)t * 2 * HD))[lane];
  __syncthreads();
  const float* Wl = W + (size_t)l * 2 * HD * HD;
  float o0 = bias[l * HD + 2 * lane];
  float o1 = bias[l * HD + 2 * lane + 1];
  #pragma unroll 4
  for (int k = 0; k < 2 * HD; k++) {
    float xv = s[k];
    float2 w = ((const float2*)(Wl + (size_t)k * HD))[lane];
    o0 = fmaf(xv, w.x, o0);
    o1 = fmaf(xv, w.y, o1);
  }
  u32 pk = (u32)__builtin_bit_cast(u16, (f16)o0)
         | ((u32)__builtin_bit_cast(u16, (f16)o1) << 16);
  ((u32*)out)[((size_t)l * MAXT + t) * 64 + lane] = pk;
}

// Combined per-(type,rel) matrices, BOTH layers; grid 2*12*256
__global__ void k_wcomb(const float* __restrict__ Wk, const float* __restrict__ Wv,
                        const float* __restrict__ bk, const float* __restrict__ bv,
                        const float* __restrict__ Ratt, const float* __restrict__ Rmsg,
                        u16* __restrict__ Wcomb, float* __restrict__ bcomb) {
  int gbc = blockIdx.x;
  int l  = gbc / (12 * 256);
  int bc = gbc % (12 * 256);
  int b  = bc >> 8;
  int c  = bc & 255;
  int st = b >> 2, rt = b & 3;
  int k  = threadIdx.x;
  bool isv = (c >= HD);
  int c0 = isv ? c - HD : c;
  int h  = c0 >> 4, cc = c0 & 15;
  const float* W = (isv ? Wv : Wk) + (((size_t)(l * T_N + st) * HD) + k) * HD + h * 16;
  const float* A = (isv ? Rmsg : Ratt) + (((size_t)(l * R_N + rt) * NH + h) * 16) * 16 + cc;
  float s = 0.f;
  #pragma unroll
  for (int d = 0; d < 16; d++) s = fmaf(W[d], A[d * 16], s);
  Wcomb[(((size_t)l * 12 + b) * 256 + c) * HD + k] = __builtin_bit_cast(u16, (f16)s);
  if (k == 0) {
    const float* bb = (isv ? bv : bk) + (size_t)(l * T_N + st) * HD + h * 16;
    float sb = 0.f;
    #pragma unroll
    for (int d = 0; d < 16; d++) sb = fmaf(bb[d], A[d * 16], sb);
    bcomb[((size_t)l * 12 + b) * 256 + c] = sb;
  }
}

// MFMA node linear over type-sorted buckets; optional fused second MFMA pass
// computing q = f16(out) @ WT2[t]^T + bias2[t] (QF). Value-identical to the
// standalone q-ngemm: same f16-rounded inputs, same fragment order.
template<int K, int ACT, bool AHALF, bool QF>
__global__ __launch_bounds__(256) void k_ngemm(
    const float* __restrict__ Af, const u16* __restrict__ Ah,
    const u16* __restrict__ WT, const float* __restrict__ bias,
    const int* __restrict__ nsorted, const int* __restrict__ nal,
    const float* __restrict__ skip_l,
    float* __restrict__ out_f, u16* __restrict__ out_h,
    const float* __restrict__ xin,
    const u16* __restrict__ WT2, const float* __restrict__ bias2,
    u16* __restrict__ q_out) {
  int tile0 = blockIdx.x * 64;
  if (tile0 >= nal[3]) return;
  int t = 0;
  #pragma unroll
  for (int i = 1; i < 3; i++) t += (tile0 >= nal[i]);

  __shared__ __align__(16) u16 ab[64 * K];   // f16, XOR-swizzled rows (G4)
  __shared__ int s_nid[64];
  int tid = threadIdx.x;
  int lane = tid & 63, w = tid >> 6;
  int l15 = lane & 15, l4 = lane >> 4;

  if (tid < 64) s_nid[tid] = nsorted[tile0 + tid];
  __syncthreads();

  { // stage A -> f16 LDS
    int r = tid >> 2, q4 = tid & 3;
    int nid = s_nid[r];
    char* rowp = (char*)ab + r * (2 * K);
    int sw = (r & 7) << 4;
    int base = q4 * (K / 2);
    if (nid >= 0) {
      if (AHALF) {
        const f16x8* ap = (const f16x8*)(Ah + (size_t)nid * K + q4 * (K / 4));
        #pragma unroll
        for (int i = 0; i < K / 32; i++)
          *(f16x8*)(rowp + ((base + 16 * i) ^ sw)) = ap[i];
      } else {
        const float4* ap = (const float4*)(Af + (size_t)nid * K + q4 * (K / 4));
        #pragma unroll
        for (int i = 0; i < K / 32; i++) {
          float4 a = ap[2 * i], a2 = ap[2 * i + 1];
          f16x8 hv;
          hv[0] = (f16)a.x;  hv[1] = (f16)a.y;  hv[2] = (f16)a.z;  hv[3] = (f16)a.w;
          hv[4] = (f16)a2.x; hv[5] = (f16)a2.y; hv[6] = (f16)a2.z; hv[7] = (f16)a2.w;
          *(f16x8*)(rowp + ((base + 16 * i) ^ sw)) = hv;
        }
      }
    } else {
      f16x8 z;
      #pragma unroll
      for (int j = 0; j < 8; j++) z[j] = (f16)0.f;
      #pragma unroll
      for (int i = 0; i < K / 32; i++)
        *(f16x8*)(rowp + ((base + 16 * i) ^ sw)) = z;
    }
  }
  __syncthreads();

  f32x4 acc[4][2];
  #pragma unroll
  for (int ni = 0; ni < 2; ni++) {
    float bc = bias[t * HD + w * 32 + ni * 16 + l15];
    #pragma unroll
    for (int mi = 0; mi < 4; mi++) {
      acc[mi][ni][0] = bc; acc[mi][ni][1] = bc;
      acc[mi][ni][2] = bc; acc[mi][ni][3] = bc;
    }
  }
  const u16* Wt = WT + (size_t)t * HD * K;
  #pragma unroll
  for (int ks = 0; ks < K / 32; ks++) {
    int k0 = ks * 32 + 8 * l4;
    f16x8 bf[2], af[4];
    #pragma unroll
    for (int ni = 0; ni < 2; ni++)
      bf[ni] = *(const f16x8*)(Wt + (size_t)(w * 32 + ni * 16 + l15) * K + k0);
    #pragma unroll
    for (int mi = 0; mi < 4; mi++) {
      int row = mi * 16 + l15;
      af[mi] = *(const f16x8*)((const char*)ab + row * (2 * K) +
                               ((2 * k0) ^ ((row & 7) << 4)));
    }
    #pragma unroll
    for (int mi = 0; mi < 4; mi++)
      #pragma unroll
      for (int ni = 0; ni < 2; ni++)
        acc[mi][ni] = __builtin_amdgcn_mfma_f32_16x16x32_f16(af[mi], bf[ni],
                                                             acc[mi][ni], 0, 0, 0);
  }

  float alpha = 0.f;
  if (ACT == 2) alpha = 1.f / (1.f + expf(-skip_l[t]));
  if (QF) __syncthreads();     // all ds_reads of ab done before re-stage
  #pragma unroll
  for (int mi = 0; mi < 4; mi++)
    #pragma unroll
    for (int r = 0; r < 4; r++) {
      int rowl = mi * 16 + l4 * 4 + r;
      int nid = s_nid[rowl];
      #pragma unroll
      for (int ni = 0; ni < 2; ni++) {
        int c = w * 32 + ni * 16 + l15;
        float val = acc[mi][ni][r];
        if (ACT == 0) val = tanhf(val);
        if (ACT == 2 && nid >= 0) {
          float xo = xin[(size_t)nid * HD + c];
          val = val * alpha + xo * (1.f - alpha);
        }
        u16 hb = __builtin_bit_cast(u16, (f16)val);
        if (nid >= 0) {
          if (out_f) out_f[(size_t)nid * HD + c] = val;
          if (out_h) out_h[(size_t)nid * HD + c] = hb;
        }
        if (QF) {   // re-stage f16(out) in K=128 swizzled layout
          char* rowp = (char*)ab + rowl * 256;
          int sw = (rowl & 7) << 4;
          *(u16*)(rowp + ((2 * c) ^ sw)) = hb;
        }
      }
    }

  if (QF) {
    __syncthreads();
    f32x4 acc2[4][2];
    #pragma unroll
    for (int ni = 0; ni < 2; ni++) {
      float bc = bias2[t * HD + w * 32 + ni * 16 + l15];
      #pragma unroll
      for (int mi = 0; mi < 4; mi++) {
        acc2[mi][ni][0] = bc; acc2[mi][ni][1] = bc;
        acc2[mi][ni][2] = bc; acc2[mi][ni][3] = bc;
      }
    }
    const u16* Wt2 = WT2 + (size_t)t * HD * HD;
    #pragma unroll
    for (int ks = 0; ks < 4; ks++) {
      int k0 = ks * 32 + 8 * l4;
      f16x8 bf[2], af[4];
      #pragma unroll
      for (int ni = 0; ni < 2; ni++)
        bf[ni] = *(const f16x8*)(Wt2 + (size_t)(w * 32 + ni * 16 + l15) * HD + k0);
      #pragma unroll
      for (int mi = 0; mi < 4; mi++) {
        int row = mi * 16 + l15;
        af[mi] = *(const f16x8*)((const char*)ab + row * 256 +
                                 ((2 * k0) ^ ((row & 7) << 4)));
      }
      #pragma unroll
      for (int mi = 0; mi < 4; mi++)
        #pragma unroll
        for (int ni = 0; ni < 2; ni++)
          acc2[mi][ni] = __builtin_amdgcn_mfma_f32_16x16x32_f16(af[mi], bf[ni],
                                                                acc2[mi][ni], 0, 0, 0);
    }
    #pragma unroll
    for (int mi = 0; mi < 4; mi++)
      #pragma unroll
      for (int r = 0; r < 4; r++) {
        int rowl = mi * 16 + l4 * 4 + r;
        int nid = s_nid[rowl];
        if (nid >= 0) {
          #pragma unroll
          for (int ni = 0; ni < 2; ni++) {
            int c = w * 32 + ni * 16 + l15;
            q_out[(size_t)nid * HD + c] =
                __builtin_bit_cast(u16, (f16)acc2[mi][ni][r]);
          }
        }
      }
  }
}

// MFMA edge kernel (R11 shape, frozen). 512 thr / 8 waves; wave w owns
// cols [w*32,w*32+32): w<4 -> k' (LDS, scores), w>=4 -> v' (global).
__global__ __launch_bounds__(512) void k_edge_gemm(
    const u16* __restrict__ x_h, const u16* __restrict__ rte_h,
    const u16* __restrict__ Wcomb, const float* __restrict__ bcomb,
    const u16* __restrict__ q_h, const int* __restrict__ esorted,
    const int* __restrict__ bal, const int* __restrict__ src,
    const int* __restrict__ dst, const int* __restrict__ etime,
    const int* __restrict__ ntype, const int* __restrict__ rank,
    const float* __restrict__ pri_l,
    u16* __restrict__ score_h, u16* __restrict__ v_csr) {
  int tile0 = blockIdx.x * 64;
  if (tile0 >= bal[12]) return;
  int b = 0;
  #pragma unroll
  for (int i = 1; i < 12; i++) b += (tile0 >= bal[i]);
  int st = b >> 2, rt = b & 3;

  __shared__ __align__(16) u16 albuf[64 * HD];   // 16 KB
  __shared__ int s_eid[64];
  __shared__ int s_dst[64];
  __shared__ int s_rank[64];
  int tid = threadIdx.x;
  int lane = tid & 63, w = tid >> 6;
  int l15 = lane & 15, l4 = lane >> 4;

  if (tid < 64) {
    int e = esorted[tile0 + tid];
    s_eid[tid] = e;
    s_dst[tid] = (e >= 0) ? dst[e] : 0;
    s_rank[tid] = (e >= 0) ? rank[e] : 0;
  }
  __syncthreads();

  {
    int r = tid >> 3, p = tid & 7;
    int e = s_eid[r];
    char* rowp = (char*)albuf + r * 256;
    int sw = (r & 7) << 4;
    if (e >= 0) {
      const f16x8* xs = (const f16x8*)(x_h + (size_t)src[e] * HD + p * 16);
      const f16x8* rp = (const f16x8*)(rte_h + (size_t)etime[e] * HD + p * 16);
      f16x8 h0 = xs[0] + rp[0];
      f16x8 h1 = xs[1] + rp[1];
      *(f16x8*)(rowp + ((p * 32) ^ sw))      = h0;
      *(f16x8*)(rowp + ((p * 32 + 16) ^ sw)) = h1;
    } else {
      f16x8 z;
      #pragma unroll
      for (int j = 0; j < 8; j++) z[j] = (f16)0.f;
      *(f16x8*)(rowp + ((p * 32) ^ sw))      = z;
      *(f16x8*)(rowp + ((p * 32 + 16) ^ sw)) = z;
    }
  }
  __syncthreads();

  f32x4 acc[4][2];
  #pragma unroll
  for (int ni = 0; ni < 2; ni++) {
    float bc = bcomb[b * 256 + w * 32 + ni * 16 + l15];
    #pragma unroll
    for (int mi = 0; mi < 4; mi++) {
      acc[mi][ni][0] = bc; acc[mi][ni][1] = bc;
      acc[mi][ni][2] = bc; acc[mi][ni][3] = bc;
    }
  }
  const u16* Wb = Wcomb + (size_t)b * 256 * HD;
  #pragma unroll
  for (int ks = 0; ks < 4; ks++) {
    int k0 = ks * 32 + 8 * l4;
    f16x8 bf[2], af[4];
    #pragma unroll
    for (int ni = 0; ni < 2; ni++)
      bf[ni] = *(const f16x8*)(Wb + (size_t)(w * 32 + ni * 16 + l15) * HD + k0);
    #pragma unroll
    for (int mi = 0; mi < 4; mi++) {
      int row = mi * 16 + l15;
      af[mi] = *(const f16x8*)((const char*)albuf + row * 256 +
                               ((2 * k0) ^ ((row & 7) << 4)));
    }
    #pragma unroll
    for (int mi = 0; mi < 4; mi++)
      #pragma unroll
      for (int ni = 0; ni < 2; ni++)
        acc[mi][ni] = __builtin_amdgcn_mfma_f32_16x16x32_f16(af[mi], bf[ni],
                                                             acc[mi][ni], 0, 0, 0);
  }
  __syncthreads();

  if (w < 4) {
    #pragma unroll
    for (int mi = 0; mi < 4; mi++)
      #pragma unroll
      for (int r = 0; r < 4; r++) {
        int row = mi * 16 + l4 * 4 + r;
        char* rowp = (char*)albuf + row * 256;
        int sw = (row & 7) << 4;
        #pragma unroll
        for (int ni = 0; ni < 2; ni++) {
          int c = w * 32 + ni * 16 + l15;
          *(u16*)(rowp + ((2 * c) ^ sw)) =
              __builtin_bit_cast(u16, (f16)acc[mi][ni][r]);
        }
      }
  } else {
    int wv = w - 4;
    #pragma unroll
    for (int mi = 0; mi < 4; mi++)
      #pragma unroll
      for (int r = 0; r < 4; r++) {
        int rowl = mi * 16 + l4 * 4 + r;
        if (s_eid[rowl] >= 0) {
          u16* vp = v_csr + (size_t)s_rank[rowl] * HD + wv * 32 + l15;
          #pragma unroll
          for (int ni = 0; ni < 2; ni++)
            vp[ni * 16] = __builtin_bit_cast(u16, (f16)acc[mi][ni][r]);
        }
      }
  }
  __syncthreads();

  {
    int e = tid >> 3, h = tid & 7;
    if (s_eid[e] >= 0) {
      int d = s_dst[e];
      int tt = ntype[d];
      const char* rowp = (const char*)albuf + e * 256;
      int sw = (e & 7) << 4;
      f16x8 kh0 = *(const f16x8*)(rowp + ((h * 32) ^ sw));
      f16x8 kh1 = *(const f16x8*)(rowp + ((h * 32 + 16) ^ sw));
      const f16x8* qp = (const f16x8*)(q_h + (size_t)d * HD + h * 16);
      f16x8 qa = qp[0], qb = qp[1];
      float sc = 0.f;
      #pragma unroll
      for (int j = 0; j < 8; j++) sc += (float)qa[j] * (float)kh0[j];
      #pragma unroll
      for (int j = 0; j < 8; j++) sc += (float)qb[j] * (float)kh1[j];
      float pri = pri_l[((tt * R_N + rt) * T_N + st) * NH + h];
      score_h[(size_t)s_rank[e] * NH + h] =
          __builtin_bit_cast(u16, (f16)(sc * pri * 0.25f));
    }
  }
}

// Per-node segment softmax + weighted v-sum + exact GELU -> g (f16).
// 256 threads = 4 independent waves, one node each.
__global__ void k_aggr(const int* __restrict__ row_ptr,
                       const u16* __restrict__ score_h,
                       const u16* __restrict__ v_csr,
                       u16* __restrict__ g_h, int N) {
  int n = blockIdx.x * 4 + (threadIdx.x >> 6);
  if (n >= N) return;
  int lane = threadIdx.x & 63;
  int start = row_ptr[n], end = row_ptr[n + 1];

  int h = lane & 7, jj = lane >> 3;
  float m = -3.0e38f;
  for (int idx = start + jj; idx < end; idx += 8)
    m = fmaxf(m, (float)__builtin_bit_cast(f16, score_h[(size_t)idx * NH + h]));
  #pragma unroll
  for (int off = 8; off < 64; off <<= 1) m = fmaxf(m, __shfl_xor(m, off));
  float z = 0.f;
  for (int idx = start + jj; idx < end; idx += 8)
    z += expf((float)__builtin_bit_cast(f16, score_h[(size_t)idx * NH + h]) - m);
  #pragma unroll
  for (int off = 8; off < 64; off <<= 1) z += __shfl_xor(z, off);

  int myh = lane >> 3;
  float md = __shfl(m, myh);
  float zd = __shfl(z, myh);
  float rz = (zd > 0.f) ? 1.f / zd : 0.f;

  float a0 = 0.f, a1 = 0.f;
  for (int idx = start; idx < end; idx++) {
    float sc = (float)__builtin_bit_cast(f16, score_h[(size_t)idx * NH + myh]);
    float wgt = expf(sc - md) * rz;
    u32 v2 = ((const u32*)(v_csr + (size_t)idx * HD))[lane];
    float v0 = (float)__builtin_bit_cast(f16, (u16)(v2 & 0xffffu));
    float v1 = (float)__builtin_bit_cast(f16, (u16)(v2 >> 16));
    a0 = fmaf(wgt, v0, a0);
    a1 = fmaf(wgt, v1, a1);
  }

  a0 = 0.5f * a0 * (1.f + erff(a0 * 0.7071067811865475f));
  a1 = 0.5f * a1 * (1.f + erff(a1 * 0.7071067811865475f));
  u32 pk = (u32)__builtin_bit_cast(u16, (f16)a0)
         | ((u32)__builtin_bit_cast(u16, (f16)a1) << 16);
  ((u32*)(g_h + (size_t)n * HD))[lane] = pk;
}

}  // namespace

extern "C" void kernel_launch(void* const* d_in, const int* in_sizes, int n_in,
                              void* d_out, int out_size, void* d_ws, size_t ws_size,
                              hipStream_t stream) {
  const float* node_feature = (const float*)d_in[0];
  const int*   node_type    = (const int*)d_in[1];
  const int*   edge_time    = (const int*)d_in[2];
  const int*   edge_type    = (const int*)d_in[3];
  const int*   edge_index   = (const int*)d_in[4];
  const float* adapt_W      = (const float*)d_in[5];
  const float* adapt_b      = (const float*)d_in[6];
  const float* Wk           = (const float*)d_in[7];
  const float* bk           = (const float*)d_in[8];
  const float* Wq           = (const float*)d_in[9];
  const float* bq           = (const float*)d_in[10];
  const float* Wv           = (const float*)d_in[11];
  const float* bv           = (const float*)d_in[12];
  const float* Wa           = (const float*)d_in[13];
  const float* ba           = (const float*)d_in[14];
  const float* rel_pri      = (const float*)d_in[15];
  const float* rel_att      = (const float*)d_in[16];
  const float* rel_msg      = (const float*)d_in[17];
  const float* skip         = (const float*)d_in[18];
  const float* rte_emb      = (const float*)d_in[19];
  const float* rte_W        = (const float*)d_in[20];
  const float* rte_b        = (const float*)d_in[21];

  const int N = in_sizes[1];
  const int E = in_sizes[2];
  const int* src  = edge_index;
  const int* dstp = edge_index + E;

  float* x = (float*)d_out;

  size_t off = 0;
  auto carve = [&](size_t bytes) -> void* {
    void* p = (char*)d_ws + off;
    off += (bytes + 255) & ~(size_t)255;
    return p;
  };
  // ~254 MB total (stay under 256MiB; R8's 290MB crashed).
  u16*   v_csr   = (u16*)  carve((size_t)E * HD * 2);   // 204.8 MB, CSR-perm
  u16*   score_h = (u16*)  carve((size_t)E * NH * 2);   // 12.8 MB, CSR-perm
  u16*   x_h     = (u16*)  carve((size_t)N * HD * 2);   // 12.8 MB
  u16*   qg      = (u16*)  carve((size_t)N * HD * 2);   // 12.8 MB: q_h then g_h
  u16*   rte_h   = (u16*)  carve((size_t)2 * MAXT * HD * 2);       // both layers
  u16*   Wcomb   = (u16*)  carve((size_t)2 * 12 * 256 * HD * 2);   // both layers
  float* bcomb   = (float*)carve((size_t)2 * 12 * 256 * 4);
  u16*   adaptWT = (u16*)  carve((size_t)T_N * HD * IND * 2);
  u16*   WqT     = (u16*)  carve((size_t)2 * T_N * HD * HD * 2);
  u16*   WaT     = (u16*)  carve((size_t)2 * T_N * HD * HD * 2);
  int*   row_ptr = (int*)  carve((size_t)(N + 1) * 4);
  int*   cnt     = (int*)  carve((size_t)(N + 1) * 4);
  int*   rank    = (int*)  carve((size_t)E * 4);
  int*   bsums   = (int*)  carve(1024 * 4);
  int*   bcnt    = (int*)  carve(16 * 4);
  int*   bal     = (int*)  carve(16 * 4);
  int*   bcur    = (int*)  carve(16 * 4);
  int*   ncnt    = (int*)  carve(16 * 4);
  int*   nal     = (int*)  carve(16 * 4);
  int*   ncur    = (int*)  carve(16 * 4);
  const int EP = E + 12 * 64;
  const int NP = N + 3 * 64;
  int*   esorted = (int*)  carve((size_t)EP * 4);
  int*   nsorted = (int*)  carve((size_t)NP * 4);
  (void)ws_size; (void)n_in; (void)out_size;

  const int gE  = (E + 255) / 256;
  const int gN1 = (N + 1 + 255) / 256;
  const int gEP = (EP + 255) / 256;
  const int etiles = (EP + 63) / 64;
  const int ntiles = (NP + 63) / 64;
  const int gAggr  = (N + 3) / 4;

  // ---- setup: 7 dispatches ----
  k_fill_all<<<gEP, 256, 0, stream>>>(cnt, esorted, nsorted, bcnt, ncnt,
                                      N + 1, EP, NP);
  k_hist_all<<<gE, 256, 0, stream>>>(src, edge_type, node_type, dstp,
                                     cnt, bcnt, ncnt, E, N);
  k_scan_a<<<gN1, 256, 0, stream>>>(cnt, row_ptr, bsums, N + 1);
  k_scan_b<<<1, 256, 0, stream>>>(bsums, gN1);
  k_scan_c_copy<<<gN1, 256, 0, stream>>>(row_ptr, bsums, cnt, N + 1, N);
  k_scan_small<<<1, 64, 0, stream>>>(bcnt, bal, bcur, ncnt, nal, ncur);
  k_scatter_all<<<gE, 256, 0, stream>>>(src, edge_type, node_type, dstp,
                                        cnt, rank, bcur, esorted,
                                        ncur, nsorted, E, N);

  // ---- weights/tables: 3 dispatches ----
  k_transp_all<<<dim3(HD, T_N * 5), 128, 0, stream>>>(adapt_W, Wq, Wa,
                                                      adaptWT, WqT, WaT);
  k_rte<<<2 * MAXT, 64, 0, stream>>>(rte_emb, rte_W, rte_b, rte_h);
  k_wcomb<<<2 * 12 * 256, 128, 0, stream>>>(Wk, Wv, bk, bv, rel_att, rel_msg,
                                            Wcomb, bcomb);

  // adapt + fused q (layer 0): x, x_h, q0 -> qg
  k_ngemm<IND, 0, false, true><<<ntiles, 256, 0, stream>>>(
      node_feature, nullptr, adaptWT, adapt_b, nsorted, nal, nullptr,
      x, x_h, nullptr, WqT, bq, qg);

  // ---- layer 0 ----
  k_edge_gemm<<<etiles, 512, 0, stream>>>(
      x_h, rte_h, Wcomb, bcomb, qg, esorted, bal, src, dstp, edge_time,
      node_type, rank, rel_pri, score_h, v_csr);
  k_aggr<<<gAggr, 256, 0, stream>>>(row_ptr, score_h, v_csr, qg, N);
  // out-linear + skip blend + fused q (layer 1)
  k_ngemm<HD, 2, true, true><<<ntiles, 256, 0, stream>>>(
      nullptr, qg, WaT, ba, nsorted, nal, skip,
      x, x_h, x, WqT + (size_t)T_N * HD * HD, bq + (size_t)T_N * HD, qg);

  // ---- layer 1 ----
  k_edge_gemm<<<etiles, 512, 0, stream>>>(
      x_h, rte_h + (size_t)MAXT * HD,
      Wcomb + (size_t)12 * 256 * HD, bcomb + (size_t)12 * 256,
      qg, esorted, bal, src, dstp, edge_time, node_type, rank,
      rel_pri + (size_t)T_N * R_N * T_N * NH, score_h, v_csr);
  k_aggr<<<gAggr, 256, 0, stream>>>(row_ptr, score_h, v_csr, qg, N);
  // final out-linear (no fused q, no x_h mirror needed)
  k_ngemm<HD, 2, true, false><<<ntiles, 256, 0, stream>>>(
      nullptr, qg, WaT + (size_t)T_N * HD * HD, ba + (size_t)T_N * HD,
      nsorted, nal, skip + T_N, x, nullptr, x, nullptr, nullptr, nullptr);
}